// Round 1
// baseline (2669.188 us; speedup 1.0000x reference)
//
#include <hip/hip_runtime.h>
#include <hip/hip_bf16.h>
#include <cstdint>
#include <cstddef>

#define N_NODES 20000
#define N_EDGES 320000
#define N_GRAPHS 512
#define IN_FEATS 128
#define HID 256

// ---------------------------------------------------------------------------
// Generic 64x64-tile fp32 GEMM: C[M,N] = A[M,K] @ B[K,N] (+bias, optional relu)
// A row-major lda=K, B row-major ldb=N, C row-major with explicit ldc.
// Requires K % 16 == 0, N % 64 == 0. M arbitrary (guarded).
// ---------------------------------------------------------------------------
__global__ __launch_bounds__(256) void gemm64(const float* __restrict__ A,
                                              const float* __restrict__ B,
                                              float* __restrict__ C,
                                              const float* __restrict__ bias,
                                              int M, int N, int K, int ldc, int relu)
{
    __shared__ float As[16][68];   // [k][m], padded row stride 68 floats (272B, 16B-mult)
    __shared__ float Bs[16][64];   // [k][n]

    const int tid = threadIdx.x;
    const int m0 = blockIdx.y * 64, n0 = blockIdx.x * 64;
    const int tx = tid & 15, ty = tid >> 4;
    const int arow = tid >> 2, ak = (tid & 3) << 2;   // A tile: 64 rows x 16 k
    const int brow = tid >> 4, bc = (tid & 15) << 2;  // B tile: 16 k x 64 cols

    float acc[4][4] = {};

    for (int k0 = 0; k0 < K; k0 += 16) {
        float4 av = make_float4(0.f, 0.f, 0.f, 0.f);
        if (m0 + arow < M)
            av = *(const float4*)(A + (size_t)(m0 + arow) * K + k0 + ak);
        float4 bv = *(const float4*)(B + (size_t)(k0 + brow) * N + n0 + bc);
        __syncthreads();
        As[ak + 0][arow] = av.x;
        As[ak + 1][arow] = av.y;
        As[ak + 2][arow] = av.z;
        As[ak + 3][arow] = av.w;
        *(float4*)&Bs[brow][bc] = bv;
        __syncthreads();
#pragma unroll
        for (int k = 0; k < 16; ++k) {
            float4 a4 = *(const float4*)&As[k][ty << 2];
            float4 b4 = *(const float4*)&Bs[k][tx << 2];
            float a[4] = {a4.x, a4.y, a4.z, a4.w};
            float b[4] = {b4.x, b4.y, b4.z, b4.w};
#pragma unroll
            for (int i = 0; i < 4; ++i)
#pragma unroll
                for (int j = 0; j < 4; ++j)
                    acc[i][j] = fmaf(a[i], b[j], acc[i][j]);
        }
    }

#pragma unroll
    for (int i = 0; i < 4; ++i) {
        int row = m0 + (ty << 2) + i;
        if (row >= M) break;
#pragma unroll
        for (int j = 0; j < 4; ++j) {
            int col = n0 + (tx << 2) + j;
            float v = acc[i][j];
            if (bias) v += bias[col];
            if (relu) v = fmaxf(v, 0.f);
            C[(size_t)row * ldc + col] = v;
        }
    }
}

// ---------------------------------------------------------------------------
// Edge scatter: agg[dst[e]] += m[src[e]], one wave (64 lanes * float4) per edge
// ---------------------------------------------------------------------------
__global__ void edge_scatter(const float* __restrict__ m, const int* __restrict__ src,
                             const int* __restrict__ dst, float* __restrict__ agg)
{
    int gidx = blockIdx.x * blockDim.x + threadIdx.x;
    int e = gidx >> 6, lane = gidx & 63;
    if (e >= N_EDGES) return;
    int s = src[e], d = dst[e];
    float4 v = *(const float4*)(m + (size_t)s * HID + lane * 4);
    float* o = agg + (size_t)d * HID + lane * 4;
    atomicAdd(o + 0, v.x);
    atomicAdd(o + 1, v.y);
    atomicAdd(o + 2, v.z);
    atomicAdd(o + 3, v.w);
}

// ---------------------------------------------------------------------------
// new = relu(agg + b) + relu(r + rb); accumulate per-column sum / sumsq
// out may alias agg_in (read-then-write same element).
// ---------------------------------------------------------------------------
__global__ __launch_bounds__(256) void combine_stats(const float* __restrict__ agg_in,
                                                     const float* __restrict__ r,
                                                     const float* __restrict__ b,
                                                     const float* __restrict__ rb,
                                                     float* __restrict__ out,
                                                     float* __restrict__ stats)
{
    int col = threadIdx.x;  // 256
    float bb = b[col], rbb = rb[col];
    float s = 0.f, s2 = 0.f;
    for (int row = blockIdx.x; row < N_NODES; row += gridDim.x) {
        size_t idx = (size_t)row * HID + col;
        float v = fmaxf(agg_in[idx] + bb, 0.f) + fmaxf(r[idx] + rbb, 0.f);
        out[idx] = v;
        s += v;
        s2 += v * v;
    }
    atomicAdd(&stats[col], s);
    atomicAdd(&stats[HID + col], s2);
}

__global__ void bn_finalize(float* __restrict__ stats, float inv_n)
{
    int c = threadIdx.x;  // 256
    float mu = stats[c] * inv_n;
    float var = stats[HID + c] * inv_n - mu * mu;
    stats[2 * HID + c] = mu;
    stats[3 * HID + c] = rsqrtf(var + 1e-5f);
}

__global__ void bn_apply(float* __restrict__ h, const float* __restrict__ stats,
                         const float* __restrict__ g, const float* __restrict__ be)
{
    int i = blockIdx.x * blockDim.x + threadIdx.x;
    if (i >= N_NODES * HID / 4) return;
    int col = (i << 2) & (HID - 1);
    float4 v = ((float4*)h)[i];
    float4 mu = *(const float4*)(stats + 2 * HID + col);
    float4 rs = *(const float4*)(stats + 3 * HID + col);
    float4 gg = *(const float4*)(g + col);
    float4 bb = *(const float4*)(be + col);
    v.x = gg.x * (v.x - mu.x) * rs.x + bb.x;
    v.y = gg.y * (v.y - mu.y) * rs.y + bb.y;
    v.z = gg.z * (v.z - mu.z) * rs.z + bb.z;
    v.w = gg.w * (v.w - mu.w) * rs.w + bb.w;
    ((float4*)h)[i] = v;
}

// ---------------------------------------------------------------------------
// Per-node attention weight: w[n] = sigmoid(h[n] . aw_W + aw_b). Wave per node.
// ---------------------------------------------------------------------------
__global__ void node_weight(const float* __restrict__ h, const float* __restrict__ awW,
                            const float* __restrict__ awb, float* __restrict__ w)
{
    int gidx = blockIdx.x * blockDim.x + threadIdx.x;
    int n = gidx >> 6, lane = gidx & 63;
    if (n >= N_NODES) return;
    float4 hv = *(const float4*)(h + (size_t)n * HID + lane * 4);
    float4 wv = *(const float4*)(awW + lane * 4);
    float d = hv.x * wv.x + hv.y * wv.y + hv.z * wv.z + hv.w * wv.w;
#pragma unroll
    for (int off = 32; off > 0; off >>= 1) d += __shfl_xor(d, off);
    if (lane == 0) w[n] = 1.f / (1.f + expf(-(d + awb[0])));
}

// ---------------------------------------------------------------------------
// Per-graph readout: weighted sum + max over the graph's (contiguous, sorted)
// node range. One block per graph, thread = feature column.
// z layout: [N_GRAPHS, 1024] = [hg_sum(256) | hg_max(256) | rdkit(512)]
// ---------------------------------------------------------------------------
__global__ __launch_bounds__(256) void readout(const float* __restrict__ h,
                                               const float* __restrict__ w,
                                               const int* __restrict__ gid,
                                               float* __restrict__ z)
{
    int g = blockIdx.x, col = threadIdx.x;
    int lo = 0, hi = N_NODES;
    while (lo < hi) { int mid = (lo + hi) >> 1; if (gid[mid] < g) lo = mid + 1; else hi = mid; }
    int start = lo;
    hi = N_NODES;
    while (lo < hi) { int mid = (lo + hi) >> 1; if (gid[mid] <= g) lo = mid + 1; else hi = mid; }
    int end = lo;
    float s = 0.f, mx = -INFINITY;
    for (int n = start; n < end; ++n) {
        float v = h[(size_t)n * HID + col];
        s = fmaf(v, w[n], s);
        mx = fmaxf(mx, v);
    }
    z[(size_t)g * 1024 + col] = s;
    z[(size_t)g * 1024 + HID + col] = mx;
}

// ---------------------------------------------------------------------------
// Final head: out[b] = ch2[b] . c_W3 + c_b3  (K=512). Wave per row.
// ---------------------------------------------------------------------------
__global__ void final_dot(const float* __restrict__ x, const float* __restrict__ W,
                          const float* __restrict__ b, float* __restrict__ out)
{
    int gidx = blockIdx.x * blockDim.x + threadIdx.x;
    int rowi = gidx >> 6, lane = gidx & 63;
    if (rowi >= N_GRAPHS) return;
    const float4* xr = (const float4*)(x + (size_t)rowi * 512);
    const float4* wr = (const float4*)W;
    float acc = 0.f;
#pragma unroll
    for (int i = 0; i < 2; ++i) {
        float4 a = xr[lane * 2 + i];
        float4 ww = wr[lane * 2 + i];
        acc += a.x * ww.x + a.y * ww.y + a.z * ww.z + a.w * ww.w;
    }
#pragma unroll
    for (int off = 32; off > 0; off >>= 1) acc += __shfl_xor(acc, off);
    if (lane == 0) out[rowi] = acc + b[0];
}

// ---------------------------------------------------------------------------
extern "C" void kernel_launch(void* const* d_in, const int* in_sizes, int n_in,
                              void* d_out, int out_size, void* d_ws, size_t ws_size,
                              hipStream_t stream)
{
    (void)in_sizes; (void)n_in; (void)out_size; (void)ws_size;

    const float* node_feats = (const float*)d_in[0];
    const float* rdkit      = (const float*)d_in[1];
    const int*   src        = (const int*)d_in[2];
    const int*   dst        = (const int*)d_in[3];
    const int*   gid        = (const int*)d_in[4];
    const float* W1  = (const float*)d_in[5];
    const float* b1  = (const float*)d_in[6];
    const float* rW1 = (const float*)d_in[7];
    const float* rb1 = (const float*)d_in[8];
    const float* g1  = (const float*)d_in[9];
    const float* be1 = (const float*)d_in[10];
    const float* W2  = (const float*)d_in[11];
    const float* b2  = (const float*)d_in[12];
    const float* rW2 = (const float*)d_in[13];
    const float* rb2 = (const float*)d_in[14];
    const float* g2  = (const float*)d_in[15];
    const float* be2 = (const float*)d_in[16];
    const float* aw_W  = (const float*)d_in[17];
    const float* aw_b  = (const float*)d_in[18];
    const float* rk_W1 = (const float*)d_in[19];
    const float* rk_b1 = (const float*)d_in[20];
    const float* rk_W2 = (const float*)d_in[21];
    const float* rk_b2 = (const float*)d_in[22];
    const float* c_W1  = (const float*)d_in[23];
    const float* c_b1  = (const float*)d_in[24];
    const float* c_W2  = (const float*)d_in[25];
    const float* c_b2  = (const float*)d_in[26];
    const float* c_W3  = (const float*)d_in[27];
    const float* c_b3  = (const float*)d_in[28];

    float* out = (float*)d_out;

    const size_t NODE = (size_t)N_NODES * HID;  // 5,120,000 floats
    float* buf_m = (float*)d_ws;          // [N_NODES, HID] gemm scratch (m then r)
    float* aggA  = buf_m + NODE;          // layer-1 agg -> h1
    float* aggB  = aggA + NODE;           // layer-2 agg -> h2
    float* stats = aggB + NODE;           // 1024: sum | sumsq | mu | rsigma
    float* wbuf  = stats + 1024;          // 20000 node weights
    // head buffers alias buf_m (free after layer-2 combine)
    float* zbuf = buf_m;                  // [512, 1024]
    float* rkh  = zbuf + 512 * 1024;      // [512, 1024]
    float* ch1  = rkh + 512 * 1024;       // [512, 1024]
    float* ch2  = ch1 + 512 * 1024;       // [512, 512]

    dim3 blk(256);
    dim3 gemm_grid_nodes(HID / 64, (N_NODES + 63) / 64);

    // ---------------- Layer 1 ----------------
    gemm64<<<gemm_grid_nodes, blk, 0, stream>>>(node_feats, W1, buf_m, nullptr,
                                                N_NODES, HID, IN_FEATS, HID, 0);
    hipMemsetAsync(aggA, 0, NODE * sizeof(float), stream);
    edge_scatter<<<(N_EDGES * 64) / 256, blk, 0, stream>>>(buf_m, src, dst, aggA);
    gemm64<<<gemm_grid_nodes, blk, 0, stream>>>(node_feats, rW1, buf_m, nullptr,
                                                N_NODES, HID, IN_FEATS, HID, 0);
    hipMemsetAsync(stats, 0, 2 * HID * sizeof(float), stream);
    combine_stats<<<256, blk, 0, stream>>>(aggA, buf_m, b1, rb1, aggA, stats);
    bn_finalize<<<1, HID, 0, stream>>>(stats, 1.0f / N_NODES);
    bn_apply<<<(N_NODES * HID / 4 + 255) / 256, blk, 0, stream>>>(aggA, stats, g1, be1);

    // ---------------- Layer 2 ----------------
    gemm64<<<gemm_grid_nodes, blk, 0, stream>>>(aggA, W2, buf_m, nullptr,
                                                N_NODES, HID, HID, HID, 0);
    hipMemsetAsync(aggB, 0, NODE * sizeof(float), stream);
    edge_scatter<<<(N_EDGES * 64) / 256, blk, 0, stream>>>(buf_m, src, dst, aggB);
    gemm64<<<gemm_grid_nodes, blk, 0, stream>>>(aggA, rW2, buf_m, nullptr,
                                                N_NODES, HID, HID, HID, 0);
    hipMemsetAsync(stats, 0, 2 * HID * sizeof(float), stream);
    combine_stats<<<256, blk, 0, stream>>>(aggB, buf_m, b2, rb2, aggB, stats);
    bn_finalize<<<1, HID, 0, stream>>>(stats, 1.0f / N_NODES);
    bn_apply<<<(N_NODES * HID / 4 + 255) / 256, blk, 0, stream>>>(aggB, stats, g2, be2);

    // ---------------- Readout ----------------
    node_weight<<<(N_NODES * 64 + 255) / 256, blk, 0, stream>>>(aggB, aw_W, aw_b, wbuf);
    readout<<<N_GRAPHS, HID, 0, stream>>>(aggB, wbuf, gid, zbuf);

    // ---------------- RDKit branch ----------------
    gemm64<<<dim3(1024 / 64, 512 / 64), blk, 0, stream>>>(rdkit, rk_W1, rkh, rk_b1,
                                                          512, 1024, 2048, 1024, 1);
    gemm64<<<dim3(512 / 64, 512 / 64), blk, 0, stream>>>(rkh, rk_W2, zbuf + 512, rk_b2,
                                                         512, 512, 1024, 1024, 1);

    // ---------------- Combined head ----------------
    gemm64<<<dim3(1024 / 64, 512 / 64), blk, 0, stream>>>(zbuf, c_W1, ch1, c_b1,
                                                          512, 1024, 1024, 1024, 1);
    gemm64<<<dim3(512 / 64, 512 / 64), blk, 0, stream>>>(ch1, c_W2, ch2, c_b2,
                                                         512, 512, 1024, 512, 1);
    final_dot<<<(N_GRAPHS * 64) / 256, blk, 0, stream>>>(ch2, c_W3, c_b3, out);
}

// Round 2
// 781.694 us; speedup vs baseline: 3.4146x; 3.4146x over previous
//
#include <hip/hip_runtime.h>
#include <hip/hip_bf16.h>
#include <cstdint>
#include <cstddef>

#define N_NODES 20000
#define N_EDGES 320000
#define N_GRAPHS 512
#define IN_FEATS 128
#define HID 256

// ---------------------------------------------------------------------------
// Generic 64x64-tile fp32 GEMM: C[M,N] = A[M,K] @ B[K,N] (+bias, optional relu)
// ---------------------------------------------------------------------------
__global__ __launch_bounds__(256) void gemm64(const float* __restrict__ A,
                                              const float* __restrict__ B,
                                              float* __restrict__ C,
                                              const float* __restrict__ bias,
                                              int M, int N, int K, int ldc, int relu)
{
    __shared__ float As[16][68];
    __shared__ float Bs[16][64];

    const int tid = threadIdx.x;
    const int m0 = blockIdx.y * 64, n0 = blockIdx.x * 64;
    const int tx = tid & 15, ty = tid >> 4;
    const int arow = tid >> 2, ak = (tid & 3) << 2;
    const int brow = tid >> 4, bc = (tid & 15) << 2;

    float acc[4][4] = {};

    for (int k0 = 0; k0 < K; k0 += 16) {
        float4 av = make_float4(0.f, 0.f, 0.f, 0.f);
        if (m0 + arow < M)
            av = *(const float4*)(A + (size_t)(m0 + arow) * K + k0 + ak);
        float4 bv = *(const float4*)(B + (size_t)(k0 + brow) * N + n0 + bc);
        __syncthreads();
        As[ak + 0][arow] = av.x;
        As[ak + 1][arow] = av.y;
        As[ak + 2][arow] = av.z;
        As[ak + 3][arow] = av.w;
        *(float4*)&Bs[brow][bc] = bv;
        __syncthreads();
#pragma unroll
        for (int k = 0; k < 16; ++k) {
            float4 a4 = *(const float4*)&As[k][ty << 2];
            float4 b4 = *(const float4*)&Bs[k][tx << 2];
            float a[4] = {a4.x, a4.y, a4.z, a4.w};
            float b[4] = {b4.x, b4.y, b4.z, b4.w};
#pragma unroll
            for (int i = 0; i < 4; ++i)
#pragma unroll
                for (int j = 0; j < 4; ++j)
                    acc[i][j] = fmaf(a[i], b[j], acc[i][j]);
        }
    }

#pragma unroll
    for (int i = 0; i < 4; ++i) {
        int row = m0 + (ty << 2) + i;
        if (row >= M) break;
#pragma unroll
        for (int j = 0; j < 4; ++j) {
            int col = n0 + (tx << 2) + j;
            float v = acc[i][j];
            if (bias) v += bias[col];
            if (relu) v = fmaxf(v, 0.f);
            C[(size_t)row * ldc + col] = v;
        }
    }
}

// ---------------------------------------------------------------------------
// CSR build: counts -> exclusive scan -> fill (atomic cursor) -> per-node sort
// ---------------------------------------------------------------------------
__global__ void csr_count(const int* __restrict__ dst, int* __restrict__ counts)
{
    int e = blockIdx.x * blockDim.x + threadIdx.x;
    if (e >= N_EDGES) return;
    atomicAdd(&counts[dst[e]], 1);
}

__global__ __launch_bounds__(256) void csr_scan(const int* __restrict__ counts,
                                                int* __restrict__ offsets)
{
    __shared__ int partial[256];
    const int t = threadIdx.x;
    const int CH = (N_NODES + 255) / 256;  // 79
    const int base = t * CH;
    int s = 0;
    for (int i = 0; i < CH; ++i) {
        int idx = base + i;
        if (idx < N_NODES) s += counts[idx];
    }
    partial[t] = s;
    __syncthreads();
    if (t == 0) {
        int run = 0;
        for (int i = 0; i < 256; ++i) { int c = partial[i]; partial[i] = run; run += c; }
        offsets[N_NODES] = run;
    }
    __syncthreads();
    int run = partial[t];
    for (int i = 0; i < CH; ++i) {
        int idx = base + i;
        if (idx < N_NODES) { offsets[idx] = run; run += counts[idx]; }
    }
}

__global__ void csr_fill(const int* __restrict__ src, const int* __restrict__ dst,
                         const int* __restrict__ offsets, int* __restrict__ cursor,
                         int* __restrict__ eidx)
{
    int e = blockIdx.x * blockDim.x + threadIdx.x;
    if (e >= N_EDGES) return;
    int d = dst[e];
    int slot = offsets[d] + atomicAdd(&cursor[d], 1);
    eidx[slot] = src[e];
}

// sort each bucket by src value -> deterministic fp32 sum order
__global__ void csr_sort(const int* __restrict__ offsets, int* __restrict__ eidx)
{
    int n = blockIdx.x * blockDim.x + threadIdx.x;
    if (n >= N_NODES) return;
    int lo = offsets[n], hi = offsets[n + 1];
    for (int i = lo + 1; i < hi; ++i) {
        int v = eidx[i];
        int j = i - 1;
        while (j >= lo && eidx[j] > v) { eidx[j + 1] = eidx[j]; --j; }
        eidx[j + 1] = v;
    }
}

// ---------------------------------------------------------------------------
// Gather-aggregate: agg[n] = sum_{e in csr[n]} m[eidx[e]]. One wave per node.
// ---------------------------------------------------------------------------
__global__ __launch_bounds__(256) void edge_gather(const float* __restrict__ m,
                                                   const int* __restrict__ offsets,
                                                   const int* __restrict__ eidx,
                                                   float* __restrict__ agg)
{
    int gidx = blockIdx.x * blockDim.x + threadIdx.x;
    int n = gidx >> 6, lane = gidx & 63;
    if (n >= N_NODES) return;
    int lo = offsets[n], hi = offsets[n + 1];
    float4 acc = make_float4(0.f, 0.f, 0.f, 0.f);
    for (int i = lo; i < hi; ++i) {
        int s = eidx[i];
        float4 v = *(const float4*)(m + (size_t)s * HID + lane * 4);
        acc.x += v.x; acc.y += v.y; acc.z += v.z; acc.w += v.w;
    }
    *(float4*)(agg + (size_t)n * HID + lane * 4) = acc;
}

// ---------------------------------------------------------------------------
// new = relu(agg + b) + relu(r + rb); accumulate per-column sum / sumsq
// ---------------------------------------------------------------------------
__global__ __launch_bounds__(256) void combine_stats(const float* __restrict__ agg_in,
                                                     const float* __restrict__ r,
                                                     const float* __restrict__ b,
                                                     const float* __restrict__ rb,
                                                     float* __restrict__ out,
                                                     float* __restrict__ stats)
{
    int col = threadIdx.x;  // 256
    float bb = b[col], rbb = rb[col];
    float s = 0.f, s2 = 0.f;
    for (int row = blockIdx.x; row < N_NODES; row += gridDim.x) {
        size_t idx = (size_t)row * HID + col;
        float v = fmaxf(agg_in[idx] + bb, 0.f) + fmaxf(r[idx] + rbb, 0.f);
        out[idx] = v;
        s += v;
        s2 += v * v;
    }
    atomicAdd(&stats[col], s);
    atomicAdd(&stats[HID + col], s2);
}

__global__ void bn_finalize(float* __restrict__ stats, float inv_n)
{
    int c = threadIdx.x;  // 256
    float mu = stats[c] * inv_n;
    float var = stats[HID + c] * inv_n - mu * mu;
    stats[2 * HID + c] = mu;
    stats[3 * HID + c] = rsqrtf(var + 1e-5f);
}

__global__ void bn_apply(float* __restrict__ h, const float* __restrict__ stats,
                         const float* __restrict__ g, const float* __restrict__ be)
{
    int i = blockIdx.x * blockDim.x + threadIdx.x;
    if (i >= N_NODES * HID / 4) return;
    int col = (i << 2) & (HID - 1);
    float4 v = ((float4*)h)[i];
    float4 mu = *(const float4*)(stats + 2 * HID + col);
    float4 rs = *(const float4*)(stats + 3 * HID + col);
    float4 gg = *(const float4*)(g + col);
    float4 bb = *(const float4*)(be + col);
    v.x = gg.x * (v.x - mu.x) * rs.x + bb.x;
    v.y = gg.y * (v.y - mu.y) * rs.y + bb.y;
    v.z = gg.z * (v.z - mu.z) * rs.z + bb.z;
    v.w = gg.w * (v.w - mu.w) * rs.w + bb.w;
    ((float4*)h)[i] = v;
}

// ---------------------------------------------------------------------------
__global__ void node_weight(const float* __restrict__ h, const float* __restrict__ awW,
                            const float* __restrict__ awb, float* __restrict__ w)
{
    int gidx = blockIdx.x * blockDim.x + threadIdx.x;
    int n = gidx >> 6, lane = gidx & 63;
    if (n >= N_NODES) return;
    float4 hv = *(const float4*)(h + (size_t)n * HID + lane * 4);
    float4 wv = *(const float4*)(awW + lane * 4);
    float d = hv.x * wv.x + hv.y * wv.y + hv.z * wv.z + hv.w * wv.w;
#pragma unroll
    for (int off = 32; off > 0; off >>= 1) d += __shfl_xor(d, off);
    if (lane == 0) w[n] = 1.f / (1.f + expf(-(d + awb[0])));
}

__global__ __launch_bounds__(256) void readout(const float* __restrict__ h,
                                               const float* __restrict__ w,
                                               const int* __restrict__ gid,
                                               float* __restrict__ z)
{
    int g = blockIdx.x, col = threadIdx.x;
    int lo = 0, hi = N_NODES;
    while (lo < hi) { int mid = (lo + hi) >> 1; if (gid[mid] < g) lo = mid + 1; else hi = mid; }
    int start = lo;
    hi = N_NODES;
    while (lo < hi) { int mid = (lo + hi) >> 1; if (gid[mid] <= g) lo = mid + 1; else hi = mid; }
    int end = lo;
    float s = 0.f, mx = -INFINITY;
    for (int n = start; n < end; ++n) {
        float v = h[(size_t)n * HID + col];
        s = fmaf(v, w[n], s);
        mx = fmaxf(mx, v);
    }
    z[(size_t)g * 1024 + col] = s;
    z[(size_t)g * 1024 + HID + col] = mx;
}

__global__ void final_dot(const float* __restrict__ x, const float* __restrict__ W,
                          const float* __restrict__ b, float* __restrict__ out)
{
    int gidx = blockIdx.x * blockDim.x + threadIdx.x;
    int rowi = gidx >> 6, lane = gidx & 63;
    if (rowi >= N_GRAPHS) return;
    const float4* xr = (const float4*)(x + (size_t)rowi * 512);
    const float4* wr = (const float4*)W;
    float acc = 0.f;
#pragma unroll
    for (int i = 0; i < 2; ++i) {
        float4 a = xr[lane * 2 + i];
        float4 ww = wr[lane * 2 + i];
        acc += a.x * ww.x + a.y * ww.y + a.z * ww.z + a.w * ww.w;
    }
#pragma unroll
    for (int off = 32; off > 0; off >>= 1) acc += __shfl_xor(acc, off);
    if (lane == 0) out[rowi] = acc + b[0];
}

// ---------------------------------------------------------------------------
extern "C" void kernel_launch(void* const* d_in, const int* in_sizes, int n_in,
                              void* d_out, int out_size, void* d_ws, size_t ws_size,
                              hipStream_t stream)
{
    (void)in_sizes; (void)n_in; (void)out_size; (void)ws_size;

    const float* node_feats = (const float*)d_in[0];
    const float* rdkit      = (const float*)d_in[1];
    const int*   src        = (const int*)d_in[2];
    const int*   dst        = (const int*)d_in[3];
    const int*   gid        = (const int*)d_in[4];
    const float* W1  = (const float*)d_in[5];
    const float* b1  = (const float*)d_in[6];
    const float* rW1 = (const float*)d_in[7];
    const float* rb1 = (const float*)d_in[8];
    const float* g1  = (const float*)d_in[9];
    const float* be1 = (const float*)d_in[10];
    const float* W2  = (const float*)d_in[11];
    const float* b2  = (const float*)d_in[12];
    const float* rW2 = (const float*)d_in[13];
    const float* rb2 = (const float*)d_in[14];
    const float* g2  = (const float*)d_in[15];
    const float* be2 = (const float*)d_in[16];
    const float* aw_W  = (const float*)d_in[17];
    const float* aw_b  = (const float*)d_in[18];
    const float* rk_W1 = (const float*)d_in[19];
    const float* rk_b1 = (const float*)d_in[20];
    const float* rk_W2 = (const float*)d_in[21];
    const float* rk_b2 = (const float*)d_in[22];
    const float* c_W1  = (const float*)d_in[23];
    const float* c_b1  = (const float*)d_in[24];
    const float* c_W2  = (const float*)d_in[25];
    const float* c_b2  = (const float*)d_in[26];
    const float* c_W3  = (const float*)d_in[27];
    const float* c_b3  = (const float*)d_in[28];

    float* out = (float*)d_out;

    const size_t NODE = (size_t)N_NODES * HID;  // 5,120,000 floats
    float* buf_m = (float*)d_ws;          // [N_NODES, HID] gemm scratch (m then r)
    float* aggA  = buf_m + NODE;          // layer-1 h
    float* aggB  = aggA + NODE;           // layer-2 h
    float* stats = aggB + NODE;           // 1024: sum | sumsq | mu | rsigma
    float* wbuf  = stats + 1024;          // 20000 node weights
    int*   counts  = (int*)(wbuf + N_NODES);
    int*   offsets = counts + N_NODES;    // N_NODES + 1
    int*   cursor  = offsets + N_NODES + 1;
    int*   eidx    = cursor + N_NODES;    // N_EDGES
    // head buffers alias buf_m (free after layer-2 combine)
    float* zbuf = buf_m;                  // [512, 1024]
    float* rkh  = zbuf + 512 * 1024;      // [512, 1024]
    float* ch1  = rkh + 512 * 1024;       // [512, 1024]
    float* ch2  = ch1 + 512 * 1024;       // [512, 512]

    dim3 blk(256);
    dim3 gemm_grid_nodes(HID / 64, (N_NODES + 63) / 64);
    const int EPB = (N_EDGES + 255) / 256;
    const int NPB = (N_NODES + 255) / 256;
    const int NWAVE = (N_NODES * 64 + 255) / 256;

    // ---------------- CSR build (dst -> sorted src list) ----------------
    hipMemsetAsync(counts, 0, 2 * N_NODES * sizeof(int) + sizeof(int), stream);  // counts+offsets head unused; cursor below
    hipMemsetAsync(cursor, 0, N_NODES * sizeof(int), stream);
    csr_count<<<EPB, blk, 0, stream>>>(dst, counts);
    csr_scan<<<1, blk, 0, stream>>>(counts, offsets);
    csr_fill<<<EPB, blk, 0, stream>>>(src, dst, offsets, cursor, eidx);
    csr_sort<<<NPB, blk, 0, stream>>>(offsets, eidx);

    // ---------------- Layer 1 ----------------
    gemm64<<<gemm_grid_nodes, blk, 0, stream>>>(node_feats, W1, buf_m, nullptr,
                                                N_NODES, HID, IN_FEATS, HID, 0);
    edge_gather<<<NWAVE, blk, 0, stream>>>(buf_m, offsets, eidx, aggA);
    gemm64<<<gemm_grid_nodes, blk, 0, stream>>>(node_feats, rW1, buf_m, nullptr,
                                                N_NODES, HID, IN_FEATS, HID, 0);
    hipMemsetAsync(stats, 0, 2 * HID * sizeof(float), stream);
    combine_stats<<<256, blk, 0, stream>>>(aggA, buf_m, b1, rb1, aggA, stats);
    bn_finalize<<<1, HID, 0, stream>>>(stats, 1.0f / N_NODES);
    bn_apply<<<(N_NODES * HID / 4 + 255) / 256, blk, 0, stream>>>(aggA, stats, g1, be1);

    // ---------------- Layer 2 ----------------
    gemm64<<<gemm_grid_nodes, blk, 0, stream>>>(aggA, W2, buf_m, nullptr,
                                                N_NODES, HID, HID, HID, 0);
    edge_gather<<<NWAVE, blk, 0, stream>>>(buf_m, offsets, eidx, aggB);
    gemm64<<<gemm_grid_nodes, blk, 0, stream>>>(aggA, rW2, buf_m, nullptr,
                                                N_NODES, HID, HID, HID, 0);
    hipMemsetAsync(stats, 0, 2 * HID * sizeof(float), stream);
    combine_stats<<<256, blk, 0, stream>>>(aggB, buf_m, b2, rb2, aggB, stats);
    bn_finalize<<<1, HID, 0, stream>>>(stats, 1.0f / N_NODES);
    bn_apply<<<(N_NODES * HID / 4 + 255) / 256, blk, 0, stream>>>(aggB, stats, g2, be2);

    // ---------------- Readout ----------------
    node_weight<<<NWAVE, blk, 0, stream>>>(aggB, aw_W, aw_b, wbuf);
    readout<<<N_GRAPHS, HID, 0, stream>>>(aggB, wbuf, gid, zbuf);

    // ---------------- RDKit branch ----------------
    gemm64<<<dim3(1024 / 64, 512 / 64), blk, 0, stream>>>(rdkit, rk_W1, rkh, rk_b1,
                                                          512, 1024, 2048, 1024, 1);
    gemm64<<<dim3(512 / 64, 512 / 64), blk, 0, stream>>>(rkh, rk_W2, zbuf + 512, rk_b2,
                                                         512, 512, 1024, 1024, 1);

    // ---------------- Combined head ----------------
    gemm64<<<dim3(1024 / 64, 512 / 64), blk, 0, stream>>>(zbuf, c_W1, ch1, c_b1,
                                                          512, 1024, 1024, 1024, 1);
    gemm64<<<dim3(512 / 64, 512 / 64), blk, 0, stream>>>(ch1, c_W2, ch2, c_b2,
                                                         512, 512, 1024, 512, 1);
    final_dot<<<(N_GRAPHS * 64) / 256, blk, 0, stream>>>(ch2, c_W3, c_b3, out);
}

// Round 3
// 640.700 us; speedup vs baseline: 4.1661x; 1.2201x over previous
//
#include <hip/hip_runtime.h>
#include <hip/hip_bf16.h>
#include <cstdint>
#include <cstddef>

#define N_NODES 20000
#define N_EDGES 320000
#define N_GRAPHS 512
#define IN_FEATS 128
#define HID 256

typedef __bf16 bhalf;
typedef __bf16 bhalf8 __attribute__((ext_vector_type(8)));
typedef __bf16 bhalf4 __attribute__((ext_vector_type(4)));
typedef float f32x4 __attribute__((ext_vector_type(4)));

// ---------------------------------------------------------------------------
// bf16 MFMA GEMM: C[M,N] = A[M,K] @ B[K,N], A bf16 row-major [M,K],
// Bt bf16 row-major [N,K] (pre-transposed). fp32 accumulate.
// Tile 128x128, BK=64, 256 threads = 4 waves (2x2), wave does 64x64 via
// 4x4 frags of 16x16x32. LDS XOR-swizzled to avoid stride-128B conflicts.
// Requires K%64==0, N%128==0; M guarded.
// ---------------------------------------------------------------------------
template<int RELU, int OUTBF16>
__global__ __launch_bounds__(256) void gemm_mfma(const bhalf* __restrict__ A,
                                                 const bhalf* __restrict__ Bt,
                                                 void* __restrict__ Cv,
                                                 const float* __restrict__ bias,
                                                 int M, int K, int ldc)
{
    __shared__ bhalf As[128 * 64];
    __shared__ bhalf Bs[128 * 64];

    const int t = threadIdx.x;
    const int lane = t & 63, wid = t >> 6;
    const int wm0 = (wid >> 1) * 64, wn0 = (wid & 1) * 64;
    const int m0 = blockIdx.y * 128, n0 = blockIdx.x * 128;

    f32x4 acc[4][4] = {};

    const int srow = t >> 3;              // staging: 1024 chunks of 8 bf16
    const int scol = (t & 7) << 3;

    for (int k0 = 0; k0 < K; k0 += 64) {
        __syncthreads();
#pragma unroll
        for (int i = 0; i < 4; ++i) {
            int row = srow + i * 32;
            int sc = scol ^ ((row & 7) << 3);
            uint4 va = make_uint4(0u, 0u, 0u, 0u);
            int gr = m0 + row;
            if (gr < M) va = *(const uint4*)(A + (size_t)gr * K + k0 + scol);
            *(uint4*)&As[row * 64 + sc] = va;
            uint4 vb = *(const uint4*)(Bt + (size_t)(n0 + row) * K + k0 + scol);
            *(uint4*)&Bs[row * 64 + sc] = vb;
        }
        __syncthreads();
#pragma unroll
        for (int kb = 0; kb < 2; ++kb) {
            const int kc = kb * 32 + (lane >> 4) * 8;
            bhalf8 af[4], bfr[4];
#pragma unroll
            for (int i = 0; i < 4; ++i) {
                int ra = wm0 + i * 16 + (lane & 15);
                af[i] = *(const bhalf8*)&As[ra * 64 + (kc ^ ((ra & 7) << 3))];
                int rb = wn0 + i * 16 + (lane & 15);
                bfr[i] = *(const bhalf8*)&Bs[rb * 64 + (kc ^ ((rb & 7) << 3))];
            }
#pragma unroll
            for (int mi = 0; mi < 4; ++mi)
#pragma unroll
                for (int ni = 0; ni < 4; ++ni)
                    acc[mi][ni] = __builtin_amdgcn_mfma_f32_16x16x32_bf16(
                        af[mi], bfr[ni], acc[mi][ni], 0, 0, 0);
        }
    }

#pragma unroll
    for (int mi = 0; mi < 4; ++mi)
#pragma unroll
        for (int ni = 0; ni < 4; ++ni) {
            int col = n0 + wn0 + ni * 16 + (lane & 15);
            float bb = bias ? bias[col] : 0.f;
            f32x4 v = acc[mi][ni];
#pragma unroll
            for (int r = 0; r < 4; ++r) {
                int row = m0 + wm0 + mi * 16 + (lane >> 4) * 4 + r;
                if (row < M) {
                    float x = v[r] + bb;
                    if (RELU) x = fmaxf(x, 0.f);
                    if (OUTBF16) ((bhalf*)Cv)[(size_t)row * ldc + col] = (bhalf)x;
                    else         ((float*)Cv)[(size_t)row * ldc + col] = x;
                }
            }
        }
}

// ---------------------------------------------------------------------------
// Weight transpose+convert: in fp32 [K,N] -> out bf16 [N,K]. K,N % 32 == 0.
// ---------------------------------------------------------------------------
__global__ __launch_bounds__(256) void wconv_t(const float* __restrict__ in,
                                               bhalf* __restrict__ out, int K, int N)
{
    __shared__ float tile[32][33];
    int bx = blockIdx.x * 32;  // N
    int by = blockIdx.y * 32;  // K
    int tx = threadIdx.x, ty = threadIdx.y;  // 32 x 8
#pragma unroll
    for (int i = 0; i < 32; i += 8)
        tile[ty + i][tx] = in[(size_t)(by + ty + i) * N + bx + tx];
    __syncthreads();
#pragma unroll
    for (int i = 0; i < 32; i += 8)
        out[(size_t)(bx + ty + i) * K + by + tx] = (bhalf)tile[tx][ty + i];
}

__global__ void conv_bf16(const float* __restrict__ in, bhalf* __restrict__ out, int n4)
{
    int i = blockIdx.x * blockDim.x + threadIdx.x;
    if (i >= n4) return;
    float4 v = ((const float4*)in)[i];
    bhalf4 o = {(bhalf)v.x, (bhalf)v.y, (bhalf)v.z, (bhalf)v.w};
    ((bhalf4*)out)[i] = o;
}

// ---------------------------------------------------------------------------
// CSR build: counts -> exclusive scan -> fill (atomic cursor) -> per-node sort
// ---------------------------------------------------------------------------
__global__ void csr_count(const int* __restrict__ dst, int* __restrict__ counts)
{
    int e = blockIdx.x * blockDim.x + threadIdx.x;
    if (e >= N_EDGES) return;
    atomicAdd(&counts[dst[e]], 1);
}

__global__ __launch_bounds__(256) void csr_scan(const int* __restrict__ counts,
                                                int* __restrict__ offsets)
{
    __shared__ int partial[256];
    const int t = threadIdx.x;
    const int CH = (N_NODES + 255) / 256;
    const int base = t * CH;
    int s = 0;
    for (int i = 0; i < CH; ++i) {
        int idx = base + i;
        if (idx < N_NODES) s += counts[idx];
    }
    partial[t] = s;
    __syncthreads();
    if (t == 0) {
        int run = 0;
        for (int i = 0; i < 256; ++i) { int c = partial[i]; partial[i] = run; run += c; }
        offsets[N_NODES] = run;
    }
    __syncthreads();
    int run = partial[t];
    for (int i = 0; i < CH; ++i) {
        int idx = base + i;
        if (idx < N_NODES) { offsets[idx] = run; run += counts[idx]; }
    }
}

__global__ void csr_fill(const int* __restrict__ src, const int* __restrict__ dst,
                         const int* __restrict__ offsets, int* __restrict__ cursor,
                         int* __restrict__ eidx)
{
    int e = blockIdx.x * blockDim.x + threadIdx.x;
    if (e >= N_EDGES) return;
    int d = dst[e];
    int slot = offsets[d] + atomicAdd(&cursor[d], 1);
    eidx[slot] = src[e];
}

__global__ void csr_sort(const int* __restrict__ offsets, int* __restrict__ eidx)
{
    int n = blockIdx.x * blockDim.x + threadIdx.x;
    if (n >= N_NODES) return;
    int lo = offsets[n], hi = offsets[n + 1];
    for (int i = lo + 1; i < hi; ++i) {
        int v = eidx[i];
        int j = i - 1;
        while (j >= lo && eidx[j] > v) { eidx[j + 1] = eidx[j]; --j; }
        eidx[j + 1] = v;
    }
}

// ---------------------------------------------------------------------------
// Gather-aggregate: agg[n] = sum_{e in csr[n]} m[eidx[e]]. One wave per node.
// ---------------------------------------------------------------------------
__global__ __launch_bounds__(256) void edge_gather(const float* __restrict__ m,
                                                   const int* __restrict__ offsets,
                                                   const int* __restrict__ eidx,
                                                   float* __restrict__ agg)
{
    int gidx = blockIdx.x * blockDim.x + threadIdx.x;
    int n = gidx >> 6, lane = gidx & 63;
    if (n >= N_NODES) return;
    int lo = offsets[n], hi = offsets[n + 1];
    float4 acc = make_float4(0.f, 0.f, 0.f, 0.f);
    for (int i = lo; i < hi; ++i) {
        int s = eidx[i];
        float4 v = *(const float4*)(m + (size_t)s * HID + lane * 4);
        acc.x += v.x; acc.y += v.y; acc.z += v.z; acc.w += v.w;
    }
    *(float4*)(agg + (size_t)n * HID + lane * 4) = acc;
}

// ---------------------------------------------------------------------------
__global__ __launch_bounds__(256) void combine_stats(const float* __restrict__ agg_in,
                                                     const float* __restrict__ r,
                                                     const float* __restrict__ b,
                                                     const float* __restrict__ rb,
                                                     float* __restrict__ out,
                                                     float* __restrict__ stats)
{
    int col = threadIdx.x;
    float bb = b[col], rbb = rb[col];
    float s = 0.f, s2 = 0.f;
    for (int row = blockIdx.x; row < N_NODES; row += gridDim.x) {
        size_t idx = (size_t)row * HID + col;
        float v = fmaxf(agg_in[idx] + bb, 0.f) + fmaxf(r[idx] + rbb, 0.f);
        out[idx] = v;
        s += v;
        s2 += v * v;
    }
    atomicAdd(&stats[col], s);
    atomicAdd(&stats[HID + col], s2);
}

__global__ void bn_finalize(float* __restrict__ stats, float inv_n)
{
    int c = threadIdx.x;
    float mu = stats[c] * inv_n;
    float var = stats[HID + c] * inv_n - mu * mu;
    stats[2 * HID + c] = mu;
    stats[3 * HID + c] = rsqrtf(var + 1e-5f);
}

// BN, fp32 in-place
__global__ void bn_apply(float* __restrict__ h, const float* __restrict__ stats,
                         const float* __restrict__ g, const float* __restrict__ be)
{
    int i = blockIdx.x * blockDim.x + threadIdx.x;
    if (i >= N_NODES * HID / 4) return;
    int col = (i << 2) & (HID - 1);
    float4 v = ((float4*)h)[i];
    float4 mu = *(const float4*)(stats + 2 * HID + col);
    float4 rs = *(const float4*)(stats + 3 * HID + col);
    float4 gg = *(const float4*)(g + col);
    float4 bb = *(const float4*)(be + col);
    v.x = gg.x * (v.x - mu.x) * rs.x + bb.x;
    v.y = gg.y * (v.y - mu.y) * rs.y + bb.y;
    v.z = gg.z * (v.z - mu.z) * rs.z + bb.z;
    v.w = gg.w * (v.w - mu.w) * rs.w + bb.w;
    ((float4*)h)[i] = v;
}

// BN, read fp32 -> write bf16 (layer-1 h feeds bf16 GEMMs only)
__global__ void bn_apply_bf16(const float* __restrict__ h, const float* __restrict__ stats,
                              const float* __restrict__ g, const float* __restrict__ be,
                              bhalf* __restrict__ outb)
{
    int i = blockIdx.x * blockDim.x + threadIdx.x;
    if (i >= N_NODES * HID / 4) return;
    int col = (i << 2) & (HID - 1);
    float4 v = ((const float4*)h)[i];
    float4 mu = *(const float4*)(stats + 2 * HID + col);
    float4 rs = *(const float4*)(stats + 3 * HID + col);
    float4 gg = *(const float4*)(g + col);
    float4 bb = *(const float4*)(be + col);
    bhalf4 o;
    o.x = (bhalf)(gg.x * (v.x - mu.x) * rs.x + bb.x);
    o.y = (bhalf)(gg.y * (v.y - mu.y) * rs.y + bb.y);
    o.z = (bhalf)(gg.z * (v.z - mu.z) * rs.z + bb.z);
    o.w = (bhalf)(gg.w * (v.w - mu.w) * rs.w + bb.w);
    ((bhalf4*)outb)[i] = o;
}

// ---------------------------------------------------------------------------
__global__ void node_weight(const float* __restrict__ h, const float* __restrict__ awW,
                            const float* __restrict__ awb, float* __restrict__ w)
{
    int gidx = blockIdx.x * blockDim.x + threadIdx.x;
    int n = gidx >> 6, lane = gidx & 63;
    if (n >= N_NODES) return;
    float4 hv = *(const float4*)(h + (size_t)n * HID + lane * 4);
    float4 wv = *(const float4*)(awW + lane * 4);
    float d = hv.x * wv.x + hv.y * wv.y + hv.z * wv.z + hv.w * wv.w;
#pragma unroll
    for (int off = 32; off > 0; off >>= 1) d += __shfl_xor(d, off);
    if (lane == 0) w[n] = 1.f / (1.f + expf(-(d + awb[0])));
}

// writes bf16 graph features into z[g][0:512] = [sum(256) | max(256)]
__global__ __launch_bounds__(256) void readout(const float* __restrict__ h,
                                               const float* __restrict__ w,
                                               const int* __restrict__ gid,
                                               bhalf* __restrict__ z)
{
    int g = blockIdx.x, col = threadIdx.x;
    int lo = 0, hi = N_NODES;
    while (lo < hi) { int mid = (lo + hi) >> 1; if (gid[mid] < g) lo = mid + 1; else hi = mid; }
    int start = lo;
    hi = N_NODES;
    while (lo < hi) { int mid = (lo + hi) >> 1; if (gid[mid] <= g) lo = mid + 1; else hi = mid; }
    int end = lo;
    float s = 0.f, mx = -INFINITY;
    for (int n = start; n < end; ++n) {
        float v = h[(size_t)n * HID + col];
        s = fmaf(v, w[n], s);
        mx = fmaxf(mx, v);
    }
    z[(size_t)g * 1024 + col] = (bhalf)s;
    z[(size_t)g * 1024 + HID + col] = (bhalf)mx;
}

__global__ void final_dot(const float* __restrict__ x, const float* __restrict__ W,
                          const float* __restrict__ b, float* __restrict__ out)
{
    int gidx = blockIdx.x * blockDim.x + threadIdx.x;
    int rowi = gidx >> 6, lane = gidx & 63;
    if (rowi >= N_GRAPHS) return;
    const float4* xr = (const float4*)(x + (size_t)rowi * 512);
    const float4* wr = (const float4*)W;
    float acc = 0.f;
#pragma unroll
    for (int i = 0; i < 2; ++i) {
        float4 a = xr[lane * 2 + i];
        float4 ww = wr[lane * 2 + i];
        acc += a.x * ww.x + a.y * ww.y + a.z * ww.z + a.w * ww.w;
    }
#pragma unroll
    for (int off = 32; off > 0; off >>= 1) acc += __shfl_xor(acc, off);
    if (lane == 0) out[rowi] = acc + b[0];
}

// ---------------------------------------------------------------------------
extern "C" void kernel_launch(void* const* d_in, const int* in_sizes, int n_in,
                              void* d_out, int out_size, void* d_ws, size_t ws_size,
                              hipStream_t stream)
{
    (void)in_sizes; (void)n_in; (void)out_size; (void)ws_size;

    const float* node_feats = (const float*)d_in[0];
    const float* rdkit      = (const float*)d_in[1];
    const int*   src        = (const int*)d_in[2];
    const int*   dst        = (const int*)d_in[3];
    const int*   gid        = (const int*)d_in[4];
    const float* W1  = (const float*)d_in[5];
    const float* b1  = (const float*)d_in[6];
    const float* rW1 = (const float*)d_in[7];
    const float* rb1 = (const float*)d_in[8];
    const float* g1  = (const float*)d_in[9];
    const float* be1 = (const float*)d_in[10];
    const float* W2  = (const float*)d_in[11];
    const float* b2  = (const float*)d_in[12];
    const float* rW2 = (const float*)d_in[13];
    const float* rb2 = (const float*)d_in[14];
    const float* g2  = (const float*)d_in[15];
    const float* be2 = (const float*)d_in[16];
    const float* aw_W  = (const float*)d_in[17];
    const float* aw_b  = (const float*)d_in[18];
    const float* rk_W1 = (const float*)d_in[19];
    const float* rk_b1 = (const float*)d_in[20];
    const float* rk_W2 = (const float*)d_in[21];
    const float* rk_b2 = (const float*)d_in[22];
    const float* c_W1  = (const float*)d_in[23];
    const float* c_b1  = (const float*)d_in[24];
    const float* c_W2  = (const float*)d_in[25];
    const float* c_b2  = (const float*)d_in[26];
    const float* c_W3  = (const float*)d_in[27];
    const float* c_b3  = (const float*)d_in[28];

    float* out = (float*)d_out;

    const size_t NODE = (size_t)N_NODES * HID;  // 5,120,000
    float* buf_m = (float*)d_ws;           // [20000,256] fp32 GEMM scratch
    float* aggA  = buf_m + NODE;           // agg / h (fp32)
    bhalf* h1b   = (bhalf*)(aggA + NODE);  // 5,120,000 bf16 (nf_bf16 aliases front)
    bhalf* nfb   = h1b;                    // [20000,128] bf16
    bhalf* W1t   = h1b + NODE;             // weights (transposed bf16)
    bhalf* rW1t  = W1t + 128 * 256;
    bhalf* W2t   = rW1t + 128 * 256;
    bhalf* rW2t  = W2t + 256 * 256;
    bhalf* rkW1t = rW2t + 256 * 256;
    bhalf* rkW2t = rkW1t + 2048 * 1024;
    bhalf* cW1t  = rkW2t + 1024 * 512;
    bhalf* cW2t  = cW1t + 1024 * 1024;
    bhalf* rdkb  = cW2t + 1024 * 512;      // [512,2048] bf16
    float* stats = (float*)(rdkb + 512 * 2048);  // 1024
    float* wbuf  = stats + 1024;           // 20000
    int*   counts  = (int*)(wbuf + N_NODES);
    int*   offsets = counts + N_NODES;     // N+1
    int*   cursor  = offsets + N_NODES + 1;
    int*   eidx    = cursor + N_NODES;     // N_EDGES
    // head buffers alias buf_m (free after layer-2 combine)
    bhalf* rkhb = (bhalf*)buf_m;           // [512,1024] bf16
    bhalf* zb   = rkhb + 512 * 1024;       // [512,1024] bf16
    bhalf* ch1b = zb + 512 * 1024;         // [512,1024] bf16
    float* ch2  = (float*)(ch1b + 512 * 1024);  // [512,512] fp32

    dim3 blk(256);
    dim3 tblk(32, 8);
    const int EPB = (N_EDGES + 255) / 256;
    const int NPB = (N_NODES + 255) / 256;
    const int NWAVE = (N_NODES * 64) / 256;
    dim3 gnode(HID / 128, (N_NODES + 127) / 128);  // (2, 157)

    // ---------------- weight/input conversion ----------------
    wconv_t<<<dim3(256/32, 128/32), tblk, 0, stream>>>(W1, W1t, 128, 256);
    wconv_t<<<dim3(256/32, 128/32), tblk, 0, stream>>>(rW1, rW1t, 128, 256);
    wconv_t<<<dim3(256/32, 256/32), tblk, 0, stream>>>(W2, W2t, 256, 256);
    wconv_t<<<dim3(256/32, 256/32), tblk, 0, stream>>>(rW2, rW2t, 256, 256);
    wconv_t<<<dim3(1024/32, 2048/32), tblk, 0, stream>>>(rk_W1, rkW1t, 2048, 1024);
    wconv_t<<<dim3(512/32, 1024/32), tblk, 0, stream>>>(rk_W2, rkW2t, 1024, 512);
    wconv_t<<<dim3(1024/32, 1024/32), tblk, 0, stream>>>(c_W1, cW1t, 1024, 1024);
    wconv_t<<<dim3(512/32, 1024/32), tblk, 0, stream>>>(c_W2, cW2t, 1024, 512);
    conv_bf16<<<(N_NODES * IN_FEATS / 4 + 255) / 256, blk, 0, stream>>>(node_feats, nfb, N_NODES * IN_FEATS / 4);
    conv_bf16<<<(512 * 2048 / 4 + 255) / 256, blk, 0, stream>>>(rdkit, rdkb, 512 * 2048 / 4);

    // ---------------- CSR build ----------------
    hipMemsetAsync(counts, 0, N_NODES * sizeof(int), stream);
    hipMemsetAsync(cursor, 0, N_NODES * sizeof(int), stream);
    csr_count<<<EPB, blk, 0, stream>>>(dst, counts);
    csr_scan<<<1, blk, 0, stream>>>(counts, offsets);
    csr_fill<<<EPB, blk, 0, stream>>>(src, dst, offsets, cursor, eidx);
    csr_sort<<<NPB, blk, 0, stream>>>(offsets, eidx);

    // ---------------- Layer 1 ----------------
    gemm_mfma<0,0><<<gnode, blk, 0, stream>>>(nfb, W1t, buf_m, nullptr, N_NODES, IN_FEATS, HID);
    edge_gather<<<NWAVE, blk, 0, stream>>>(buf_m, offsets, eidx, aggA);
    gemm_mfma<0,0><<<gnode, blk, 0, stream>>>(nfb, rW1t, buf_m, nullptr, N_NODES, IN_FEATS, HID);
    hipMemsetAsync(stats, 0, 2 * HID * sizeof(float), stream);
    combine_stats<<<256, blk, 0, stream>>>(aggA, buf_m, b1, rb1, aggA, stats);
    bn_finalize<<<1, HID, 0, stream>>>(stats, 1.0f / N_NODES);
    bn_apply_bf16<<<(N_NODES * HID / 4 + 255) / 256, blk, 0, stream>>>(aggA, stats, g1, be1, h1b);

    // ---------------- Layer 2 ----------------
    gemm_mfma<0,0><<<gnode, blk, 0, stream>>>(h1b, W2t, buf_m, nullptr, N_NODES, HID, HID);
    edge_gather<<<NWAVE, blk, 0, stream>>>(buf_m, offsets, eidx, aggA);
    gemm_mfma<0,0><<<gnode, blk, 0, stream>>>(h1b, rW2t, buf_m, nullptr, N_NODES, HID, HID);
    hipMemsetAsync(stats, 0, 2 * HID * sizeof(float), stream);
    combine_stats<<<256, blk, 0, stream>>>(aggA, buf_m, b2, rb2, aggA, stats);
    bn_finalize<<<1, HID, 0, stream>>>(stats, 1.0f / N_NODES);
    bn_apply<<<(N_NODES * HID / 4 + 255) / 256, blk, 0, stream>>>(aggA, stats, g2, be2);

    // ---------------- Readout ----------------
    node_weight<<<NWAVE, blk, 0, stream>>>(aggA, aw_W, aw_b, wbuf);
    readout<<<N_GRAPHS, HID, 0, stream>>>(aggA, wbuf, gid, zb);

    // ---------------- RDKit branch ----------------
    gemm_mfma<1,1><<<dim3(1024/128, 4), blk, 0, stream>>>(rdkb, rkW1t, rkhb, rk_b1, 512, 2048, 1024);
    gemm_mfma<1,1><<<dim3(512/128, 4), blk, 0, stream>>>(rkhb, rkW2t, zb + 512, rk_b2, 512, 1024, 1024);

    // ---------------- Combined head ----------------
    gemm_mfma<1,1><<<dim3(1024/128, 4), blk, 0, stream>>>(zb, cW1t, ch1b, c_b1, 512, 1024, 1024);
    gemm_mfma<1,0><<<dim3(512/128, 4), blk, 0, stream>>>(ch1b, cW2t, ch2, c_b2, 512, 1024, 512);
    final_dot<<<(N_GRAPHS * 64) / 256, blk, 0, stream>>>(ch2, c_W3, c_b3, out);
}

// Round 4
// 550.947 us; speedup vs baseline: 4.8447x; 1.1629x over previous
//
#include <hip/hip_runtime.h>
#include <hip/hip_bf16.h>
#include <cstdint>
#include <cstddef>

#define N_NODES 20000
#define N_EDGES 320000
#define N_GRAPHS 512
#define IN_FEATS 128
#define HID 256

typedef __bf16 bhalf;
typedef __bf16 bhalf8 __attribute__((ext_vector_type(8)));
typedef __bf16 bhalf4 __attribute__((ext_vector_type(4)));
typedef float f32x4 __attribute__((ext_vector_type(4)));

// ---------------------------------------------------------------------------
// bf16 MFMA GEMM: C[M,N] = A[M,K] @ B[K,N], A bf16 row-major [M,K],
// Bt bf16 row-major [N,K] (pre-transposed). fp32 accumulate.
// Tile 128x128, BK=64, 4 waves (2x2), 4x4 frags of 16x16x32 per wave.
// LDS XOR-swizzled. Requires K%64==0, N%128==0; M guarded.
// ---------------------------------------------------------------------------
template<int RELU, int OUTBF16>
__global__ __launch_bounds__(256) void gemm_mfma(const bhalf* __restrict__ A,
                                                 const bhalf* __restrict__ Bt,
                                                 void* __restrict__ Cv,
                                                 const float* __restrict__ bias,
                                                 int M, int K, int ldc)
{
    __shared__ bhalf As[128 * 64];
    __shared__ bhalf Bs[128 * 64];

    const int t = threadIdx.x;
    const int lane = t & 63, wid = t >> 6;
    const int wm0 = (wid >> 1) * 64, wn0 = (wid & 1) * 64;
    const int m0 = blockIdx.y * 128, n0 = blockIdx.x * 128;

    f32x4 acc[4][4] = {};

    const int srow = t >> 3;
    const int scol = (t & 7) << 3;

    for (int k0 = 0; k0 < K; k0 += 64) {
        __syncthreads();
#pragma unroll
        for (int i = 0; i < 4; ++i) {
            int row = srow + i * 32;
            int sc = scol ^ ((row & 7) << 3);
            uint4 va = make_uint4(0u, 0u, 0u, 0u);
            int gr = m0 + row;
            if (gr < M) va = *(const uint4*)(A + (size_t)gr * K + k0 + scol);
            *(uint4*)&As[row * 64 + sc] = va;
            uint4 vb = *(const uint4*)(Bt + (size_t)(n0 + row) * K + k0 + scol);
            *(uint4*)&Bs[row * 64 + sc] = vb;
        }
        __syncthreads();
#pragma unroll
        for (int kb = 0; kb < 2; ++kb) {
            const int kc = kb * 32 + (lane >> 4) * 8;
            bhalf8 af[4], bfr[4];
#pragma unroll
            for (int i = 0; i < 4; ++i) {
                int ra = wm0 + i * 16 + (lane & 15);
                af[i] = *(const bhalf8*)&As[ra * 64 + (kc ^ ((ra & 7) << 3))];
                int rb = wn0 + i * 16 + (lane & 15);
                bfr[i] = *(const bhalf8*)&Bs[rb * 64 + (kc ^ ((rb & 7) << 3))];
            }
#pragma unroll
            for (int mi = 0; mi < 4; ++mi)
#pragma unroll
                for (int ni = 0; ni < 4; ++ni)
                    acc[mi][ni] = __builtin_amdgcn_mfma_f32_16x16x32_bf16(
                        af[mi], bfr[ni], acc[mi][ni], 0, 0, 0);
        }
    }

#pragma unroll
    for (int mi = 0; mi < 4; ++mi)
#pragma unroll
        for (int ni = 0; ni < 4; ++ni) {
            int col = n0 + wn0 + ni * 16 + (lane & 15);
            float bb = bias ? bias[col] : 0.f;
            f32x4 v = acc[mi][ni];
#pragma unroll
            for (int r = 0; r < 4; ++r) {
                int row = m0 + wm0 + mi * 16 + (lane >> 4) * 4 + r;
                if (row < M) {
                    float x = v[r] + bb;
                    if (RELU) x = fmaxf(x, 0.f);
                    if (OUTBF16) ((bhalf*)Cv)[(size_t)row * ldc + col] = (bhalf)x;
                    else         ((float*)Cv)[(size_t)row * ldc + col] = x;
                }
            }
        }
}

// ---------------------------------------------------------------------------
// Batched weight transpose+convert: 8 tensors fp32 [K,N] -> bf16 [N,K].
// One 32x32 tile per block, table passed by value.
// ---------------------------------------------------------------------------
struct WEnt { const float* src; bhalf* dst; int K; int N; int tiles_end; };
struct WTab { WEnt e[8]; };

__global__ __launch_bounds__(256) void wconv_batch(WTab tab)
{
    __shared__ float tile[32][33];
    int tb = blockIdx.x;
    int idx = 0;
#pragma unroll
    for (int i = 0; i < 8; ++i)
        if (tb >= tab.e[i].tiles_end) idx = i + 1;
    const WEnt& E = tab.e[idx];
    int t0 = idx ? tab.e[idx - 1].tiles_end : 0;
    int lt = tb - t0;
    int tX = E.N >> 5;
    int bx = (lt % tX) << 5;   // N-dim
    int by = (lt / tX) << 5;   // K-dim
    int tx = threadIdx.x & 31, ty = threadIdx.x >> 5;  // 32 x 8
#pragma unroll
    for (int i = 0; i < 32; i += 8)
        tile[ty + i][tx] = E.src[(size_t)(by + ty + i) * E.N + bx + tx];
    __syncthreads();
#pragma unroll
    for (int i = 0; i < 32; i += 8)
        E.dst[(size_t)(bx + ty + i) * E.K + by + tx] = (bhalf)tile[tx][ty + i];
}

// two fp32->bf16 conversions in one launch (float4 granules)
__global__ void conv_batch(const float* __restrict__ a, bhalf* __restrict__ oa, int n4a,
                           const float* __restrict__ b, bhalf* __restrict__ ob, int n4b)
{
    int i = blockIdx.x * blockDim.x + threadIdx.x;
    const float* s; bhalf* d; int j;
    if (i < n4a) { s = a; d = oa; j = i; }
    else { j = i - n4a; if (j >= n4b) return; s = b; d = ob; }
    float4 v = ((const float4*)s)[j];
    bhalf4 o = {(bhalf)v.x, (bhalf)v.y, (bhalf)v.z, (bhalf)v.w};
    ((bhalf4*)d)[j] = o;
}

// ---------------------------------------------------------------------------
// CSR build: counts -> exclusive scan -> fill (atomic cursor) -> wave sort
// ---------------------------------------------------------------------------
__global__ void csr_count(const int* __restrict__ dst, int* __restrict__ counts)
{
    int e = blockIdx.x * blockDim.x + threadIdx.x;
    if (e >= N_EDGES) return;
    atomicAdd(&counts[dst[e]], 1);
}

__global__ __launch_bounds__(256) void csr_scan(const int* __restrict__ counts,
                                                int* __restrict__ offsets)
{
    __shared__ int partial[256];
    const int t = threadIdx.x;
    const int CH = (N_NODES + 255) / 256;
    const int base = t * CH;
    int s = 0;
    for (int i = 0; i < CH; ++i) {
        int idx = base + i;
        if (idx < N_NODES) s += counts[idx];
    }
    partial[t] = s;
    __syncthreads();
    if (t == 0) {
        int run = 0;
        for (int i = 0; i < 256; ++i) { int c = partial[i]; partial[i] = run; run += c; }
        offsets[N_NODES] = run;
    }
    __syncthreads();
    int run = partial[t];
    for (int i = 0; i < CH; ++i) {
        int idx = base + i;
        if (idx < N_NODES) { offsets[idx] = run; run += counts[idx]; }
    }
}

__global__ void csr_fill(const int* __restrict__ src, const int* __restrict__ dst,
                         const int* __restrict__ offsets, int* __restrict__ cursor,
                         int* __restrict__ eidx)
{
    int e = blockIdx.x * blockDim.x + threadIdx.x;
    if (e >= N_EDGES) return;
    int d = dst[e];
    int slot = offsets[d] + atomicAdd(&cursor[d], 1);
    eidx[slot] = src[e];
}

// wave-parallel rank sort per bucket (deterministic array content)
__global__ __launch_bounds__(256) void csr_sort_wave(const int* __restrict__ offsets,
                                                     int* __restrict__ eidx)
{
    int gidx = blockIdx.x * blockDim.x + threadIdx.x;
    int n = gidx >> 6, lane = gidx & 63;
    if (n >= N_NODES) return;
    int lo = offsets[n], hi = offsets[n + 1];
    int cnt = hi - lo;
    if (cnt <= 1) return;
    if (cnt <= 64) {
        int v = (lane < cnt) ? eidx[lo + lane] : 0x7fffffff;
        int rank = 0;
        for (int j = 0; j < cnt; ++j) {
            int vj = __shfl(v, j);
            if (vj < v || (vj == v && j < lane)) ++rank;
        }
        if (lane < cnt) eidx[lo + rank] = v;
    } else if (lane == 0) {  // statistically never at lambda=16
        for (int i = lo + 1; i < hi; ++i) {
            int v = eidx[i]; int j = i - 1;
            while (j >= lo && eidx[j] > v) { eidx[j + 1] = eidx[j]; --j; }
            eidx[j + 1] = v;
        }
    }
}

// ---------------------------------------------------------------------------
// Gather-aggregate: agg[n] = sum_{e in csr[n]} m[eidx[e]]. One wave per node.
// ---------------------------------------------------------------------------
__global__ __launch_bounds__(256) void edge_gather(const float* __restrict__ m,
                                                   const int* __restrict__ offsets,
                                                   const int* __restrict__ eidx,
                                                   float* __restrict__ agg)
{
    int gidx = blockIdx.x * blockDim.x + threadIdx.x;
    int n = gidx >> 6, lane = gidx & 63;
    if (n >= N_NODES) return;
    int lo = offsets[n], hi = offsets[n + 1];
    float4 acc = make_float4(0.f, 0.f, 0.f, 0.f);
    for (int i = lo; i < hi; ++i) {
        int s = eidx[i];
        float4 v = *(const float4*)(m + (size_t)s * HID + lane * 4);
        acc.x += v.x; acc.y += v.y; acc.z += v.z; acc.w += v.w;
    }
    *(float4*)(agg + (size_t)n * HID + lane * 4) = acc;
}

// ---------------------------------------------------------------------------
__global__ __launch_bounds__(256) void combine_stats(const float* __restrict__ agg_in,
                                                     const float* __restrict__ r,
                                                     const float* __restrict__ b,
                                                     const float* __restrict__ rb,
                                                     float* __restrict__ out,
                                                     float* __restrict__ stats)
{
    int col = threadIdx.x;
    float bb = b[col], rbb = rb[col];
    float s = 0.f, s2 = 0.f;
    for (int row = blockIdx.x; row < N_NODES; row += gridDim.x) {
        size_t idx = (size_t)row * HID + col;
        float v = fmaxf(agg_in[idx] + bb, 0.f) + fmaxf(r[idx] + rbb, 0.f);
        out[idx] = v;
        s += v;
        s2 += v * v;
    }
    atomicAdd(&stats[col], s);
    atomicAdd(&stats[HID + col], s2);
}

__global__ void bn_finalize(float* __restrict__ stats, float inv_n)
{
    int c = threadIdx.x;
    float mu = stats[c] * inv_n;
    float var = stats[HID + c] * inv_n - mu * mu;
    stats[2 * HID + c] = mu;
    stats[3 * HID + c] = rsqrtf(var + 1e-5f);
}

// ---------------------------------------------------------------------------
// Wave-per-node BN. MODE 0: write bf16 h (layer 1).
// MODE 1: write fp32 in-place + fused node attention weight (layer 2).
// ---------------------------------------------------------------------------
template<int MODE>
__global__ __launch_bounds__(256) void bn_row(const float* __restrict__ h,
                                              const float* __restrict__ stats,
                                              const float* __restrict__ g,
                                              const float* __restrict__ be,
                                              bhalf* __restrict__ outb,
                                              float* __restrict__ outf,
                                              const float* __restrict__ awW,
                                              const float* __restrict__ awb,
                                              float* __restrict__ w)
{
    int gidx = blockIdx.x * blockDim.x + threadIdx.x;
    int n = gidx >> 6, lane = gidx & 63;
    if (n >= N_NODES) return;
    int col = lane * 4;
    float4 v  = *(const float4*)(h + (size_t)n * HID + col);
    float4 mu = *(const float4*)(stats + 2 * HID + col);
    float4 rs = *(const float4*)(stats + 3 * HID + col);
    float4 gg = *(const float4*)(g + col);
    float4 bb = *(const float4*)(be + col);
    float4 o;
    o.x = gg.x * (v.x - mu.x) * rs.x + bb.x;
    o.y = gg.y * (v.y - mu.y) * rs.y + bb.y;
    o.z = gg.z * (v.z - mu.z) * rs.z + bb.z;
    o.w = gg.w * (v.w - mu.w) * rs.w + bb.w;
    if (MODE == 0) {
        bhalf4 ob = {(bhalf)o.x, (bhalf)o.y, (bhalf)o.z, (bhalf)o.w};
        *(bhalf4*)(outb + (size_t)n * HID + col) = ob;
    } else {
        *(float4*)(outf + (size_t)n * HID + col) = o;
        float4 wv = *(const float4*)(awW + col);
        float d = o.x * wv.x + o.y * wv.y + o.z * wv.z + o.w * wv.w;
#pragma unroll
        for (int off = 32; off > 0; off >>= 1) d += __shfl_xor(d, off);
        if (lane == 0) w[n] = 1.f / (1.f + expf(-(d + awb[0])));
    }
}

// ---------------------------------------------------------------------------
// writes bf16 graph features into z[g][0:512] = [sum(256) | max(256)]
__global__ __launch_bounds__(256) void readout(const float* __restrict__ h,
                                               const float* __restrict__ w,
                                               const int* __restrict__ gid,
                                               bhalf* __restrict__ z)
{
    int g = blockIdx.x, col = threadIdx.x;
    int lo = 0, hi = N_NODES;
    while (lo < hi) { int mid = (lo + hi) >> 1; if (gid[mid] < g) lo = mid + 1; else hi = mid; }
    int start = lo;
    hi = N_NODES;
    while (lo < hi) { int mid = (lo + hi) >> 1; if (gid[mid] <= g) lo = mid + 1; else hi = mid; }
    int end = lo;
    float s = 0.f, mx = -INFINITY;
    for (int n = start; n < end; ++n) {
        float v = h[(size_t)n * HID + col];
        s = fmaf(v, w[n], s);
        mx = fmaxf(mx, v);
    }
    z[(size_t)g * 1024 + col] = (bhalf)s;
    z[(size_t)g * 1024 + HID + col] = (bhalf)mx;
}

__global__ void final_dot(const float* __restrict__ x, const float* __restrict__ W,
                          const float* __restrict__ b, float* __restrict__ out)
{
    int gidx = blockIdx.x * blockDim.x + threadIdx.x;
    int rowi = gidx >> 6, lane = gidx & 63;
    if (rowi >= N_GRAPHS) return;
    const float4* xr = (const float4*)(x + (size_t)rowi * 512);
    const float4* wr = (const float4*)W;
    float acc = 0.f;
#pragma unroll
    for (int i = 0; i < 2; ++i) {
        float4 a = xr[lane * 2 + i];
        float4 ww = wr[lane * 2 + i];
        acc += a.x * ww.x + a.y * ww.y + a.z * ww.z + a.w * ww.w;
    }
#pragma unroll
    for (int off = 32; off > 0; off >>= 1) acc += __shfl_xor(acc, off);
    if (lane == 0) out[rowi] = acc + b[0];
}

// ---------------------------------------------------------------------------
extern "C" void kernel_launch(void* const* d_in, const int* in_sizes, int n_in,
                              void* d_out, int out_size, void* d_ws, size_t ws_size,
                              hipStream_t stream)
{
    (void)in_sizes; (void)n_in; (void)out_size; (void)ws_size;

    const float* node_feats = (const float*)d_in[0];
    const float* rdkit      = (const float*)d_in[1];
    const int*   src        = (const int*)d_in[2];
    const int*   dst        = (const int*)d_in[3];
    const int*   gid        = (const int*)d_in[4];
    const float* W1  = (const float*)d_in[5];
    const float* b1  = (const float*)d_in[6];
    const float* rW1 = (const float*)d_in[7];
    const float* rb1 = (const float*)d_in[8];
    const float* g1  = (const float*)d_in[9];
    const float* be1 = (const float*)d_in[10];
    const float* W2  = (const float*)d_in[11];
    const float* b2  = (const float*)d_in[12];
    const float* rW2 = (const float*)d_in[13];
    const float* rb2 = (const float*)d_in[14];
    const float* g2  = (const float*)d_in[15];
    const float* be2 = (const float*)d_in[16];
    const float* aw_W  = (const float*)d_in[17];
    const float* aw_b  = (const float*)d_in[18];
    const float* rk_W1 = (const float*)d_in[19];
    const float* rk_b1 = (const float*)d_in[20];
    const float* rk_W2 = (const float*)d_in[21];
    const float* rk_b2 = (const float*)d_in[22];
    const float* c_W1  = (const float*)d_in[23];
    const float* c_b1  = (const float*)d_in[24];
    const float* c_W2  = (const float*)d_in[25];
    const float* c_b2  = (const float*)d_in[26];
    const float* c_W3  = (const float*)d_in[27];
    const float* c_b3  = (const float*)d_in[28];

    float* out = (float*)d_out;

    const size_t NODE = (size_t)N_NODES * HID;  // 5,120,000
    float* buf_m = (float*)d_ws;           // [20000,256] fp32 GEMM scratch
    float* aggA  = buf_m + NODE;           // agg / h (fp32)
    bhalf* h1b   = (bhalf*)(aggA + NODE);  // 5,120,000 bf16 (nfb aliases front)
    bhalf* nfb   = h1b;                    // [20000,128] bf16
    bhalf* W1t   = h1b + NODE;             // weights (transposed bf16)
    bhalf* rW1t  = W1t + 128 * 256;
    bhalf* W2t   = rW1t + 128 * 256;
    bhalf* rW2t  = W2t + 256 * 256;
    bhalf* rkW1t = rW2t + 256 * 256;
    bhalf* rkW2t = rkW1t + 2048 * 1024;
    bhalf* cW1t  = rkW2t + 1024 * 512;
    bhalf* cW2t  = cW1t + 1024 * 1024;
    bhalf* rdkb  = cW2t + 1024 * 512;      // [512,2048] bf16
    float* stats = (float*)(rdkb + 512 * 2048);  // 1024
    float* wbuf  = stats + 1024;           // 20000
    int*   counts  = (int*)(wbuf + N_NODES);
    int*   offsets = counts + N_NODES;     // N+1
    int*   cursor  = offsets + N_NODES + 1;
    int*   eidx    = cursor + N_NODES;     // N_EDGES
    // head buffers alias buf_m (free after layer-2 combine)
    bhalf* rkhb = (bhalf*)buf_m;           // [512,1024] bf16
    bhalf* zb   = rkhb + 512 * 1024;       // [512,1024] bf16
    bhalf* ch1b = zb + 512 * 1024;         // [512,1024] bf16
    float* ch2  = (float*)(ch1b + 512 * 1024);  // [512,512] fp32

    dim3 blk(256);
    const int EPB = (N_EDGES + 255) / 256;
    const int NWAVE = (N_NODES * 64) / 256;   // 5000 blocks, wave per node
    dim3 gnode(HID / 128, (N_NODES + 127) / 128);  // (2, 157)

    // ---------------- weight/input conversion (2 launches) ----------------
    WTab tab;
    tab.e[0] = {W1,    W1t,   128, 256,   32};
    tab.e[1] = {rW1,   rW1t,  128, 256,   64};
    tab.e[2] = {W2,    W2t,   256, 256,  128};
    tab.e[3] = {rW2,   rW2t,  256, 256,  192};
    tab.e[4] = {rk_W1, rkW1t, 2048, 1024, 2240};
    tab.e[5] = {rk_W2, rkW2t, 1024, 512, 2752};
    tab.e[6] = {c_W1,  cW1t,  1024, 1024, 3776};
    tab.e[7] = {c_W2,  cW2t,  1024, 512, 4288};
    wconv_batch<<<4288, blk, 0, stream>>>(tab);
    {
        int n4a = N_NODES * IN_FEATS / 4, n4b = 512 * 2048 / 4;
        conv_batch<<<(n4a + n4b + 255) / 256, blk, 0, stream>>>(node_feats, nfb, n4a,
                                                                rdkit, rdkb, n4b);
    }

    // ---------------- CSR build ----------------
    hipMemsetAsync(counts, 0, N_NODES * sizeof(int), stream);
    hipMemsetAsync(cursor, 0, N_NODES * sizeof(int), stream);
    csr_count<<<EPB, blk, 0, stream>>>(dst, counts);
    csr_scan<<<1, blk, 0, stream>>>(counts, offsets);
    csr_fill<<<EPB, blk, 0, stream>>>(src, dst, offsets, cursor, eidx);
    csr_sort_wave<<<NWAVE, blk, 0, stream>>>(offsets, eidx);

    // ---------------- Layer 1 ----------------
    gemm_mfma<0,0><<<gnode, blk, 0, stream>>>(nfb, W1t, buf_m, nullptr, N_NODES, IN_FEATS, HID);
    edge_gather<<<NWAVE, blk, 0, stream>>>(buf_m, offsets, eidx, aggA);
    gemm_mfma<0,0><<<gnode, blk, 0, stream>>>(nfb, rW1t, buf_m, nullptr, N_NODES, IN_FEATS, HID);
    hipMemsetAsync(stats, 0, 2 * HID * sizeof(float), stream);
    combine_stats<<<512, blk, 0, stream>>>(aggA, buf_m, b1, rb1, aggA, stats);
    bn_finalize<<<1, HID, 0, stream>>>(stats, 1.0f / N_NODES);
    bn_row<0><<<NWAVE, blk, 0, stream>>>(aggA, stats, g1, be1, h1b, nullptr, nullptr, nullptr, nullptr);

    // ---------------- Layer 2 ----------------
    gemm_mfma<0,0><<<gnode, blk, 0, stream>>>(h1b, W2t, buf_m, nullptr, N_NODES, HID, HID);
    edge_gather<<<NWAVE, blk, 0, stream>>>(buf_m, offsets, eidx, aggA);
    gemm_mfma<0,0><<<gnode, blk, 0, stream>>>(h1b, rW2t, buf_m, nullptr, N_NODES, HID, HID);
    hipMemsetAsync(stats, 0, 2 * HID * sizeof(float), stream);
    combine_stats<<<512, blk, 0, stream>>>(aggA, buf_m, b2, rb2, aggA, stats);
    bn_finalize<<<1, HID, 0, stream>>>(stats, 1.0f / N_NODES);
    bn_row<1><<<NWAVE, blk, 0, stream>>>(aggA, stats, g2, be2, nullptr, aggA, aw_W, aw_b, wbuf);

    // ---------------- Readout ----------------
    readout<<<N_GRAPHS, HID, 0, stream>>>(aggA, wbuf, gid, zb);

    // ---------------- RDKit branch ----------------
    gemm_mfma<1,1><<<dim3(1024/128, 4), blk, 0, stream>>>(rdkb, rkW1t, rkhb, rk_b1, 512, 2048, 1024);
    gemm_mfma<1,1><<<dim3(512/128, 4), blk, 0, stream>>>(rkhb, rkW2t, zb + 512, rk_b2, 512, 1024, 1024);

    // ---------------- Combined head ----------------
    gemm_mfma<1,1><<<dim3(1024/128, 4), blk, 0, stream>>>(zb, cW1t, ch1b, c_b1, 512, 1024, 1024);
    gemm_mfma<1,0><<<dim3(512/128, 4), blk, 0, stream>>>(ch1b, cW2t, ch2, c_b2, 512, 1024, 512);
    final_dot<<<(N_GRAPHS * 64) / 256, blk, 0, stream>>>(ch2, c_W3, c_b3, out);
}

// Round 5
// 396.761 us; speedup vs baseline: 6.7274x; 1.3886x over previous
//
#include <hip/hip_runtime.h>
#include <hip/hip_bf16.h>
#include <cstdint>
#include <cstddef>

#define N_NODES 20000
#define N_EDGES 320000
#define N_GRAPHS 512
#define IN_FEATS 128
#define HID 256

typedef __bf16 bhalf;
typedef __bf16 bhalf8 __attribute__((ext_vector_type(8)));
typedef __bf16 bhalf4 __attribute__((ext_vector_type(4)));
typedef float f32x4 __attribute__((ext_vector_type(4)));

// ---------------------------------------------------------------------------
// bf16 MFMA GEMM, latency-tolerant small-tile version.
// C[M,N] = A[M,K] @ Bt[N,K]^T. Tile 64x64, BK=64, 4 waves (2x2), each wave
// 32x32 via 2x2 frags of 16x16x32. Register-prefetch pipeline: next tile's
// global loads are issued before the MFMA cluster of the current tile.
// LDS XOR-swizzled ( col ^ ((row&7)<<3) in bf16 units ). K%64==0, N%64==0.
// ---------------------------------------------------------------------------
template<int RELU, int OUTBF16>
__global__ __launch_bounds__(256) void gemm_mfma(const bhalf* __restrict__ A,
                                                 const bhalf* __restrict__ Bt,
                                                 void* __restrict__ Cv,
                                                 const float* __restrict__ bias,
                                                 int M, int K, int ldc)
{
    __shared__ bhalf As[64 * 64];
    __shared__ bhalf Bs[64 * 64];

    const int t = threadIdx.x;
    const int lane = t & 63, wid = t >> 6;
    const int wm0 = (wid >> 1) * 32, wn0 = (wid & 1) * 32;
    const int m0 = blockIdx.y * 64, n0 = blockIdx.x * 64;

    const int srow = t >> 2;           // 0..63
    const int sc0 = (t & 3) << 3;      // bf16 col 0,8,16,24

    f32x4 acc[2][2] = {};
    uint4 ra0, ra1, rb0, rb1;

    const bool mok = (m0 + srow) < M;
    const bhalf* Abase = A + (size_t)(m0 + srow) * K;
    const bhalf* Bbase = Bt + (size_t)(n0 + srow) * K;

    // prefetch tile 0
    {
        ra0 = mok ? *(const uint4*)(Abase + sc0)      : make_uint4(0u,0u,0u,0u);
        ra1 = mok ? *(const uint4*)(Abase + sc0 + 32) : make_uint4(0u,0u,0u,0u);
        rb0 = *(const uint4*)(Bbase + sc0);
        rb1 = *(const uint4*)(Bbase + sc0 + 32);
    }

    const int swz = (srow & 7) << 3;
    for (int k0 = 0; k0 < K; k0 += 64) {
        __syncthreads();   // previous iteration's LDS reads complete
        *(uint4*)&As[srow * 64 + (sc0 ^ swz)]        = ra0;
        *(uint4*)&As[srow * 64 + ((sc0 + 32) ^ swz)] = ra1;
        *(uint4*)&Bs[srow * 64 + (sc0 ^ swz)]        = rb0;
        *(uint4*)&Bs[srow * 64 + ((sc0 + 32) ^ swz)] = rb1;
        __syncthreads();
        if (k0 + 64 < K) {   // issue next tile's loads; in flight during MFMA
            const bhalf* An = Abase + k0 + 64;
            const bhalf* Bn = Bbase + k0 + 64;
            ra0 = mok ? *(const uint4*)(An + sc0)      : make_uint4(0u,0u,0u,0u);
            ra1 = mok ? *(const uint4*)(An + sc0 + 32) : make_uint4(0u,0u,0u,0u);
            rb0 = *(const uint4*)(Bn + sc0);
            rb1 = *(const uint4*)(Bn + sc0 + 32);
        }
#pragma unroll
        for (int kb = 0; kb < 2; ++kb) {
            const int kc = kb * 32 + (lane >> 4) * 8;
            bhalf8 af[2], bfr[2];
#pragma unroll
            for (int i = 0; i < 2; ++i) {
                int rA = wm0 + i * 16 + (lane & 15);
                af[i] = *(const bhalf8*)&As[rA * 64 + (kc ^ ((rA & 7) << 3))];
                int rB = wn0 + i * 16 + (lane & 15);
                bfr[i] = *(const bhalf8*)&Bs[rB * 64 + (kc ^ ((rB & 7) << 3))];
            }
#pragma unroll
            for (int mi = 0; mi < 2; ++mi)
#pragma unroll
                for (int ni = 0; ni < 2; ++ni)
                    acc[mi][ni] = __builtin_amdgcn_mfma_f32_16x16x32_bf16(
                        af[mi], bfr[ni], acc[mi][ni], 0, 0, 0);
        }
    }

#pragma unroll
    for (int mi = 0; mi < 2; ++mi)
#pragma unroll
        for (int ni = 0; ni < 2; ++ni) {
            int col = n0 + wn0 + ni * 16 + (lane & 15);
            float bb = bias ? bias[col] : 0.f;
            f32x4 v = acc[mi][ni];
#pragma unroll
            for (int r = 0; r < 4; ++r) {
                int row = m0 + wm0 + mi * 16 + (lane >> 4) * 4 + r;
                if (row < M) {
                    float x = v[r] + bb;
                    if (RELU) x = fmaxf(x, 0.f);
                    if (OUTBF16) ((bhalf*)Cv)[(size_t)row * ldc + col] = (bhalf)x;
                    else         ((float*)Cv)[(size_t)row * ldc + col] = x;
                }
            }
        }
}

// ---------------------------------------------------------------------------
// Batched weight transpose+convert: 8 tensors fp32 [K,N] -> bf16 [N,K].
// ---------------------------------------------------------------------------
struct WEnt { const float* src; bhalf* dst; int K; int N; int tiles_end; };
struct WTab { WEnt e[8]; };

__global__ __launch_bounds__(256) void wconv_batch(WTab tab)
{
    __shared__ float tile[32][33];
    int tb = blockIdx.x;
    int idx = 0;
#pragma unroll
    for (int i = 0; i < 8; ++i)
        if (tb >= tab.e[i].tiles_end) idx = i + 1;
    const WEnt& E = tab.e[idx];
    int t0 = idx ? tab.e[idx - 1].tiles_end : 0;
    int lt = tb - t0;
    int tX = E.N >> 5;
    int bx = (lt % tX) << 5;
    int by = (lt / tX) << 5;
    int tx = threadIdx.x & 31, ty = threadIdx.x >> 5;
#pragma unroll
    for (int i = 0; i < 32; i += 8)
        tile[ty + i][tx] = E.src[(size_t)(by + ty + i) * E.N + bx + tx];
    __syncthreads();
#pragma unroll
    for (int i = 0; i < 32; i += 8)
        E.dst[(size_t)(bx + ty + i) * E.K + by + tx] = (bhalf)tile[tx][ty + i];
}

__global__ void conv_batch(const float* __restrict__ a, bhalf* __restrict__ oa, int n4a,
                           const float* __restrict__ b, bhalf* __restrict__ ob, int n4b)
{
    int i = blockIdx.x * blockDim.x + threadIdx.x;
    const float* s; bhalf* d; int j;
    if (i < n4a) { s = a; d = oa; j = i; }
    else { j = i - n4a; if (j >= n4b) return; s = b; d = ob; }
    float4 v = ((const float4*)s)[j];
    bhalf4 o = {(bhalf)v.x, (bhalf)v.y, (bhalf)v.z, (bhalf)v.w};
    ((bhalf4*)d)[j] = o;
}

// ---------------------------------------------------------------------------
// CSR build
// ---------------------------------------------------------------------------
__global__ void csr_count(const int* __restrict__ dst, int* __restrict__ counts)
{
    int e = blockIdx.x * blockDim.x + threadIdx.x;
    if (e >= N_EDGES) return;
    atomicAdd(&counts[dst[e]], 1);
}

__global__ __launch_bounds__(256) void csr_scan(const int* __restrict__ counts,
                                                int* __restrict__ offsets)
{
    __shared__ int partial[256];
    const int t = threadIdx.x;
    const int CH = (N_NODES + 255) / 256;
    const int base = t * CH;
    int s = 0;
    for (int i = 0; i < CH; ++i) {
        int idx = base + i;
        if (idx < N_NODES) s += counts[idx];
    }
    partial[t] = s;
    __syncthreads();
    if (t == 0) {
        int run = 0;
        for (int i = 0; i < 256; ++i) { int c = partial[i]; partial[i] = run; run += c; }
        offsets[N_NODES] = run;
    }
    __syncthreads();
    int run = partial[t];
    for (int i = 0; i < CH; ++i) {
        int idx = base + i;
        if (idx < N_NODES) { offsets[idx] = run; run += counts[idx]; }
    }
}

__global__ void csr_fill(const int* __restrict__ src, const int* __restrict__ dst,
                         const int* __restrict__ offsets, int* __restrict__ cursor,
                         int* __restrict__ eidx)
{
    int e = blockIdx.x * blockDim.x + threadIdx.x;
    if (e >= N_EDGES) return;
    int d = dst[e];
    int slot = offsets[d] + atomicAdd(&cursor[d], 1);
    eidx[slot] = src[e];
}

__global__ void csr_sort_wave(const int* __restrict__ offsets, int* __restrict__ eidx)
{
    int gidx = blockIdx.x * blockDim.x + threadIdx.x;
    int n = gidx >> 6, lane = gidx & 63;
    if (n >= N_NODES) return;
    int lo = offsets[n], hi = offsets[n + 1];
    int cnt = hi - lo;
    if (cnt <= 1) return;
    if (cnt <= 64) {
        int v = (lane < cnt) ? eidx[lo + lane] : 0x7fffffff;
        int rank = 0;
        for (int j = 0; j < cnt; ++j) {
            int vj = __shfl(v, j);
            if (vj < v || (vj == v && j < lane)) ++rank;
        }
        if (lane < cnt) eidx[lo + rank] = v;
    } else if (lane == 0) {
        for (int i = lo + 1; i < hi; ++i) {
            int v = eidx[i]; int j = i - 1;
            while (j >= lo && eidx[j] > v) { eidx[j + 1] = eidx[j]; --j; }
            eidx[j + 1] = v;
        }
    }
}

// ---------------------------------------------------------------------------
// Gather-aggregate with leading-dim: agg[n] = sum m[eidx[e]*ldm .. +256)
// ---------------------------------------------------------------------------
__global__ __launch_bounds__(256) void edge_gather(const float* __restrict__ m, int ldm,
                                                   const int* __restrict__ offsets,
                                                   const int* __restrict__ eidx,
                                                   float* __restrict__ agg)
{
    int gidx = blockIdx.x * blockDim.x + threadIdx.x;
    int n = gidx >> 6, lane = gidx & 63;
    if (n >= N_NODES) return;
    int lo = offsets[n], hi = offsets[n + 1];
    float4 acc = make_float4(0.f, 0.f, 0.f, 0.f);
    for (int i = lo; i < hi; ++i) {
        int s = eidx[i];
        float4 v = *(const float4*)(m + (size_t)s * ldm + lane * 4);
        acc.x += v.x; acc.y += v.y; acc.z += v.z; acc.w += v.w;
    }
    *(float4*)(agg + (size_t)n * HID + lane * 4) = acc;
}

// ---------------------------------------------------------------------------
__global__ __launch_bounds__(256) void combine_stats(const float* __restrict__ agg_in,
                                                     const float* __restrict__ r, int ldr,
                                                     const float* __restrict__ b,
                                                     const float* __restrict__ rb,
                                                     float* __restrict__ out,
                                                     float* __restrict__ stats)
{
    int col = threadIdx.x;
    float bb = b[col], rbb = rb[col];
    float s = 0.f, s2 = 0.f;
    for (int row = blockIdx.x; row < N_NODES; row += gridDim.x) {
        float v = fmaxf(agg_in[(size_t)row * HID + col] + bb, 0.f)
                + fmaxf(r[(size_t)row * ldr + col] + rbb, 0.f);
        out[(size_t)row * HID + col] = v;
        s += v;
        s2 += v * v;
    }
    atomicAdd(&stats[col], s);
    atomicAdd(&stats[HID + col], s2);
}

__global__ void bn_finalize(float* __restrict__ stats, float inv_n)
{
    int c = threadIdx.x;
    float mu = stats[c] * inv_n;
    float var = stats[HID + c] * inv_n - mu * mu;
    stats[2 * HID + c] = mu;
    stats[3 * HID + c] = rsqrtf(var + 1e-5f);
}

// ---------------------------------------------------------------------------
template<int MODE>
__global__ __launch_bounds__(256) void bn_row(const float* __restrict__ h,
                                              const float* __restrict__ stats,
                                              const float* __restrict__ g,
                                              const float* __restrict__ be,
                                              bhalf* __restrict__ outb,
                                              float* __restrict__ outf,
                                              const float* __restrict__ awW,
                                              const float* __restrict__ awb,
                                              float* __restrict__ w)
{
    int gidx = blockIdx.x * blockDim.x + threadIdx.x;
    int n = gidx >> 6, lane = gidx & 63;
    if (n >= N_NODES) return;
    int col = lane * 4;
    float4 v  = *(const float4*)(h + (size_t)n * HID + col);
    float4 mu = *(const float4*)(stats + 2 * HID + col);
    float4 rs = *(const float4*)(stats + 3 * HID + col);
    float4 gg = *(const float4*)(g + col);
    float4 bb = *(const float4*)(be + col);
    float4 o;
    o.x = gg.x * (v.x - mu.x) * rs.x + bb.x;
    o.y = gg.y * (v.y - mu.y) * rs.y + bb.y;
    o.z = gg.z * (v.z - mu.z) * rs.z + bb.z;
    o.w = gg.w * (v.w - mu.w) * rs.w + bb.w;
    if (MODE == 0) {
        bhalf4 ob = {(bhalf)o.x, (bhalf)o.y, (bhalf)o.z, (bhalf)o.w};
        *(bhalf4*)(outb + (size_t)n * HID + col) = ob;
    } else {
        *(float4*)(outf + (size_t)n * HID + col) = o;
        float4 wv = *(const float4*)(awW + col);
        float d = o.x * wv.x + o.y * wv.y + o.z * wv.z + o.w * wv.w;
#pragma unroll
        for (int off = 32; off > 0; off >>= 1) d += __shfl_xor(d, off);
        if (lane == 0) w[n] = 1.f / (1.f + expf(-(d + awb[0])));
    }
}

// ---------------------------------------------------------------------------
__global__ __launch_bounds__(256) void readout(const float* __restrict__ h,
                                               const float* __restrict__ w,
                                               const int* __restrict__ gid,
                                               bhalf* __restrict__ z)
{
    int g = blockIdx.x, col = threadIdx.x;
    int lo = 0, hi = N_NODES;
    while (lo < hi) { int mid = (lo + hi) >> 1; if (gid[mid] < g) lo = mid + 1; else hi = mid; }
    int start = lo;
    hi = N_NODES;
    while (lo < hi) { int mid = (lo + hi) >> 1; if (gid[mid] <= g) lo = mid + 1; else hi = mid; }
    int end = lo;
    float s = 0.f, mx = -INFINITY;
    for (int n = start; n < end; ++n) {
        float v = h[(size_t)n * HID + col];
        s = fmaf(v, w[n], s);
        mx = fmaxf(mx, v);
    }
    z[(size_t)g * 1024 + col] = (bhalf)s;
    z[(size_t)g * 1024 + HID + col] = (bhalf)mx;
}

__global__ void final_dot(const float* __restrict__ x, const float* __restrict__ W,
                          const float* __restrict__ b, float* __restrict__ out)
{
    int gidx = blockIdx.x * blockDim.x + threadIdx.x;
    int rowi = gidx >> 6, lane = gidx & 63;
    if (rowi >= N_GRAPHS) return;
    const float4* xr = (const float4*)(x + (size_t)rowi * 512);
    const float4* wr = (const float4*)W;
    float acc = 0.f;
#pragma unroll
    for (int i = 0; i < 2; ++i) {
        float4 a = xr[lane * 2 + i];
        float4 ww = wr[lane * 2 + i];
        acc += a.x * ww.x + a.y * ww.y + a.z * ww.z + a.w * ww.w;
    }
#pragma unroll
    for (int off = 32; off > 0; off >>= 1) acc += __shfl_xor(acc, off);
    if (lane == 0) out[rowi] = acc + b[0];
}

// ---------------------------------------------------------------------------
extern "C" void kernel_launch(void* const* d_in, const int* in_sizes, int n_in,
                              void* d_out, int out_size, void* d_ws, size_t ws_size,
                              hipStream_t stream)
{
    (void)in_sizes; (void)n_in; (void)out_size; (void)ws_size;

    const float* node_feats = (const float*)d_in[0];
    const float* rdkit      = (const float*)d_in[1];
    const int*   src        = (const int*)d_in[2];
    const int*   dst        = (const int*)d_in[3];
    const int*   gid        = (const int*)d_in[4];
    const float* W1  = (const float*)d_in[5];
    const float* b1  = (const float*)d_in[6];
    const float* rW1 = (const float*)d_in[7];
    const float* rb1 = (const float*)d_in[8];
    const float* g1  = (const float*)d_in[9];
    const float* be1 = (const float*)d_in[10];
    const float* W2  = (const float*)d_in[11];
    const float* b2  = (const float*)d_in[12];
    const float* rW2 = (const float*)d_in[13];
    const float* rb2 = (const float*)d_in[14];
    const float* g2  = (const float*)d_in[15];
    const float* be2 = (const float*)d_in[16];
    const float* aw_W  = (const float*)d_in[17];
    const float* aw_b  = (const float*)d_in[18];
    const float* rk_W1 = (const float*)d_in[19];
    const float* rk_b1 = (const float*)d_in[20];
    const float* rk_W2 = (const float*)d_in[21];
    const float* rk_b2 = (const float*)d_in[22];
    const float* c_W1  = (const float*)d_in[23];
    const float* c_b1  = (const float*)d_in[24];
    const float* c_W2  = (const float*)d_in[25];
    const float* c_b2  = (const float*)d_in[26];
    const float* c_W3  = (const float*)d_in[27];
    const float* c_b3  = (const float*)d_in[28];

    float* out = (float*)d_out;

    const size_t NODE = (size_t)N_NODES * HID;       // 5,120,000
    float* buf_mr = (float*)d_ws;                    // [20000,512] fp32: m | r
    float* aggA   = buf_mr + (size_t)N_NODES * 512;  // [20000,256] fp32
    bhalf* h1b    = (bhalf*)(aggA + NODE);           // [20000,256] bf16 (nfb aliases)
    bhalf* nfb    = h1b;                             // [20000,128] bf16
    bhalf* W1cat  = h1b + NODE;                      // [512,128]  = W1^T | rW1^T
    bhalf* W2cat  = W1cat + 512 * 128;               // [512,256]  = W2^T | rW2^T
    bhalf* rkW1t  = W2cat + 512 * 256;               // [1024,2048]
    bhalf* rkW2t  = rkW1t + 2048 * 1024;             // [512,1024]
    bhalf* cW1t   = rkW2t + 1024 * 512;              // [1024,1024]
    bhalf* cW2t   = cW1t + 1024 * 1024;              // [512,1024]
    bhalf* rdkb   = cW2t + 1024 * 512;               // [512,2048]
    float* stats  = (float*)(rdkb + 512 * 2048);     // 1024
    float* wbuf   = stats + 1024;                    // 20000
    int*   counts  = (int*)(wbuf + N_NODES);
    int*   offsets = counts + N_NODES;               // N+1
    int*   cursor  = offsets + N_NODES + 1;
    int*   eidx    = cursor + N_NODES;               // N_EDGES
    // head buffers alias buf_mr (free after layer-2 combine)
    bhalf* rkhb = (bhalf*)buf_mr;                    // [512,1024] bf16
    bhalf* zb   = rkhb + 512 * 1024;                 // [512,1024] bf16
    bhalf* ch1b = zb + 512 * 1024;                   // [512,1024] bf16
    float* ch2  = (float*)(ch1b + 512 * 1024);       // [512,512] fp32

    dim3 blk(256);
    const int EPB = (N_EDGES + 255) / 256;
    const int NWAVE = (N_NODES * 64) / 256;          // wave per node
    dim3 g1grid(512 / 64, (N_NODES + 63) / 64);      // (8, 313) fused W|rW
    dim3 g2grid(512 / 64, (N_NODES + 63) / 64);

    // ---------------- weight/input conversion (2 launches) ----------------
    WTab tab;
    tab.e[0] = {W1,    W1cat,             128, 256,   32};
    tab.e[1] = {rW1,   W1cat + 256 * 128, 128, 256,   64};
    tab.e[2] = {W2,    W2cat,             256, 256,  128};
    tab.e[3] = {rW2,   W2cat + 256 * 256, 256, 256,  192};
    tab.e[4] = {rk_W1, rkW1t,            2048, 1024, 2240};
    tab.e[5] = {rk_W2, rkW2t,            1024, 512,  2752};
    tab.e[6] = {c_W1,  cW1t,             1024, 1024, 3776};
    tab.e[7] = {c_W2,  cW2t,             1024, 512,  4288};
    wconv_batch<<<4288, blk, 0, stream>>>(tab);
    {
        int n4a = N_NODES * IN_FEATS / 4, n4b = 512 * 2048 / 4;
        conv_batch<<<(n4a + n4b + 255) / 256, blk, 0, stream>>>(node_feats, nfb, n4a,
                                                                rdkit, rdkb, n4b);
    }

    // ---------------- CSR build ----------------
    hipMemsetAsync(counts, 0, N_NODES * sizeof(int), stream);
    hipMemsetAsync(cursor, 0, N_NODES * sizeof(int), stream);
    csr_count<<<EPB, blk, 0, stream>>>(dst, counts);
    csr_scan<<<1, blk, 0, stream>>>(counts, offsets);
    csr_fill<<<EPB, blk, 0, stream>>>(src, dst, offsets, cursor, eidx);
    csr_sort_wave<<<NWAVE, blk, 0, stream>>>(offsets, eidx);

    // ---------------- Layer 1 (fused m|r GEMM) ----------------
    gemm_mfma<0,0><<<g1grid, blk, 0, stream>>>(nfb, W1cat, buf_mr, nullptr,
                                               N_NODES, IN_FEATS, 512);
    edge_gather<<<NWAVE, blk, 0, stream>>>(buf_mr, 512, offsets, eidx, aggA);
    hipMemsetAsync(stats, 0, 2 * HID * sizeof(float), stream);
    combine_stats<<<512, blk, 0, stream>>>(aggA, buf_mr + 256, 512, b1, rb1, aggA, stats);
    bn_finalize<<<1, HID, 0, stream>>>(stats, 1.0f / N_NODES);
    bn_row<0><<<NWAVE, blk, 0, stream>>>(aggA, stats, g1, be1, h1b, nullptr, nullptr, nullptr, nullptr);

    // ---------------- Layer 2 (fused m|r GEMM) ----------------
    gemm_mfma<0,0><<<g2grid, blk, 0, stream>>>(h1b, W2cat, buf_mr, nullptr,
                                               N_NODES, HID, 512);
    edge_gather<<<NWAVE, blk, 0, stream>>>(buf_mr, 512, offsets, eidx, aggA);
    hipMemsetAsync(stats, 0, 2 * HID * sizeof(float), stream);
    combine_stats<<<512, blk, 0, stream>>>(aggA, buf_mr + 256, 512, b2, rb2, aggA, stats);
    bn_finalize<<<1, HID, 0, stream>>>(stats, 1.0f / N_NODES);
    bn_row<1><<<NWAVE, blk, 0, stream>>>(aggA, stats, g2, be2, nullptr, aggA, aw_W, aw_b, wbuf);

    // ---------------- Readout ----------------
    readout<<<N_GRAPHS, HID, 0, stream>>>(aggA, wbuf, gid, zb);

    // ---------------- RDKit branch ----------------
    gemm_mfma<1,1><<<dim3(1024/64, 8), blk, 0, stream>>>(rdkb, rkW1t, rkhb, rk_b1, 512, 2048, 1024);
    gemm_mfma<1,1><<<dim3(512/64, 8), blk, 0, stream>>>(rkhb, rkW2t, zb + 512, rk_b2, 512, 1024, 1024);

    // ---------------- Combined head ----------------
    gemm_mfma<1,1><<<dim3(1024/64, 8), blk, 0, stream>>>(zb, cW1t, ch1b, c_b1, 512, 1024, 1024);
    gemm_mfma<1,0><<<dim3(512/64, 8), blk, 0, stream>>>(ch1b, cW2t, ch2, c_b2, 512, 1024, 512);
    final_dot<<<(N_GRAPHS * 64) / 256, blk, 0, stream>>>(ch2, c_W3, c_b3, out);
}

// Round 6
// 351.514 us; speedup vs baseline: 7.5934x; 1.1287x over previous
//
#include <hip/hip_runtime.h>
#include <hip/hip_bf16.h>
#include <cstdint>
#include <cstddef>

#define N_NODES 20000
#define N_EDGES 320000
#define N_GRAPHS 512
#define IN_FEATS 128
#define HID 256

typedef __bf16 bhalf;
typedef __bf16 bhalf8 __attribute__((ext_vector_type(8)));
typedef __bf16 bhalf4 __attribute__((ext_vector_type(4)));
typedef float f32x4 __attribute__((ext_vector_type(4)));

// ---------------------------------------------------------------------------
// bf16 MFMA GEMM: C[M,N] = A[M,K] @ Bt[N,K]^T. Tile 64x64, BK=64, 4 waves
// (2x2), wave = 32x32 via 2x2 frags of 16x16x32. Register-prefetch pipeline.
// LDS XOR-swizzled. K%(64*gridDim.z)==0, N%64==0; M guarded.
// gridDim.z > 1 => split-K: each z-slice writes an fp32 partial
// Cpart[(z*M+row)*ldc+col] (no bias/relu); combine in splitk_combine.
// ---------------------------------------------------------------------------
template<int RELU, int OUTBF16>
__global__ __launch_bounds__(256) void gemm_mfma(const bhalf* __restrict__ A,
                                                 const bhalf* __restrict__ Bt,
                                                 void* __restrict__ Cv,
                                                 const float* __restrict__ bias,
                                                 int M, int K, int ldc)
{
    __shared__ bhalf As[64 * 64];
    __shared__ bhalf Bs[64 * 64];

    const int t = threadIdx.x;
    const int lane = t & 63, wid = t >> 6;
    const int wm0 = (wid >> 1) * 32, wn0 = (wid & 1) * 32;
    const int m0 = blockIdx.y * 64, n0 = blockIdx.x * 64;
    const int S = gridDim.z, kz = blockIdx.z;
    const int Ks = K / S;

    const int srow = t >> 2;           // 0..63
    const int sc0 = (t & 3) << 3;      // bf16 col 0,8,16,24

    f32x4 acc[2][2] = {};
    uint4 ra0, ra1, rb0, rb1;

    const bool mok = (m0 + srow) < M;
    const bhalf* Abase = A + (size_t)(m0 + srow) * K + (size_t)kz * Ks;
    const bhalf* Bbase = Bt + (size_t)(n0 + srow) * K + (size_t)kz * Ks;

    // prefetch tile 0
    ra0 = mok ? *(const uint4*)(Abase + sc0)      : make_uint4(0u,0u,0u,0u);
    ra1 = mok ? *(const uint4*)(Abase + sc0 + 32) : make_uint4(0u,0u,0u,0u);
    rb0 = *(const uint4*)(Bbase + sc0);
    rb1 = *(const uint4*)(Bbase + sc0 + 32);

    const int swz = (srow & 7) << 3;
    for (int k0 = 0; k0 < Ks; k0 += 64) {
        __syncthreads();
        *(uint4*)&As[srow * 64 + (sc0 ^ swz)]        = ra0;
        *(uint4*)&As[srow * 64 + ((sc0 + 32) ^ swz)] = ra1;
        *(uint4*)&Bs[srow * 64 + (sc0 ^ swz)]        = rb0;
        *(uint4*)&Bs[srow * 64 + ((sc0 + 32) ^ swz)] = rb1;
        __syncthreads();
        if (k0 + 64 < Ks) {   // next tile's loads fly during MFMA
            const bhalf* An = Abase + k0 + 64;
            const bhalf* Bn = Bbase + k0 + 64;
            ra0 = mok ? *(const uint4*)(An + sc0)      : make_uint4(0u,0u,0u,0u);
            ra1 = mok ? *(const uint4*)(An + sc0 + 32) : make_uint4(0u,0u,0u,0u);
            rb0 = *(const uint4*)(Bn + sc0);
            rb1 = *(const uint4*)(Bn + sc0 + 32);
        }
#pragma unroll
        for (int kb = 0; kb < 2; ++kb) {
            const int kc = kb * 32 + (lane >> 4) * 8;
            bhalf8 af[2], bfr[2];
#pragma unroll
            for (int i = 0; i < 2; ++i) {
                int rA = wm0 + i * 16 + (lane & 15);
                af[i] = *(const bhalf8*)&As[rA * 64 + (kc ^ ((rA & 7) << 3))];
                int rB = wn0 + i * 16 + (lane & 15);
                bfr[i] = *(const bhalf8*)&Bs[rB * 64 + (kc ^ ((rB & 7) << 3))];
            }
#pragma unroll
            for (int mi = 0; mi < 2; ++mi)
#pragma unroll
                for (int ni = 0; ni < 2; ++ni)
                    acc[mi][ni] = __builtin_amdgcn_mfma_f32_16x16x32_bf16(
                        af[mi], bfr[ni], acc[mi][ni], 0, 0, 0);
        }
    }

#pragma unroll
    for (int mi = 0; mi < 2; ++mi)
#pragma unroll
        for (int ni = 0; ni < 2; ++ni) {
            int col = n0 + wn0 + ni * 16 + (lane & 15);
            f32x4 v = acc[mi][ni];
            if (S > 1) {   // split-K partial, raw fp32
#pragma unroll
                for (int r = 0; r < 4; ++r) {
                    int row = m0 + wm0 + mi * 16 + (lane >> 4) * 4 + r;
                    if (row < M)
                        ((float*)Cv)[((size_t)kz * M + row) * ldc + col] = v[r];
                }
            } else {
                float bb = bias ? bias[col] : 0.f;
#pragma unroll
                for (int r = 0; r < 4; ++r) {
                    int row = m0 + wm0 + mi * 16 + (lane >> 4) * 4 + r;
                    if (row < M) {
                        float x = v[r] + bb;
                        if (RELU) x = fmaxf(x, 0.f);
                        if (OUTBF16) ((bhalf*)Cv)[(size_t)row * ldc + col] = (bhalf)x;
                        else         ((float*)Cv)[(size_t)row * ldc + col] = x;
                    }
                }
            }
        }
}

// sum S split-K partials + bias + act, write bf16 or fp32 with out-ld
template<int RELU, int OUTBF16>
__global__ __launch_bounds__(256) void splitk_combine(const float* __restrict__ part,
                                                      int S, int M, int N, int ldo,
                                                      const float* __restrict__ bias,
                                                      void* __restrict__ outv)
{
    int i = blockIdx.x * blockDim.x + threadIdx.x;
    int n4 = N >> 2;
    if (i >= M * n4) return;
    int row = i / n4, c4 = (i - row * n4) << 2;
    float4 s = make_float4(0.f, 0.f, 0.f, 0.f);
    for (int z = 0; z < S; ++z) {
        float4 p = *(const float4*)(part + ((size_t)z * M + row) * N + c4);
        s.x += p.x; s.y += p.y; s.z += p.z; s.w += p.w;
    }
    float4 bb = *(const float4*)(bias + c4);
    s.x += bb.x; s.y += bb.y; s.z += bb.z; s.w += bb.w;
    if (RELU) {
        s.x = fmaxf(s.x, 0.f); s.y = fmaxf(s.y, 0.f);
        s.z = fmaxf(s.z, 0.f); s.w = fmaxf(s.w, 0.f);
    }
    if (OUTBF16) {
        bhalf4 o = {(bhalf)s.x, (bhalf)s.y, (bhalf)s.z, (bhalf)s.w};
        *(bhalf4*)((bhalf*)outv + (size_t)row * ldo + c4) = o;
    } else {
        *(float4*)((float*)outv + (size_t)row * ldo + c4) = s;
    }
}

// ---------------------------------------------------------------------------
// Batched weight transpose+convert: 8 tensors fp32 [K,N] -> bf16 [N,K].
// ---------------------------------------------------------------------------
struct WEnt { const float* src; bhalf* dst; int K; int N; int tiles_end; };
struct WTab { WEnt e[8]; };

__global__ __launch_bounds__(256) void wconv_batch(WTab tab)
{
    __shared__ float tile[32][33];
    int tb = blockIdx.x;
    int idx = 0;
#pragma unroll
    for (int i = 0; i < 8; ++i)
        if (tb >= tab.e[i].tiles_end) idx = i + 1;
    const WEnt& E = tab.e[idx];
    int t0 = idx ? tab.e[idx - 1].tiles_end : 0;
    int lt = tb - t0;
    int tX = E.N >> 5;
    int bx = (lt % tX) << 5;
    int by = (lt / tX) << 5;
    int tx = threadIdx.x & 31, ty = threadIdx.x >> 5;
#pragma unroll
    for (int i = 0; i < 32; i += 8)
        tile[ty + i][tx] = E.src[(size_t)(by + ty + i) * E.N + bx + tx];
    __syncthreads();
#pragma unroll
    for (int i = 0; i < 32; i += 8)
        E.dst[(size_t)(bx + ty + i) * E.K + by + tx] = (bhalf)tile[tx][ty + i];
}

__global__ void conv_batch(const float* __restrict__ a, bhalf* __restrict__ oa, int n4a,
                           const float* __restrict__ b, bhalf* __restrict__ ob, int n4b)
{
    int i = blockIdx.x * blockDim.x + threadIdx.x;
    const float* s; bhalf* d; int j;
    if (i < n4a) { s = a; d = oa; j = i; }
    else { j = i - n4a; if (j >= n4b) return; s = b; d = ob; }
    float4 v = ((const float4*)s)[j];
    bhalf4 o = {(bhalf)v.x, (bhalf)v.y, (bhalf)v.z, (bhalf)v.w};
    ((bhalf4*)d)[j] = o;
}

// ---------------------------------------------------------------------------
// CSR build
// ---------------------------------------------------------------------------
__global__ void csr_count(const int* __restrict__ dst, int* __restrict__ counts)
{
    int e = blockIdx.x * blockDim.x + threadIdx.x;
    if (e >= N_EDGES) return;
    atomicAdd(&counts[dst[e]], 1);
}

__global__ __launch_bounds__(256) void csr_scan(const int* __restrict__ counts,
                                                int* __restrict__ offsets)
{
    __shared__ int partial[256];
    const int t = threadIdx.x;
    const int CH = (N_NODES + 255) / 256;
    const int base = t * CH;
    int s = 0;
    for (int i = 0; i < CH; ++i) {
        int idx = base + i;
        if (idx < N_NODES) s += counts[idx];
    }
    partial[t] = s;
    __syncthreads();
    if (t == 0) {
        int run = 0;
        for (int i = 0; i < 256; ++i) { int c = partial[i]; partial[i] = run; run += c; }
        offsets[N_NODES] = run;
    }
    __syncthreads();
    int run = partial[t];
    for (int i = 0; i < CH; ++i) {
        int idx = base + i;
        if (idx < N_NODES) { offsets[idx] = run; run += counts[idx]; }
    }
}

__global__ void csr_fill(const int* __restrict__ src, const int* __restrict__ dst,
                         const int* __restrict__ offsets, int* __restrict__ cursor,
                         int* __restrict__ eidx)
{
    int e = blockIdx.x * blockDim.x + threadIdx.x;
    if (e >= N_EDGES) return;
    int d = dst[e];
    int slot = offsets[d] + atomicAdd(&cursor[d], 1);
    eidx[slot] = src[e];
}

__global__ void csr_sort_wave(const int* __restrict__ offsets, int* __restrict__ eidx)
{
    int gidx = blockIdx.x * blockDim.x + threadIdx.x;
    int n = gidx >> 6, lane = gidx & 63;
    if (n >= N_NODES) return;
    int lo = offsets[n], hi = offsets[n + 1];
    int cnt = hi - lo;
    if (cnt <= 1) return;
    if (cnt <= 64) {
        int v = (lane < cnt) ? eidx[lo + lane] : 0x7fffffff;
        int rank = 0;
        for (int j = 0; j < cnt; ++j) {
            int vj = __shfl(v, j);
            if (vj < v || (vj == v && j < lane)) ++rank;
        }
        if (lane < cnt) eidx[lo + rank] = v;
    } else if (lane == 0) {
        for (int i = lo + 1; i < hi; ++i) {
            int v = eidx[i]; int j = i - 1;
            while (j >= lo && eidx[j] > v) { eidx[j + 1] = eidx[j]; --j; }
            eidx[j + 1] = v;
        }
    }
}

// ---------------------------------------------------------------------------
// Gather-aggregate (bf16 messages): agg[n] = sum m[eidx[e]] in fp32.
// Wave per node, lane covers 4 cols (bhalf4 = 8B). Unrolled x2 for MLP.
// ---------------------------------------------------------------------------
__global__ __launch_bounds__(256) void edge_gather(const bhalf* __restrict__ m, int ldm,
                                                   const int* __restrict__ offsets,
                                                   const int* __restrict__ eidx,
                                                   float* __restrict__ agg)
{
    int gidx = blockIdx.x * blockDim.x + threadIdx.x;
    int n = gidx >> 6, lane = gidx & 63;
    if (n >= N_NODES) return;
    int lo = offsets[n], hi = offsets[n + 1];
    float4 acc = make_float4(0.f, 0.f, 0.f, 0.f);
    int i = lo;
    for (; i + 2 <= hi; i += 2) {
        int s0 = eidx[i], s1 = eidx[i + 1];
        bhalf4 v0 = *(const bhalf4*)(m + (size_t)s0 * ldm + lane * 4);
        bhalf4 v1 = *(const bhalf4*)(m + (size_t)s1 * ldm + lane * 4);
        acc.x += (float)v0.x + (float)v1.x;
        acc.y += (float)v0.y + (float)v1.y;
        acc.z += (float)v0.z + (float)v1.z;
        acc.w += (float)v0.w + (float)v1.w;
    }
    if (i < hi) {
        bhalf4 v0 = *(const bhalf4*)(m + (size_t)eidx[i] * ldm + lane * 4);
        acc.x += (float)v0.x; acc.y += (float)v0.y;
        acc.z += (float)v0.z; acc.w += (float)v0.w;
    }
    *(float4*)(agg + (size_t)n * HID + lane * 4) = acc;
}

// ---------------------------------------------------------------------------
// new = relu(agg + b) + relu(r + rb); r is bf16 (cols 256.. of fused GEMM out)
// ---------------------------------------------------------------------------
__global__ __launch_bounds__(256) void combine_stats(const float* __restrict__ agg_in,
                                                     const bhalf* __restrict__ r, int ldr,
                                                     const float* __restrict__ b,
                                                     const float* __restrict__ rb,
                                                     float* __restrict__ out,
                                                     float* __restrict__ stats)
{
    int col = threadIdx.x;
    float bb = b[col], rbb = rb[col];
    float s = 0.f, s2 = 0.f;
    for (int row = blockIdx.x; row < N_NODES; row += gridDim.x) {
        float rv = (float)r[(size_t)row * ldr + col];
        float v = fmaxf(agg_in[(size_t)row * HID + col] + bb, 0.f)
                + fmaxf(rv + rbb, 0.f);
        out[(size_t)row * HID + col] = v;
        s += v;
        s2 += v * v;
    }
    atomicAdd(&stats[col], s);
    atomicAdd(&stats[HID + col], s2);
}

__global__ void bn_finalize(float* __restrict__ stats, float inv_n)
{
    int c = threadIdx.x;
    float mu = stats[c] * inv_n;
    float var = stats[HID + c] * inv_n - mu * mu;
    stats[2 * HID + c] = mu;
    stats[3 * HID + c] = rsqrtf(var + 1e-5f);
}

// ---------------------------------------------------------------------------
template<int MODE>
__global__ __launch_bounds__(256) void bn_row(const float* __restrict__ h,
                                              const float* __restrict__ stats,
                                              const float* __restrict__ g,
                                              const float* __restrict__ be,
                                              bhalf* __restrict__ outb,
                                              float* __restrict__ outf,
                                              const float* __restrict__ awW,
                                              const float* __restrict__ awb,
                                              float* __restrict__ w)
{
    int gidx = blockIdx.x * blockDim.x + threadIdx.x;
    int n = gidx >> 6, lane = gidx & 63;
    if (n >= N_NODES) return;
    int col = lane * 4;
    float4 v  = *(const float4*)(h + (size_t)n * HID + col);
    float4 mu = *(const float4*)(stats + 2 * HID + col);
    float4 rs = *(const float4*)(stats + 3 * HID + col);
    float4 gg = *(const float4*)(g + col);
    float4 bb = *(const float4*)(be + col);
    float4 o;
    o.x = gg.x * (v.x - mu.x) * rs.x + bb.x;
    o.y = gg.y * (v.y - mu.y) * rs.y + bb.y;
    o.z = gg.z * (v.z - mu.z) * rs.z + bb.z;
    o.w = gg.w * (v.w - mu.w) * rs.w + bb.w;
    if (MODE == 0) {
        bhalf4 ob = {(bhalf)o.x, (bhalf)o.y, (bhalf)o.z, (bhalf)o.w};
        *(bhalf4*)(outb + (size_t)n * HID + col) = ob;
    } else {
        *(float4*)(outf + (size_t)n * HID + col) = o;
        float4 wv = *(const float4*)(awW + col);
        float d = o.x * wv.x + o.y * wv.y + o.z * wv.z + o.w * wv.w;
#pragma unroll
        for (int off = 32; off > 0; off >>= 1) d += __shfl_xor(d, off);
        if (lane == 0) w[n] = 1.f / (1.f + expf(-(d + awb[0])));
    }
}

// ---------------------------------------------------------------------------
__global__ __launch_bounds__(256) void readout(const float* __restrict__ h,
                                               const float* __restrict__ w,
                                               const int* __restrict__ gid,
                                               bhalf* __restrict__ z)
{
    int g = blockIdx.x, col = threadIdx.x;
    int lo = 0, hi = N_NODES;
    while (lo < hi) { int mid = (lo + hi) >> 1; if (gid[mid] < g) lo = mid + 1; else hi = mid; }
    int start = lo;
    hi = N_NODES;
    while (lo < hi) { int mid = (lo + hi) >> 1; if (gid[mid] <= g) lo = mid + 1; else hi = mid; }
    int end = lo;
    float s = 0.f, mx = -INFINITY;
    for (int n = start; n < end; ++n) {
        float v = h[(size_t)n * HID + col];
        s = fmaf(v, w[n], s);
        mx = fmaxf(mx, v);
    }
    z[(size_t)g * 1024 + col] = (bhalf)s;
    z[(size_t)g * 1024 + HID + col] = (bhalf)mx;
}

__global__ void final_dot(const float* __restrict__ x, const float* __restrict__ W,
                          const float* __restrict__ b, float* __restrict__ out)
{
    int gidx = blockIdx.x * blockDim.x + threadIdx.x;
    int rowi = gidx >> 6, lane = gidx & 63;
    if (rowi >= N_GRAPHS) return;
    const float4* xr = (const float4*)(x + (size_t)rowi * 512);
    const float4* wr = (const float4*)W;
    float acc = 0.f;
#pragma unroll
    for (int i = 0; i < 2; ++i) {
        float4 a = xr[lane * 2 + i];
        float4 ww = wr[lane * 2 + i];
        acc += a.x * ww.x + a.y * ww.y + a.z * ww.z + a.w * ww.w;
    }
#pragma unroll
    for (int off = 32; off > 0; off >>= 1) acc += __shfl_xor(acc, off);
    if (lane == 0) out[rowi] = acc + b[0];
}

// ---------------------------------------------------------------------------
extern "C" void kernel_launch(void* const* d_in, const int* in_sizes, int n_in,
                              void* d_out, int out_size, void* d_ws, size_t ws_size,
                              hipStream_t stream)
{
    (void)in_sizes; (void)n_in; (void)out_size; (void)ws_size;

    const float* node_feats = (const float*)d_in[0];
    const float* rdkit      = (const float*)d_in[1];
    const int*   src        = (const int*)d_in[2];
    const int*   dst        = (const int*)d_in[3];
    const int*   gid        = (const int*)d_in[4];
    const float* W1  = (const float*)d_in[5];
    const float* b1  = (const float*)d_in[6];
    const float* rW1 = (const float*)d_in[7];
    const float* rb1 = (const float*)d_in[8];
    const float* g1  = (const float*)d_in[9];
    const float* be1 = (const float*)d_in[10];
    const float* W2  = (const float*)d_in[11];
    const float* b2  = (const float*)d_in[12];
    const float* rW2 = (const float*)d_in[13];
    const float* rb2 = (const float*)d_in[14];
    const float* g2  = (const float*)d_in[15];
    const float* be2 = (const float*)d_in[16];
    const float* aw_W  = (const float*)d_in[17];
    const float* aw_b  = (const float*)d_in[18];
    const float* rk_W1 = (const float*)d_in[19];
    const float* rk_b1 = (const float*)d_in[20];
    const float* rk_W2 = (const float*)d_in[21];
    const float* rk_b2 = (const float*)d_in[22];
    const float* c_W1  = (const float*)d_in[23];
    const float* c_b1  = (const float*)d_in[24];
    const float* c_W2  = (const float*)d_in[25];
    const float* c_b2  = (const float*)d_in[26];
    const float* c_W3  = (const float*)d_in[27];
    const float* c_b3  = (const float*)d_in[28];

    float* out = (float*)d_out;

    const size_t NODE = (size_t)N_NODES * HID;         // 5,120,000
    bhalf* buf_mr = (bhalf*)d_ws;                      // [20000,512] bf16: m | r
    float* aggA   = (float*)(buf_mr + (size_t)N_NODES * 512);  // [20000,256] fp32
    bhalf* h1b    = (bhalf*)(aggA + NODE);             // [20000,256] bf16 (nfb aliases)
    bhalf* nfb    = h1b;                               // [20000,128] bf16
    bhalf* W1cat  = h1b + NODE;                        // [512,128]  = W1^T | rW1^T
    bhalf* W2cat  = W1cat + 512 * 128;                 // [512,256]  = W2^T | rW2^T
    bhalf* rkW1t  = W2cat + 512 * 256;                 // [1024,2048]
    bhalf* rkW2t  = rkW1t + 2048 * 1024;               // [512,1024]
    bhalf* cW1t   = rkW2t + 1024 * 512;                // [1024,1024]
    bhalf* cW2t   = cW1t + 1024 * 1024;                // [512,1024]
    bhalf* rdkb   = cW2t + 1024 * 512;                 // [512,2048]
    float* stats  = (float*)(rdkb + 512 * 2048);       // 1024
    float* wbuf   = stats + 1024;                      // 20000
    int*   counts  = (int*)(wbuf + N_NODES);
    int*   offsets = counts + N_NODES;                 // N+1
    int*   cursor  = offsets + N_NODES + 1;
    int*   eidx    = cursor + N_NODES;                 // N_EDGES
    // head buffers alias buf_mr (free after layer-2 combine)
    bhalf* rkhb  = (bhalf*)buf_mr;                     // [512,1024] bf16
    bhalf* zb    = rkhb + 512 * 1024;                  // [512,1024] bf16
    bhalf* ch1b  = zb + 512 * 1024;                    // [512,1024] bf16
    float* ch2   = (float*)(ch1b + 512 * 1024);        // [512,512] fp32
    float* spart = ch2 + 512 * 512;                    // split-K partials (<=2M fp32)

    dim3 blk(256);
    const int EPB = (N_EDGES + 255) / 256;
    const int NWAVE = (N_NODES * 64) / 256;            // wave per node
    dim3 gnode(512 / 64, (N_NODES + 63) / 64);         // (8, 313) fused W|rW

    // ---------------- weight/input conversion (2 launches) ----------------
    WTab tab;
    tab.e[0] = {W1,    W1cat,             128, 256,   32};
    tab.e[1] = {rW1,   W1cat + 256 * 128, 128, 256,   64};
    tab.e[2] = {W2,    W2cat,             256, 256,  128};
    tab.e[3] = {rW2,   W2cat + 256 * 256, 256, 256,  192};
    tab.e[4] = {rk_W1, rkW1t,            2048, 1024, 2240};
    tab.e[5] = {rk_W2, rkW2t,            1024, 512,  2752};
    tab.e[6] = {c_W1,  cW1t,             1024, 1024, 3776};
    tab.e[7] = {c_W2,  cW2t,             1024, 512,  4288};
    wconv_batch<<<4288, blk, 0, stream>>>(tab);
    {
        int n4a = N_NODES * IN_FEATS / 4, n4b = 512 * 2048 / 4;
        conv_batch<<<(n4a + n4b + 255) / 256, blk, 0, stream>>>(node_feats, nfb, n4a,
                                                                rdkit, rdkb, n4b);
    }

    // ---------------- CSR build ----------------
    hipMemsetAsync(counts, 0, N_NODES * sizeof(int), stream);
    hipMemsetAsync(cursor, 0, N_NODES * sizeof(int), stream);
    csr_count<<<EPB, blk, 0, stream>>>(dst, counts);
    csr_scan<<<1, blk, 0, stream>>>(counts, offsets);
    csr_fill<<<EPB, blk, 0, stream>>>(src, dst, offsets, cursor, eidx);
    csr_sort_wave<<<NWAVE, blk, 0, stream>>>(offsets, eidx);

    // ---------------- Layer 1 (fused m|r GEMM -> bf16) ----------------
    gemm_mfma<0,1><<<gnode, blk, 0, stream>>>(nfb, W1cat, buf_mr, nullptr,
                                              N_NODES, IN_FEATS, 512);
    edge_gather<<<NWAVE, blk, 0, stream>>>(buf_mr, 512, offsets, eidx, aggA);
    hipMemsetAsync(stats, 0, 2 * HID * sizeof(float), stream);
    combine_stats<<<512, blk, 0, stream>>>(aggA, buf_mr + 256, 512, b1, rb1, aggA, stats);
    bn_finalize<<<1, HID, 0, stream>>>(stats, 1.0f / N_NODES);
    bn_row<0><<<NWAVE, blk, 0, stream>>>(aggA, stats, g1, be1, h1b, nullptr, nullptr, nullptr, nullptr);

    // ---------------- Layer 2 (fused m|r GEMM -> bf16) ----------------
    gemm_mfma<0,1><<<gnode, blk, 0, stream>>>(h1b, W2cat, buf_mr, nullptr,
                                              N_NODES, HID, 512);
    edge_gather<<<NWAVE, blk, 0, stream>>>(buf_mr, 512, offsets, eidx, aggA);
    hipMemsetAsync(stats, 0, 2 * HID * sizeof(float), stream);
    combine_stats<<<512, blk, 0, stream>>>(aggA, buf_mr + 256, 512, b2, rb2, aggA, stats);
    bn_finalize<<<1, HID, 0, stream>>>(stats, 1.0f / N_NODES);
    bn_row<1><<<NWAVE, blk, 0, stream>>>(aggA, stats, g2, be2, nullptr, aggA, aw_W, aw_b, wbuf);

    // ---------------- Readout ----------------
    readout<<<N_GRAPHS, HID, 0, stream>>>(aggA, wbuf, gid, zb);

    // ---------------- RDKit branch (split-K) ----------------
    gemm_mfma<0,0><<<dim3(16, 8, 4), blk, 0, stream>>>(rdkb, rkW1t, spart, nullptr,
                                                       512, 2048, 1024);
    splitk_combine<1,1><<<512, blk, 0, stream>>>(spart, 4, 512, 1024, 1024, rk_b1, rkhb);
    gemm_mfma<0,0><<<dim3(8, 8, 8), blk, 0, stream>>>(rkhb, rkW2t, spart, nullptr,
                                                      512, 1024, 512);
    splitk_combine<1,1><<<256, blk, 0, stream>>>(spart, 8, 512, 512, 1024, rk_b2, zb + 512);

    // ---------------- Combined head (split-K) ----------------
    gemm_mfma<0,0><<<dim3(16, 8, 4), blk, 0, stream>>>(zb, cW1t, spart, nullptr,
                                                       512, 1024, 1024);
    splitk_combine<1,1><<<512, blk, 0, stream>>>(spart, 4, 512, 1024, 1024, c_b1, ch1b);
    gemm_mfma<0,0><<<dim3(8, 8, 8), blk, 0, stream>>>(ch1b, cW2t, spart, nullptr,
                                                      512, 1024, 512);
    splitk_combine<1,0><<<256, blk, 0, stream>>>(spart, 8, 512, 512, 512, c_b2, ch2);
    final_dot<<<(N_GRAPHS * 64) / 256, blk, 0, stream>>>(ch2, c_W3, c_b3, out);
}

// Round 7
// 308.792 us; speedup vs baseline: 8.6440x; 1.1384x over previous
//
#include <hip/hip_runtime.h>
#include <hip/hip_bf16.h>
#include <cstdint>
#include <cstddef>

#define N_NODES 20000
#define N_EDGES 320000
#define N_GRAPHS 512
#define IN_FEATS 128
#define HID 256

typedef __bf16 bhalf;
typedef __bf16 bhalf8 __attribute__((ext_vector_type(8)));
typedef __bf16 bhalf4 __attribute__((ext_vector_type(4)));
typedef float f32x4 __attribute__((ext_vector_type(4)));

// ---------------------------------------------------------------------------
// bf16 MFMA GEMM: C[M,N] = A[M,K] @ Bt[N,K]^T. Tile 64x64, BK=64, 4 waves
// (2x2), wave = 32x32 via 2x2 frags of 16x16x32. Register-prefetch pipeline.
// LDS XOR-swizzled. K%(64*gridDim.z)==0, N%64==0; M guarded.
// gridDim.z > 1 => split-K: z-slice writes fp32 partial (no bias/relu).
// ---------------------------------------------------------------------------
template<int RELU, int OUTBF16>
__global__ __launch_bounds__(256) void gemm_mfma(const bhalf* __restrict__ A,
                                                 const bhalf* __restrict__ Bt,
                                                 void* __restrict__ Cv,
                                                 const float* __restrict__ bias,
                                                 int M, int K, int ldc)
{
    __shared__ bhalf As[64 * 64];
    __shared__ bhalf Bs[64 * 64];

    const int t = threadIdx.x;
    const int lane = t & 63, wid = t >> 6;
    const int wm0 = (wid >> 1) * 32, wn0 = (wid & 1) * 32;
    const int m0 = blockIdx.y * 64, n0 = blockIdx.x * 64;
    const int S = gridDim.z, kz = blockIdx.z;
    const int Ks = K / S;

    const int srow = t >> 2;           // 0..63
    const int sc0 = (t & 3) << 3;      // bf16 col 0,8,16,24

    f32x4 acc[2][2] = {};
    uint4 ra0, ra1, rb0, rb1;

    const bool mok = (m0 + srow) < M;
    const bhalf* Abase = A + (size_t)(m0 + srow) * K + (size_t)kz * Ks;
    const bhalf* Bbase = Bt + (size_t)(n0 + srow) * K + (size_t)kz * Ks;

    ra0 = mok ? *(const uint4*)(Abase + sc0)      : make_uint4(0u,0u,0u,0u);
    ra1 = mok ? *(const uint4*)(Abase + sc0 + 32) : make_uint4(0u,0u,0u,0u);
    rb0 = *(const uint4*)(Bbase + sc0);
    rb1 = *(const uint4*)(Bbase + sc0 + 32);

    const int swz = (srow & 7) << 3;
    for (int k0 = 0; k0 < Ks; k0 += 64) {
        __syncthreads();
        *(uint4*)&As[srow * 64 + (sc0 ^ swz)]        = ra0;
        *(uint4*)&As[srow * 64 + ((sc0 + 32) ^ swz)] = ra1;
        *(uint4*)&Bs[srow * 64 + (sc0 ^ swz)]        = rb0;
        *(uint4*)&Bs[srow * 64 + ((sc0 + 32) ^ swz)] = rb1;
        __syncthreads();
        if (k0 + 64 < Ks) {
            const bhalf* An = Abase + k0 + 64;
            const bhalf* Bn = Bbase + k0 + 64;
            ra0 = mok ? *(const uint4*)(An + sc0)      : make_uint4(0u,0u,0u,0u);
            ra1 = mok ? *(const uint4*)(An + sc0 + 32) : make_uint4(0u,0u,0u,0u);
            rb0 = *(const uint4*)(Bn + sc0);
            rb1 = *(const uint4*)(Bn + sc0 + 32);
        }
#pragma unroll
        for (int kb = 0; kb < 2; ++kb) {
            const int kc = kb * 32 + (lane >> 4) * 8;
            bhalf8 af[2], bfr[2];
#pragma unroll
            for (int i = 0; i < 2; ++i) {
                int rA = wm0 + i * 16 + (lane & 15);
                af[i] = *(const bhalf8*)&As[rA * 64 + (kc ^ ((rA & 7) << 3))];
                int rB = wn0 + i * 16 + (lane & 15);
                bfr[i] = *(const bhalf8*)&Bs[rB * 64 + (kc ^ ((rB & 7) << 3))];
            }
#pragma unroll
            for (int mi = 0; mi < 2; ++mi)
#pragma unroll
                for (int ni = 0; ni < 2; ++ni)
                    acc[mi][ni] = __builtin_amdgcn_mfma_f32_16x16x32_bf16(
                        af[mi], bfr[ni], acc[mi][ni], 0, 0, 0);
        }
    }

#pragma unroll
    for (int mi = 0; mi < 2; ++mi)
#pragma unroll
        for (int ni = 0; ni < 2; ++ni) {
            int col = n0 + wn0 + ni * 16 + (lane & 15);
            f32x4 v = acc[mi][ni];
            if (S > 1) {
#pragma unroll
                for (int r = 0; r < 4; ++r) {
                    int row = m0 + wm0 + mi * 16 + (lane >> 4) * 4 + r;
                    if (row < M)
                        ((float*)Cv)[((size_t)kz * M + row) * ldc + col] = v[r];
                }
            } else {
                float bb = bias ? bias[col] : 0.f;
#pragma unroll
                for (int r = 0; r < 4; ++r) {
                    int row = m0 + wm0 + mi * 16 + (lane >> 4) * 4 + r;
                    if (row < M) {
                        float x = v[r] + bb;
                        if (RELU) x = fmaxf(x, 0.f);
                        if (OUTBF16) ((bhalf*)Cv)[(size_t)row * ldc + col] = (bhalf)x;
                        else         ((float*)Cv)[(size_t)row * ldc + col] = x;
                    }
                }
            }
        }
}

// sum S split-K partials + bias + act, write bf16/fp32 with out-ld
template<int RELU, int OUTBF16>
__global__ __launch_bounds__(256) void splitk_combine(const float* __restrict__ part,
                                                      int S, int M, int N, int ldo,
                                                      const float* __restrict__ bias,
                                                      void* __restrict__ outv)
{
    int i = blockIdx.x * blockDim.x + threadIdx.x;
    int n4 = N >> 2;
    if (i >= M * n4) return;
    int row = i / n4, c4 = (i - row * n4) << 2;
    float4 s = make_float4(0.f, 0.f, 0.f, 0.f);
    for (int z = 0; z < S; ++z) {
        float4 p = *(const float4*)(part + ((size_t)z * M + row) * N + c4);
        s.x += p.x; s.y += p.y; s.z += p.z; s.w += p.w;
    }
    float4 bb = *(const float4*)(bias + c4);
    s.x += bb.x; s.y += bb.y; s.z += bb.z; s.w += bb.w;
    if (RELU) {
        s.x = fmaxf(s.x, 0.f); s.y = fmaxf(s.y, 0.f);
        s.z = fmaxf(s.z, 0.f); s.w = fmaxf(s.w, 0.f);
    }
    if (OUTBF16) {
        bhalf4 o = {(bhalf)s.x, (bhalf)s.y, (bhalf)s.z, (bhalf)s.w};
        *(bhalf4*)((bhalf*)outv + (size_t)row * ldo + c4) = o;
    } else {
        *(float4*)((float*)outv + (size_t)row * ldo + c4) = s;
    }
}

// last head layer: combine S partials + bias + relu, dot with W3, write out[row]
__global__ __launch_bounds__(128) void splitk_combine_dot(const float* __restrict__ part,
                                                          int S, int M, int N,
                                                          const float* __restrict__ bias,
                                                          const float* __restrict__ W3,
                                                          const float* __restrict__ b3,
                                                          float* __restrict__ out)
{
    int row = blockIdx.x, t = threadIdx.x;   // N=512 -> 128 threads x 4 cols
    int c4 = t << 2;
    float4 s = make_float4(0.f, 0.f, 0.f, 0.f);
    for (int z = 0; z < S; ++z) {
        float4 p = *(const float4*)(part + ((size_t)z * M + row) * N + c4);
        s.x += p.x; s.y += p.y; s.z += p.z; s.w += p.w;
    }
    float4 bb = *(const float4*)(bias + c4);
    float4 w = *(const float4*)(W3 + c4);
    float d = fmaxf(s.x + bb.x, 0.f) * w.x + fmaxf(s.y + bb.y, 0.f) * w.y
            + fmaxf(s.z + bb.z, 0.f) * w.z + fmaxf(s.w + bb.w, 0.f) * w.w;
#pragma unroll
    for (int off = 32; off > 0; off >>= 1) d += __shfl_xor(d, off);
    __shared__ float ws2[2];
    if ((t & 63) == 0) ws2[t >> 6] = d;
    __syncthreads();
    if (t == 0) out[row] = ws2[0] + ws2[1] + b3[0];
}

// ---------------------------------------------------------------------------
// Batched weight transpose+convert: 8 tensors fp32 [K,N] -> bf16 [N,K].
// ---------------------------------------------------------------------------
struct WEnt { const float* src; bhalf* dst; int K; int N; int tiles_end; };
struct WTab { WEnt e[8]; };

__global__ __launch_bounds__(256) void wconv_batch(WTab tab)
{
    __shared__ float tile[32][33];
    int tb = blockIdx.x;
    int idx = 0;
#pragma unroll
    for (int i = 0; i < 8; ++i)
        if (tb >= tab.e[i].tiles_end) idx = i + 1;
    const WEnt& E = tab.e[idx];
    int t0 = idx ? tab.e[idx - 1].tiles_end : 0;
    int lt = tb - t0;
    int tX = E.N >> 5;
    int bx = (lt % tX) << 5;
    int by = (lt / tX) << 5;
    int tx = threadIdx.x & 31, ty = threadIdx.x >> 5;
#pragma unroll
    for (int i = 0; i < 32; i += 8)
        tile[ty + i][tx] = E.src[(size_t)(by + ty + i) * E.N + bx + tx];
    __syncthreads();
#pragma unroll
    for (int i = 0; i < 32; i += 8)
        E.dst[(size_t)(bx + ty + i) * E.K + by + tx] = (bhalf)tile[tx][ty + i];
}

__global__ void conv_batch(const float* __restrict__ a, bhalf* __restrict__ oa, int n4a,
                           const float* __restrict__ b, bhalf* __restrict__ ob, int n4b)
{
    int i = blockIdx.x * blockDim.x + threadIdx.x;
    const float* s; bhalf* d; int j;
    if (i < n4a) { s = a; d = oa; j = i; }
    else { j = i - n4a; if (j >= n4b) return; s = b; d = ob; }
    float4 v = ((const float4*)s)[j];
    bhalf4 o = {(bhalf)v.x, (bhalf)v.y, (bhalf)v.z, (bhalf)v.w};
    ((bhalf4*)d)[j] = o;
}

// ---------------------------------------------------------------------------
// CSR build: count -> hierarchical scan (a,b,c) -> fill -> wave sort
// ---------------------------------------------------------------------------
__global__ void csr_count(const int* __restrict__ dst, int* __restrict__ counts)
{
    int e = blockIdx.x * blockDim.x + threadIdx.x;
    if (e >= N_EDGES) return;
    atomicAdd(&counts[dst[e]], 1);
}

__global__ __launch_bounds__(256) void csr_scan_a(const int* __restrict__ counts,
                                                  int* __restrict__ bsum)
{
    int i = blockIdx.x * 256 + threadIdx.x;
    int v = (i < N_NODES) ? counts[i] : 0;
#pragma unroll
    for (int off = 32; off > 0; off >>= 1) v += __shfl_down(v, off);
    __shared__ int ws[4];
    if ((threadIdx.x & 63) == 0) ws[threadIdx.x >> 6] = v;
    __syncthreads();
    if (threadIdx.x == 0) bsum[blockIdx.x] = ws[0] + ws[1] + ws[2] + ws[3];
}

__global__ __launch_bounds__(128) void csr_scan_b(int* __restrict__ bsum, int nb)
{
    __shared__ int tmp[128];
    int t = threadIdx.x;
    tmp[t] = (t < nb) ? bsum[t] : 0;
    __syncthreads();
    if (t == 0) {
        int run = 0;
        for (int i = 0; i < nb; ++i) { int c = tmp[i]; tmp[i] = run; run += c; }
    }
    __syncthreads();
    if (t < nb) bsum[t] = tmp[t];
}

__global__ __launch_bounds__(256) void csr_scan_c(const int* __restrict__ counts,
                                                  const int* __restrict__ bsum,
                                                  int* __restrict__ offsets)
{
    int t = threadIdx.x, b = blockIdx.x;
    int i = b * 256 + t;
    int v = (i < N_NODES) ? counts[i] : 0;
    int x = v;
#pragma unroll
    for (int off = 1; off < 64; off <<= 1) {
        int y = __shfl_up(x, off);
        if ((t & 63) >= off) x += y;
    }
    __shared__ int wsum[4];
    if ((t & 63) == 63) wsum[t >> 6] = x;
    __syncthreads();
    int add = bsum[b];
    for (int w = 0; w < (t >> 6); ++w) add += wsum[w];
    int excl = x - v + add;
    if (i < N_NODES) offsets[i] = excl;
    if (i == N_NODES - 1) offsets[N_NODES] = excl + v;
}

__global__ void csr_fill(const int* __restrict__ src, const int* __restrict__ dst,
                         const int* __restrict__ offsets, int* __restrict__ cursor,
                         int* __restrict__ eidx)
{
    int e = blockIdx.x * blockDim.x + threadIdx.x;
    if (e >= N_EDGES) return;
    int d = dst[e];
    int slot = offsets[d] + atomicAdd(&cursor[d], 1);
    eidx[slot] = src[e];
}

__global__ void csr_sort_wave(const int* __restrict__ offsets, int* __restrict__ eidx)
{
    int gidx = blockIdx.x * blockDim.x + threadIdx.x;
    int n = gidx >> 6, lane = gidx & 63;
    if (n >= N_NODES) return;
    int lo = offsets[n], hi = offsets[n + 1];
    int cnt = hi - lo;
    if (cnt <= 1) return;
    if (cnt <= 64) {
        int v = (lane < cnt) ? eidx[lo + lane] : 0x7fffffff;
        int rank = 0;
        for (int j = 0; j < cnt; ++j) {
            int vj = __shfl(v, j);
            if (vj < v || (vj == v && j < lane)) ++rank;
        }
        if (lane < cnt) eidx[lo + rank] = v;
    } else if (lane == 0) {
        for (int i = lo + 1; i < hi; ++i) {
            int v = eidx[i]; int j = i - 1;
            while (j >= lo && eidx[j] > v) { eidx[j + 1] = eidx[j]; --j; }
            eidx[j + 1] = v;
        }
    }
}

// ---------------------------------------------------------------------------
// Gather-aggregate (bf16 messages): agg[n] = sum m[eidx[e]] in fp32.
// ---------------------------------------------------------------------------
__global__ __launch_bounds__(256) void edge_gather(const bhalf* __restrict__ m, int ldm,
                                                   const int* __restrict__ offsets,
                                                   const int* __restrict__ eidx,
                                                   float* __restrict__ agg)
{
    int gidx = blockIdx.x * blockDim.x + threadIdx.x;
    int n = gidx >> 6, lane = gidx & 63;
    if (n >= N_NODES) return;
    int lo = offsets[n], hi = offsets[n + 1];
    float4 acc = make_float4(0.f, 0.f, 0.f, 0.f);
    int i = lo;
    for (; i + 2 <= hi; i += 2) {
        int s0 = eidx[i], s1 = eidx[i + 1];
        bhalf4 v0 = *(const bhalf4*)(m + (size_t)s0 * ldm + lane * 4);
        bhalf4 v1 = *(const bhalf4*)(m + (size_t)s1 * ldm + lane * 4);
        acc.x += (float)v0.x + (float)v1.x;
        acc.y += (float)v0.y + (float)v1.y;
        acc.z += (float)v0.z + (float)v1.z;
        acc.w += (float)v0.w + (float)v1.w;
    }
    if (i < hi) {
        bhalf4 v0 = *(const bhalf4*)(m + (size_t)eidx[i] * ldm + lane * 4);
        acc.x += (float)v0.x; acc.y += (float)v0.y;
        acc.z += (float)v0.z; acc.w += (float)v0.w;
    }
    *(float4*)(agg + (size_t)n * HID + lane * 4) = acc;
}

// ---------------------------------------------------------------------------
__global__ __launch_bounds__(256) void combine_stats(const float* __restrict__ agg_in,
                                                     const bhalf* __restrict__ r, int ldr,
                                                     const float* __restrict__ b,
                                                     const float* __restrict__ rb,
                                                     float* __restrict__ out,
                                                     float* __restrict__ stats)
{
    int col = threadIdx.x;
    float bb = b[col], rbb = rb[col];
    float s = 0.f, s2 = 0.f;
    for (int row = blockIdx.x; row < N_NODES; row += gridDim.x) {
        float rv = (float)r[(size_t)row * ldr + col];
        float v = fmaxf(agg_in[(size_t)row * HID + col] + bb, 0.f)
                + fmaxf(rv + rbb, 0.f);
        out[(size_t)row * HID + col] = v;
        s += v;
        s2 += v * v;
    }
    atomicAdd(&stats[col], s);
    atomicAdd(&stats[HID + col], s2);
}

__global__ void bn_finalize(float* __restrict__ stats, float inv_n)
{
    int c = threadIdx.x;
    float mu = stats[c] * inv_n;
    float var = stats[HID + c] * inv_n - mu * mu;
    stats[2 * HID + c] = mu;
    stats[3 * HID + c] = rsqrtf(var + 1e-5f);
}

// ---------------------------------------------------------------------------
template<int MODE>
__global__ __launch_bounds__(256) void bn_row(const float* __restrict__ h,
                                              const float* __restrict__ stats,
                                              const float* __restrict__ g,
                                              const float* __restrict__ be,
                                              bhalf* __restrict__ outb,
                                              float* __restrict__ outf,
                                              const float* __restrict__ awW,
                                              const float* __restrict__ awb,
                                              float* __restrict__ w)
{
    int gidx = blockIdx.x * blockDim.x + threadIdx.x;
    int n = gidx >> 6, lane = gidx & 63;
    if (n >= N_NODES) return;
    int col = lane * 4;
    float4 v  = *(const float4*)(h + (size_t)n * HID + col);
    float4 mu = *(const float4*)(stats + 2 * HID + col);
    float4 rs = *(const float4*)(stats + 3 * HID + col);
    float4 gg = *(const float4*)(g + col);
    float4 bb = *(const float4*)(be + col);
    float4 o;
    o.x = gg.x * (v.x - mu.x) * rs.x + bb.x;
    o.y = gg.y * (v.y - mu.y) * rs.y + bb.y;
    o.z = gg.z * (v.z - mu.z) * rs.z + bb.z;
    o.w = gg.w * (v.w - mu.w) * rs.w + bb.w;
    if (MODE == 0) {
        bhalf4 ob = {(bhalf)o.x, (bhalf)o.y, (bhalf)o.z, (bhalf)o.w};
        *(bhalf4*)(outb + (size_t)n * HID + col) = ob;
    } else {
        *(float4*)(outf + (size_t)n * HID + col) = o;
        float4 wv = *(const float4*)(awW + col);
        float d = o.x * wv.x + o.y * wv.y + o.z * wv.z + o.w * wv.w;
#pragma unroll
        for (int off = 32; off > 0; off >>= 1) d += __shfl_xor(d, off);
        if (lane == 0) w[n] = 1.f / (1.f + expf(-(d + awb[0])));
    }
}

// ---------------------------------------------------------------------------
__global__ __launch_bounds__(256) void readout(const float* __restrict__ h,
                                               const float* __restrict__ w,
                                               const int* __restrict__ gid,
                                               bhalf* __restrict__ z)
{
    int g = blockIdx.x, col = threadIdx.x;
    int lo = 0, hi = N_NODES;
    while (lo < hi) { int mid = (lo + hi) >> 1; if (gid[mid] < g) lo = mid + 1; else hi = mid; }
    int start = lo;
    hi = N_NODES;
    while (lo < hi) { int mid = (lo + hi) >> 1; if (gid[mid] <= g) lo = mid + 1; else hi = mid; }
    int end = lo;
    float s = 0.f, mx = -INFINITY;
    for (int n = start; n < end; ++n) {
        float v = h[(size_t)n * HID + col];
        s = fmaf(v, w[n], s);
        mx = fmaxf(mx, v);
    }
    z[(size_t)g * 1024 + col] = (bhalf)s;
    z[(size_t)g * 1024 + HID + col] = (bhalf)mx;
}

// ---------------------------------------------------------------------------
extern "C" void kernel_launch(void* const* d_in, const int* in_sizes, int n_in,
                              void* d_out, int out_size, void* d_ws, size_t ws_size,
                              hipStream_t stream)
{
    (void)in_sizes; (void)n_in; (void)out_size; (void)ws_size;

    const float* node_feats = (const float*)d_in[0];
    const float* rdkit      = (const float*)d_in[1];
    const int*   src        = (const int*)d_in[2];
    const int*   dst        = (const int*)d_in[3];
    const int*   gid        = (const int*)d_in[4];
    const float* W1  = (const float*)d_in[5];
    const float* b1  = (const float*)d_in[6];
    const float* rW1 = (const float*)d_in[7];
    const float* rb1 = (const float*)d_in[8];
    const float* g1  = (const float*)d_in[9];
    const float* be1 = (const float*)d_in[10];
    const float* W2  = (const float*)d_in[11];
    const float* b2  = (const float*)d_in[12];
    const float* rW2 = (const float*)d_in[13];
    const float* rb2 = (const float*)d_in[14];
    const float* g2  = (const float*)d_in[15];
    const float* be2 = (const float*)d_in[16];
    const float* aw_W  = (const float*)d_in[17];
    const float* aw_b  = (const float*)d_in[18];
    const float* rk_W1 = (const float*)d_in[19];
    const float* rk_b1 = (const float*)d_in[20];
    const float* rk_W2 = (const float*)d_in[21];
    const float* rk_b2 = (const float*)d_in[22];
    const float* c_W1  = (const float*)d_in[23];
    const float* c_b1  = (const float*)d_in[24];
    const float* c_W2  = (const float*)d_in[25];
    const float* c_b2  = (const float*)d_in[26];
    const float* c_W3  = (const float*)d_in[27];
    const float* c_b3  = (const float*)d_in[28];

    float* out = (float*)d_out;

    const size_t NODE = (size_t)N_NODES * HID;         // 5,120,000
    bhalf* buf_mr = (bhalf*)d_ws;                      // [20000,512] bf16: m | r
    float* aggA   = (float*)(buf_mr + (size_t)N_NODES * 512);  // [20000,256] fp32
    bhalf* h1b    = (bhalf*)(aggA + NODE);             // [20000,256] bf16 (nfb aliases)
    bhalf* nfb    = h1b;                               // [20000,128] bf16
    bhalf* W1cat  = h1b + NODE;                        // [512,128]  = W1^T | rW1^T
    bhalf* W2cat  = W1cat + 512 * 128;                 // [512,256]  = W2^T | rW2^T
    bhalf* rkW1t  = W2cat + 512 * 256;                 // [1024,2048]
    bhalf* rkW2t  = rkW1t + 2048 * 1024;               // [512,1024]
    bhalf* cW1t   = rkW2t + 1024 * 512;                // [1024,1024]
    bhalf* cW2t   = cW1t + 1024 * 1024;                // [512,1024]
    bhalf* rdkb   = cW2t + 1024 * 512;                 // [512,2048]
    float* stats1 = (float*)(rdkb + 512 * 2048);       // 1024 (sum|sumsq|mu|rs)
    float* stats2 = stats1 + 1024;                     // 1024
    float* wbuf   = stats2 + 1024;                     // 20000
    int*   counts  = (int*)(wbuf + N_NODES);           // N  (adjacent w/ cursor)
    int*   cursor  = counts + N_NODES;                 // N
    int*   offsets = cursor + N_NODES;                 // N+1
    int*   eidx    = offsets + N_NODES + 1;            // N_EDGES
    int*   bsum    = eidx + N_EDGES;                   // 128
    // head buffers alias buf_mr (free after layer-2 combine)
    bhalf* rkhb  = (bhalf*)buf_mr;                     // [512,1024] bf16
    bhalf* zb    = rkhb + 512 * 1024;                  // [512,1024] bf16
    bhalf* ch1b  = zb + 512 * 1024;                    // [512,1024] bf16
    float* spart = (float*)(ch1b + 512 * 1024);        // split-K partials (<=2M fp32)

    dim3 blk(256);
    const int EPB = (N_EDGES + 255) / 256;
    const int NPB = (N_NODES + 255) / 256;             // 79
    const int NWAVE = (N_NODES * 64) / 256;            // wave per node
    dim3 gnode(512 / 64, (N_NODES + 63) / 64);         // (8, 313) fused W|rW

    // ---------------- weight/input conversion ----------------
    WTab tab;
    tab.e[0] = {W1,    W1cat,             128, 256,   32};
    tab.e[1] = {rW1,   W1cat + 256 * 128, 128, 256,   64};
    tab.e[2] = {W2,    W2cat,             256, 256,  128};
    tab.e[3] = {rW2,   W2cat + 256 * 256, 256, 256,  192};
    tab.e[4] = {rk_W1, rkW1t,            2048, 1024, 2240};
    tab.e[5] = {rk_W2, rkW2t,            1024, 512,  2752};
    tab.e[6] = {c_W1,  cW1t,             1024, 1024, 3776};
    tab.e[7] = {c_W2,  cW2t,             1024, 512,  4288};
    wconv_batch<<<4288, blk, 0, stream>>>(tab);
    {
        int n4a = N_NODES * IN_FEATS / 4, n4b = 512 * 2048 / 4;
        conv_batch<<<(n4a + n4b + 255) / 256, blk, 0, stream>>>(node_feats, nfb, n4a,
                                                                rdkit, rdkb, n4b);
    }

    // ---------------- zero scratch (counts+cursor, both stats) ----------------
    hipMemsetAsync(counts, 0, 2 * N_NODES * sizeof(int), stream);
    hipMemsetAsync(stats1, 0, 2048 * sizeof(float), stream);

    // ---------------- CSR build ----------------
    csr_count<<<EPB, blk, 0, stream>>>(dst, counts);
    csr_scan_a<<<NPB, blk, 0, stream>>>(counts, bsum);
    csr_scan_b<<<1, 128, 0, stream>>>(bsum, NPB);
    csr_scan_c<<<NPB, blk, 0, stream>>>(counts, bsum, offsets);
    csr_fill<<<EPB, blk, 0, stream>>>(src, dst, offsets, cursor, eidx);
    csr_sort_wave<<<NWAVE, blk, 0, stream>>>(offsets, eidx);

    // ---------------- Layer 1 (fused m|r GEMM -> bf16) ----------------
    gemm_mfma<0,1><<<gnode, blk, 0, stream>>>(nfb, W1cat, buf_mr, nullptr,
                                              N_NODES, IN_FEATS, 512);
    edge_gather<<<NWAVE, blk, 0, stream>>>(buf_mr, 512, offsets, eidx, aggA);
    combine_stats<<<512, blk, 0, stream>>>(aggA, buf_mr + 256, 512, b1, rb1, aggA, stats1);
    bn_finalize<<<1, HID, 0, stream>>>(stats1, 1.0f / N_NODES);
    bn_row<0><<<NWAVE, blk, 0, stream>>>(aggA, stats1, g1, be1, h1b, nullptr, nullptr, nullptr, nullptr);

    // ---------------- Layer 2 (fused m|r GEMM -> bf16) ----------------
    gemm_mfma<0,1><<<gnode, blk, 0, stream>>>(h1b, W2cat, buf_mr, nullptr,
                                              N_NODES, HID, 512);
    edge_gather<<<NWAVE, blk, 0, stream>>>(buf_mr, 512, offsets, eidx, aggA);
    combine_stats<<<512, blk, 0, stream>>>(aggA, buf_mr + 256, 512, b2, rb2, aggA, stats2);
    bn_finalize<<<1, HID, 0, stream>>>(stats2, 1.0f / N_NODES);
    bn_row<1><<<NWAVE, blk, 0, stream>>>(aggA, stats2, g2, be2, nullptr, aggA, aw_W, aw_b, wbuf);

    // ---------------- Readout ----------------
    readout<<<N_GRAPHS, HID, 0, stream>>>(aggA, wbuf, gid, zb);

    // ---------------- RDKit branch (split-K) ----------------
    gemm_mfma<0,0><<<dim3(16, 8, 4), blk, 0, stream>>>(rdkb, rkW1t, spart, nullptr,
                                                       512, 2048, 1024);
    splitk_combine<1,1><<<512, blk, 0, stream>>>(spart, 4, 512, 1024, 1024, rk_b1, rkhb);
    gemm_mfma<0,0><<<dim3(8, 8, 8), blk, 0, stream>>>(rkhb, rkW2t, spart, nullptr,
                                                      512, 1024, 512);
    splitk_combine<1,1><<<256, blk, 0, stream>>>(spart, 8, 512, 512, 1024, rk_b2, zb + 512);

    // ---------------- Combined head (split-K) ----------------
    gemm_mfma<0,0><<<dim3(16, 8, 4), blk, 0, stream>>>(zb, cW1t, spart, nullptr,
                                                       512, 1024, 1024);
    splitk_combine<1,1><<<512, blk, 0, stream>>>(spart, 4, 512, 1024, 1024, c_b1, ch1b);
    gemm_mfma<0,0><<<dim3(8, 8, 8), blk, 0, stream>>>(ch1b, cW2t, spart, nullptr,
                                                      512, 1024, 512);
    splitk_combine_dot<<<512, 128, 0, stream>>>(spart, 8, 512, 512, c_b2, c_W3, c_b3, out);
}

// Round 8
// 290.279 us; speedup vs baseline: 9.1952x; 1.0638x over previous
//
#include <hip/hip_runtime.h>
#include <hip/hip_bf16.h>
#include <cstdint>
#include <cstddef>

#define N_NODES 20000
#define N_EDGES 320000
#define N_GRAPHS 512
#define IN_FEATS 128
#define HID 256

typedef __bf16 bhalf;
typedef __bf16 bhalf8 __attribute__((ext_vector_type(8)));
typedef __bf16 bhalf4 __attribute__((ext_vector_type(4)));
typedef __bf16 bhalf2 __attribute__((ext_vector_type(2)));
typedef float f32x4 __attribute__((ext_vector_type(4)));

// ---------------------------------------------------------------------------
// bf16 MFMA GEMM (head layers): C = A @ Bt^T. 64x64 tile, BK=64, 4 waves,
// register-prefetch. Split-K via gridDim.z (fp32 partials).
// ---------------------------------------------------------------------------
template<int RELU, int OUTBF16>
__global__ __launch_bounds__(256) void gemm_mfma(const bhalf* __restrict__ A,
                                                 const bhalf* __restrict__ Bt,
                                                 void* __restrict__ Cv,
                                                 const float* __restrict__ bias,
                                                 int M, int K, int ldc)
{
    __shared__ bhalf As[64 * 64];
    __shared__ bhalf Bs[64 * 64];

    const int t = threadIdx.x;
    const int lane = t & 63, wid = t >> 6;
    const int wm0 = (wid >> 1) * 32, wn0 = (wid & 1) * 32;
    const int m0 = blockIdx.y * 64, n0 = blockIdx.x * 64;
    const int S = gridDim.z, kz = blockIdx.z;
    const int Ks = K / S;

    const int srow = t >> 2;
    const int sc0 = (t & 3) << 3;

    f32x4 acc[2][2] = {};
    uint4 ra0, ra1, rb0, rb1;

    const bool mok = (m0 + srow) < M;
    const bhalf* Abase = A + (size_t)(m0 + srow) * K + (size_t)kz * Ks;
    const bhalf* Bbase = Bt + (size_t)(n0 + srow) * K + (size_t)kz * Ks;

    ra0 = mok ? *(const uint4*)(Abase + sc0)      : make_uint4(0u,0u,0u,0u);
    ra1 = mok ? *(const uint4*)(Abase + sc0 + 32) : make_uint4(0u,0u,0u,0u);
    rb0 = *(const uint4*)(Bbase + sc0);
    rb1 = *(const uint4*)(Bbase + sc0 + 32);

    const int swz = (srow & 7) << 3;
    for (int k0 = 0; k0 < Ks; k0 += 64) {
        __syncthreads();
        *(uint4*)&As[srow * 64 + (sc0 ^ swz)]        = ra0;
        *(uint4*)&As[srow * 64 + ((sc0 + 32) ^ swz)] = ra1;
        *(uint4*)&Bs[srow * 64 + (sc0 ^ swz)]        = rb0;
        *(uint4*)&Bs[srow * 64 + ((sc0 + 32) ^ swz)] = rb1;
        __syncthreads();
        if (k0 + 64 < Ks) {
            const bhalf* An = Abase + k0 + 64;
            const bhalf* Bn = Bbase + k0 + 64;
            ra0 = mok ? *(const uint4*)(An + sc0)      : make_uint4(0u,0u,0u,0u);
            ra1 = mok ? *(const uint4*)(An + sc0 + 32) : make_uint4(0u,0u,0u,0u);
            rb0 = *(const uint4*)(Bn + sc0);
            rb1 = *(const uint4*)(Bn + sc0 + 32);
        }
#pragma unroll
        for (int kb = 0; kb < 2; ++kb) {
            const int kc = kb * 32 + (lane >> 4) * 8;
            bhalf8 af[2], bfr[2];
#pragma unroll
            for (int i = 0; i < 2; ++i) {
                int rA = wm0 + i * 16 + (lane & 15);
                af[i] = *(const bhalf8*)&As[rA * 64 + (kc ^ ((rA & 7) << 3))];
                int rB = wn0 + i * 16 + (lane & 15);
                bfr[i] = *(const bhalf8*)&Bs[rB * 64 + (kc ^ ((rB & 7) << 3))];
            }
#pragma unroll
            for (int mi = 0; mi < 2; ++mi)
#pragma unroll
                for (int ni = 0; ni < 2; ++ni)
                    acc[mi][ni] = __builtin_amdgcn_mfma_f32_16x16x32_bf16(
                        af[mi], bfr[ni], acc[mi][ni], 0, 0, 0);
        }
    }

#pragma unroll
    for (int mi = 0; mi < 2; ++mi)
#pragma unroll
        for (int ni = 0; ni < 2; ++ni) {
            int col = n0 + wn0 + ni * 16 + (lane & 15);
            f32x4 v = acc[mi][ni];
            if (S > 1) {
#pragma unroll
                for (int r = 0; r < 4; ++r) {
                    int row = m0 + wm0 + mi * 16 + (lane >> 4) * 4 + r;
                    if (row < M)
                        ((float*)Cv)[((size_t)kz * M + row) * ldc + col] = v[r];
                }
            } else {
                float bb = bias ? bias[col] : 0.f;
#pragma unroll
                for (int r = 0; r < 4; ++r) {
                    int row = m0 + wm0 + mi * 16 + (lane >> 4) * 4 + r;
                    if (row < M) {
                        float x = v[r] + bb;
                        if (RELU) x = fmaxf(x, 0.f);
                        if (OUTBF16) ((bhalf*)Cv)[(size_t)row * ldc + col] = (bhalf)x;
                        else         ((float*)Cv)[(size_t)row * ldc + col] = x;
                    }
                }
            }
        }
}

// ---------------------------------------------------------------------------
// Dual bf16 GEMM (node layers): blocks [0,nx) compute A0 @ B0^T into cols
// [0, nx*64); blocks [nx, 2nx) compute A1 @ B1^T into cols [nx*64, 2nx*64).
// Same K for both. Output bf16, no bias. M guarded.
// ---------------------------------------------------------------------------
__global__ __launch_bounds__(256) void gemm_dual(const bhalf* __restrict__ A0,
                                                 const bhalf* __restrict__ B0,
                                                 const bhalf* __restrict__ A1,
                                                 const bhalf* __restrict__ B1,
                                                 bhalf* __restrict__ C,
                                                 int M, int K, int nx, int ldc)
{
    __shared__ bhalf As[64 * 64];
    __shared__ bhalf Bs[64 * 64];

    const int t = threadIdx.x;
    const int lane = t & 63, wid = t >> 6;
    const int wm0 = (wid >> 1) * 32, wn0 = (wid & 1) * 32;
    const int bx = blockIdx.x;
    const bool h1 = bx >= nx;
    const bhalf* A  = h1 ? A1 : A0;
    const bhalf* Bt = h1 ? B1 : B0;
    const int nb = h1 ? bx - nx : bx;     // tile row within Bt
    const int m0 = blockIdx.y * 64;
    const int n0c = bx * 64;              // output column base

    const int srow = t >> 2;
    const int sc0 = (t & 3) << 3;

    f32x4 acc[2][2] = {};
    uint4 ra0, ra1, rb0, rb1;

    const bool mok = (m0 + srow) < M;
    const bhalf* Abase = A + (size_t)(m0 + srow) * K;
    const bhalf* Bbase = Bt + (size_t)(nb * 64 + srow) * K;

    ra0 = mok ? *(const uint4*)(Abase + sc0)      : make_uint4(0u,0u,0u,0u);
    ra1 = mok ? *(const uint4*)(Abase + sc0 + 32) : make_uint4(0u,0u,0u,0u);
    rb0 = *(const uint4*)(Bbase + sc0);
    rb1 = *(const uint4*)(Bbase + sc0 + 32);

    const int swz = (srow & 7) << 3;
    for (int k0 = 0; k0 < K; k0 += 64) {
        __syncthreads();
        *(uint4*)&As[srow * 64 + (sc0 ^ swz)]        = ra0;
        *(uint4*)&As[srow * 64 + ((sc0 + 32) ^ swz)] = ra1;
        *(uint4*)&Bs[srow * 64 + (sc0 ^ swz)]        = rb0;
        *(uint4*)&Bs[srow * 64 + ((sc0 + 32) ^ swz)] = rb1;
        __syncthreads();
        if (k0 + 64 < K) {
            const bhalf* An = Abase + k0 + 64;
            const bhalf* Bn = Bbase + k0 + 64;
            ra0 = mok ? *(const uint4*)(An + sc0)      : make_uint4(0u,0u,0u,0u);
            ra1 = mok ? *(const uint4*)(An + sc0 + 32) : make_uint4(0u,0u,0u,0u);
            rb0 = *(const uint4*)(Bn + sc0);
            rb1 = *(const uint4*)(Bn + sc0 + 32);
        }
#pragma unroll
        for (int kb = 0; kb < 2; ++kb) {
            const int kc = kb * 32 + (lane >> 4) * 8;
            bhalf8 af[2], bfr[2];
#pragma unroll
            for (int i = 0; i < 2; ++i) {
                int rA = wm0 + i * 16 + (lane & 15);
                af[i] = *(const bhalf8*)&As[rA * 64 + (kc ^ ((rA & 7) << 3))];
                int rB = wn0 + i * 16 + (lane & 15);
                bfr[i] = *(const bhalf8*)&Bs[rB * 64 + (kc ^ ((rB & 7) << 3))];
            }
#pragma unroll
            for (int mi = 0; mi < 2; ++mi)
#pragma unroll
                for (int ni = 0; ni < 2; ++ni)
                    acc[mi][ni] = __builtin_amdgcn_mfma_f32_16x16x32_bf16(
                        af[mi], bfr[ni], acc[mi][ni], 0, 0, 0);
        }
    }

#pragma unroll
    for (int mi = 0; mi < 2; ++mi)
#pragma unroll
        for (int ni = 0; ni < 2; ++ni) {
            int col = n0c + wn0 + ni * 16 + (lane & 15);
            f32x4 v = acc[mi][ni];
#pragma unroll
            for (int r = 0; r < 4; ++r) {
                int row = m0 + wm0 + mi * 16 + (lane >> 4) * 4 + r;
                if (row < M)
                    C[(size_t)row * ldc + col] = (bhalf)v[r];
            }
        }
}

// sum S split-K partials + bias + act
template<int RELU, int OUTBF16>
__global__ __launch_bounds__(256) void splitk_combine(const float* __restrict__ part,
                                                      int S, int M, int N, int ldo,
                                                      const float* __restrict__ bias,
                                                      void* __restrict__ outv)
{
    int i = blockIdx.x * blockDim.x + threadIdx.x;
    int n4 = N >> 2;
    if (i >= M * n4) return;
    int row = i / n4, c4 = (i - row * n4) << 2;
    float4 s = make_float4(0.f, 0.f, 0.f, 0.f);
    for (int z = 0; z < S; ++z) {
        float4 p = *(const float4*)(part + ((size_t)z * M + row) * N + c4);
        s.x += p.x; s.y += p.y; s.z += p.z; s.w += p.w;
    }
    float4 bb = *(const float4*)(bias + c4);
    s.x += bb.x; s.y += bb.y; s.z += bb.z; s.w += bb.w;
    if (RELU) {
        s.x = fmaxf(s.x, 0.f); s.y = fmaxf(s.y, 0.f);
        s.z = fmaxf(s.z, 0.f); s.w = fmaxf(s.w, 0.f);
    }
    if (OUTBF16) {
        bhalf4 o = {(bhalf)s.x, (bhalf)s.y, (bhalf)s.z, (bhalf)s.w};
        *(bhalf4*)((bhalf*)outv + (size_t)row * ldo + c4) = o;
    } else {
        *(float4*)((float*)outv + (size_t)row * ldo + c4) = s;
    }
}

// last head layer: combine S partials + bias + relu, dot with W3
__global__ __launch_bounds__(128) void splitk_combine_dot(const float* __restrict__ part,
                                                          int S, int M, int N,
                                                          const float* __restrict__ bias,
                                                          const float* __restrict__ W3,
                                                          const float* __restrict__ b3,
                                                          float* __restrict__ out)
{
    int row = blockIdx.x, t = threadIdx.x;
    int c4 = t << 2;
    float4 s = make_float4(0.f, 0.f, 0.f, 0.f);
    for (int z = 0; z < S; ++z) {
        float4 p = *(const float4*)(part + ((size_t)z * M + row) * N + c4);
        s.x += p.x; s.y += p.y; s.z += p.z; s.w += p.w;
    }
    float4 bb = *(const float4*)(bias + c4);
    float4 w = *(const float4*)(W3 + c4);
    float d = fmaxf(s.x + bb.x, 0.f) * w.x + fmaxf(s.y + bb.y, 0.f) * w.y
            + fmaxf(s.z + bb.z, 0.f) * w.z + fmaxf(s.w + bb.w, 0.f) * w.w;
#pragma unroll
    for (int off = 32; off > 0; off >>= 1) d += __shfl_xor(d, off);
    __shared__ float ws2[2];
    if ((t & 63) == 0) ws2[t >> 6] = d;
    __syncthreads();
    if (t == 0) out[row] = ws2[0] + ws2[1] + b3[0];
}

// ---------------------------------------------------------------------------
// Batched weight transpose+convert
// ---------------------------------------------------------------------------
struct WEnt { const float* src; bhalf* dst; int K; int N; int tiles_end; };
struct WTab { WEnt e[8]; };

__global__ __launch_bounds__(256) void wconv_batch(WTab tab)
{
    __shared__ float tile[32][33];
    int tb = blockIdx.x;
    int idx = 0;
#pragma unroll
    for (int i = 0; i < 8; ++i)
        if (tb >= tab.e[i].tiles_end) idx = i + 1;
    const WEnt& E = tab.e[idx];
    int t0 = idx ? tab.e[idx - 1].tiles_end : 0;
    int lt = tb - t0;
    int tX = E.N >> 5;
    int bx = (lt % tX) << 5;
    int by = (lt / tX) << 5;
    int tx = threadIdx.x & 31, ty = threadIdx.x >> 5;
#pragma unroll
    for (int i = 0; i < 32; i += 8)
        tile[ty + i][tx] = E.src[(size_t)(by + ty + i) * E.N + bx + tx];
    __syncthreads();
#pragma unroll
    for (int i = 0; i < 32; i += 8)
        E.dst[(size_t)(bx + ty + i) * E.K + by + tx] = (bhalf)tile[tx][ty + i];
}

__global__ void conv_batch(const float* __restrict__ a, bhalf* __restrict__ oa, int n4a,
                           const float* __restrict__ b, bhalf* __restrict__ ob, int n4b)
{
    int i = blockIdx.x * blockDim.x + threadIdx.x;
    const float* s; bhalf* d; int j;
    if (i < n4a) { s = a; d = oa; j = i; }
    else { j = i - n4a; if (j >= n4b) return; s = b; d = ob; }
    float4 v = ((const float4*)s)[j];
    bhalf4 o = {(bhalf)v.x, (bhalf)v.y, (bhalf)v.z, (bhalf)v.w};
    ((bhalf4*)d)[j] = o;
}

// ---------------------------------------------------------------------------
// CSR build
// ---------------------------------------------------------------------------
__global__ void csr_count(const int* __restrict__ dst, int* __restrict__ counts)
{
    int e = blockIdx.x * blockDim.x + threadIdx.x;
    if (e >= N_EDGES) return;
    atomicAdd(&counts[dst[e]], 1);
}

__global__ __launch_bounds__(256) void csr_scan_a(const int* __restrict__ counts,
                                                  int* __restrict__ bsum)
{
    int i = blockIdx.x * 256 + threadIdx.x;
    int v = (i < N_NODES) ? counts[i] : 0;
#pragma unroll
    for (int off = 32; off > 0; off >>= 1) v += __shfl_down(v, off);
    __shared__ int ws[4];
    if ((threadIdx.x & 63) == 0) ws[threadIdx.x >> 6] = v;
    __syncthreads();
    if (threadIdx.x == 0) bsum[blockIdx.x] = ws[0] + ws[1] + ws[2] + ws[3];
}

__global__ __launch_bounds__(128) void csr_scan_b(int* __restrict__ bsum, int nb)
{
    __shared__ int tmp[128];
    int t = threadIdx.x;
    tmp[t] = (t < nb) ? bsum[t] : 0;
    __syncthreads();
    if (t == 0) {
        int run = 0;
        for (int i = 0; i < nb; ++i) { int c = tmp[i]; tmp[i] = run; run += c; }
    }
    __syncthreads();
    if (t < nb) bsum[t] = tmp[t];
}

__global__ __launch_bounds__(256) void csr_scan_c(const int* __restrict__ counts,
                                                  const int* __restrict__ bsum,
                                                  int* __restrict__ offsets)
{
    int t = threadIdx.x, b = blockIdx.x;
    int i = b * 256 + t;
    int v = (i < N_NODES) ? counts[i] : 0;
    int x = v;
#pragma unroll
    for (int off = 1; off < 64; off <<= 1) {
        int y = __shfl_up(x, off);
        if ((t & 63) >= off) x += y;
    }
    __shared__ int wsum[4];
    if ((t & 63) == 63) wsum[t >> 6] = x;
    __syncthreads();
    int add = bsum[b];
    for (int w = 0; w < (t >> 6); ++w) add += wsum[w];
    int excl = x - v + add;
    if (i < N_NODES) offsets[i] = excl;
    if (i == N_NODES - 1) offsets[N_NODES] = excl + v;
}

__global__ void csr_fill(const int* __restrict__ src, const int* __restrict__ dst,
                         const int* __restrict__ offsets, int* __restrict__ cursor,
                         int* __restrict__ eidx)
{
    int e = blockIdx.x * blockDim.x + threadIdx.x;
    if (e >= N_EDGES) return;
    int d = dst[e];
    int slot = offsets[d] + atomicAdd(&cursor[d], 1);
    eidx[slot] = src[e];
}

__global__ void csr_sort_wave(const int* __restrict__ offsets, int* __restrict__ eidx)
{
    int gidx = blockIdx.x * blockDim.x + threadIdx.x;
    int n = gidx >> 6, lane = gidx & 63;
    if (n >= N_NODES) return;
    int lo = offsets[n], hi = offsets[n + 1];
    int cnt = hi - lo;
    if (cnt <= 1) return;
    if (cnt <= 64) {
        int v = (lane < cnt) ? eidx[lo + lane] : 0x7fffffff;
        int rank = 0;
        for (int j = 0; j < cnt; ++j) {
            int vj = __shfl(v, j);
            if (vj < v || (vj == v && j < lane)) ++rank;
        }
        if (lane < cnt) eidx[lo + rank] = v;
    } else if (lane == 0) {
        for (int i = lo + 1; i < hi; ++i) {
            int v = eidx[i]; int j = i - 1;
            while (j >= lo && eidx[j] > v) { eidx[j + 1] = eidx[j]; --j; }
            eidx[j + 1] = v;
        }
    }
}

// ---------------------------------------------------------------------------
// Gather-aggregate on bf16 features (COLS = 128 or 256), fp32 accumulate,
// bf16 output. Wave per node.
// ---------------------------------------------------------------------------
template<int COLS>
__global__ __launch_bounds__(256) void edge_gather_b(const bhalf* __restrict__ m,
                                                     const int* __restrict__ offsets,
                                                     const int* __restrict__ eidx,
                                                     bhalf* __restrict__ agg)
{
    int gidx = blockIdx.x * blockDim.x + threadIdx.x;
    int n = gidx >> 6, lane = gidx & 63;
    if (n >= N_NODES) return;
    int lo = offsets[n], hi = offsets[n + 1];
    if (COLS == 256) {
        const bhalf* base = m + lane * 4;
        float4 acc = make_float4(0.f, 0.f, 0.f, 0.f);
        int i = lo;
        for (; i + 2 <= hi; i += 2) {
            bhalf4 v0 = *(const bhalf4*)(base + (size_t)eidx[i] * COLS);
            bhalf4 v1 = *(const bhalf4*)(base + (size_t)eidx[i + 1] * COLS);
            acc.x += (float)v0.x + (float)v1.x;
            acc.y += (float)v0.y + (float)v1.y;
            acc.z += (float)v0.z + (float)v1.z;
            acc.w += (float)v0.w + (float)v1.w;
        }
        if (i < hi) {
            bhalf4 v0 = *(const bhalf4*)(base + (size_t)eidx[i] * COLS);
            acc.x += (float)v0.x; acc.y += (float)v0.y;
            acc.z += (float)v0.z; acc.w += (float)v0.w;
        }
        bhalf4 o = {(bhalf)acc.x, (bhalf)acc.y, (bhalf)acc.z, (bhalf)acc.w};
        *(bhalf4*)(agg + (size_t)n * COLS + lane * 4) = o;
    } else {
        const bhalf* base = m + lane * 2;
        float ax = 0.f, ay = 0.f;
        int i = lo;
        for (; i + 2 <= hi; i += 2) {
            bhalf2 v0 = *(const bhalf2*)(base + (size_t)eidx[i] * COLS);
            bhalf2 v1 = *(const bhalf2*)(base + (size_t)eidx[i + 1] * COLS);
            ax += (float)v0.x + (float)v1.x;
            ay += (float)v0.y + (float)v1.y;
        }
        if (i < hi) {
            bhalf2 v0 = *(const bhalf2*)(base + (size_t)eidx[i] * COLS);
            ax += (float)v0.x; ay += (float)v0.y;
        }
        bhalf2 o = {(bhalf)ax, (bhalf)ay};
        *(bhalf2*)(agg + (size_t)n * COLS + lane * 2) = o;
    }
}

// ---------------------------------------------------------------------------
// v = relu(m + b) + relu(r + rb); m,r are the two bf16 halves of buf_mr.
// Accumulates per-column sum/sumsq into stats (raw).
// ---------------------------------------------------------------------------
__global__ __launch_bounds__(256) void combine_stats(const bhalf* __restrict__ mr, int ld,
                                                     const float* __restrict__ b,
                                                     const float* __restrict__ rb,
                                                     float* __restrict__ out,
                                                     float* __restrict__ stats)
{
    int col = threadIdx.x;
    float bb = b[col], rbb = rb[col];
    float s = 0.f, s2 = 0.f;
    for (int row = blockIdx.x; row < N_NODES; row += gridDim.x) {
        float mv = (float)mr[(size_t)row * ld + col];
        float rv = (float)mr[(size_t)row * ld + 256 + col];
        float v = fmaxf(mv + bb, 0.f) + fmaxf(rv + rbb, 0.f);
        out[(size_t)row * HID + col] = v;
        s += v;
        s2 += v * v;
    }
    atomicAdd(&stats[col], s);
    atomicAdd(&stats[HID + col], s2);
}

// ---------------------------------------------------------------------------
// Wave-per-node BN with inline finalize (stats holds raw sum|sumsq).
// MODE 0: write bf16 h. MODE 1: write fp32 in-place + node attention weight.
// ---------------------------------------------------------------------------
template<int MODE>
__global__ __launch_bounds__(256) void bn_row(const float* __restrict__ h,
                                              const float* __restrict__ stats,
                                              float inv_n,
                                              const float* __restrict__ g,
                                              const float* __restrict__ be,
                                              bhalf* __restrict__ outb,
                                              float* __restrict__ outf,
                                              const float* __restrict__ awW,
                                              const float* __restrict__ awb,
                                              float* __restrict__ w)
{
    int gidx = blockIdx.x * blockDim.x + threadIdx.x;
    int n = gidx >> 6, lane = gidx & 63;
    if (n >= N_NODES) return;
    int col = lane * 4;
    float4 v  = *(const float4*)(h + (size_t)n * HID + col);
    float4 sm = *(const float4*)(stats + col);
    float4 sq = *(const float4*)(stats + HID + col);
    float4 gg = *(const float4*)(g + col);
    float4 bb = *(const float4*)(be + col);
    float mux = sm.x * inv_n, muy = sm.y * inv_n, muz = sm.z * inv_n, muw = sm.w * inv_n;
    float rsx = rsqrtf(sq.x * inv_n - mux * mux + 1e-5f);
    float rsy = rsqrtf(sq.y * inv_n - muy * muy + 1e-5f);
    float rsz = rsqrtf(sq.z * inv_n - muz * muz + 1e-5f);
    float rsw = rsqrtf(sq.w * inv_n - muw * muw + 1e-5f);
    float4 o;
    o.x = gg.x * (v.x - mux) * rsx + bb.x;
    o.y = gg.y * (v.y - muy) * rsy + bb.y;
    o.z = gg.z * (v.z - muz) * rsz + bb.z;
    o.w = gg.w * (v.w - muw) * rsw + bb.w;
    if (MODE == 0) {
        bhalf4 ob = {(bhalf)o.x, (bhalf)o.y, (bhalf)o.z, (bhalf)o.w};
        *(bhalf4*)(outb + (size_t)n * HID + col) = ob;
    } else {
        *(float4*)(outf + (size_t)n * HID + col) = o;
        float4 wv = *(const float4*)(awW + col);
        float d = o.x * wv.x + o.y * wv.y + o.z * wv.z + o.w * wv.w;
#pragma unroll
        for (int off = 32; off > 0; off >>= 1) d += __shfl_xor(d, off);
        if (lane == 0) w[n] = 1.f / (1.f + expf(-(d + awb[0])));
    }
}

// ---------------------------------------------------------------------------
__global__ __launch_bounds__(256) void readout(const float* __restrict__ h,
                                               const float* __restrict__ w,
                                               const int* __restrict__ gid,
                                               bhalf* __restrict__ z)
{
    int g = blockIdx.x, col = threadIdx.x;
    int lo = 0, hi = N_NODES;
    while (lo < hi) { int mid = (lo + hi) >> 1; if (gid[mid] < g) lo = mid + 1; else hi = mid; }
    int start = lo;
    hi = N_NODES;
    while (lo < hi) { int mid = (lo + hi) >> 1; if (gid[mid] <= g) lo = mid + 1; else hi = mid; }
    int end = lo;
    float s = 0.f, mx = -INFINITY;
    for (int n = start; n < end; ++n) {
        float v = h[(size_t)n * HID + col];
        s = fmaf(v, w[n], s);
        mx = fmaxf(mx, v);
    }
    z[(size_t)g * 1024 + col] = (bhalf)s;
    z[(size_t)g * 1024 + HID + col] = (bhalf)mx;
}

// ---------------------------------------------------------------------------
extern "C" void kernel_launch(void* const* d_in, const int* in_sizes, int n_in,
                              void* d_out, int out_size, void* d_ws, size_t ws_size,
                              hipStream_t stream)
{
    (void)in_sizes; (void)n_in; (void)out_size; (void)ws_size;

    const float* node_feats = (const float*)d_in[0];
    const float* rdkit      = (const float*)d_in[1];
    const int*   src        = (const int*)d_in[2];
    const int*   dst        = (const int*)d_in[3];
    const int*   gid        = (const int*)d_in[4];
    const float* W1  = (const float*)d_in[5];
    const float* b1  = (const float*)d_in[6];
    const float* rW1 = (const float*)d_in[7];
    const float* rb1 = (const float*)d_in[8];
    const float* g1  = (const float*)d_in[9];
    const float* be1 = (const float*)d_in[10];
    const float* W2  = (const float*)d_in[11];
    const float* b2  = (const float*)d_in[12];
    const float* rW2 = (const float*)d_in[13];
    const float* rb2 = (const float*)d_in[14];
    const float* g2  = (const float*)d_in[15];
    const float* be2 = (const float*)d_in[16];
    const float* aw_W  = (const float*)d_in[17];
    const float* aw_b  = (const float*)d_in[18];
    const float* rk_W1 = (const float*)d_in[19];
    const float* rk_b1 = (const float*)d_in[20];
    const float* rk_W2 = (const float*)d_in[21];
    const float* rk_b2 = (const float*)d_in[22];
    const float* c_W1  = (const float*)d_in[23];
    const float* c_b1  = (const float*)d_in[24];
    const float* c_W2  = (const float*)d_in[25];
    const float* c_b2  = (const float*)d_in[26];
    const float* c_W3  = (const float*)d_in[27];
    const float* c_b3  = (const float*)d_in[28];

    float* out = (float*)d_out;

    const size_t NODE = (size_t)N_NODES * HID;         // 5,120,000
    bhalf* buf_mr = (bhalf*)d_ws;                      // [20000,512] bf16: m | r
    float* vbuf   = (float*)(buf_mr + (size_t)N_NODES * 512);  // [20000,256] fp32
    bhalf* h1b    = (bhalf*)(vbuf + NODE);             // [20000,256] bf16 (nfb aliases)
    bhalf* nfb    = h1b;                               // [20000,128] bf16
    bhalf* aggb   = h1b + NODE;                        // [20000,256] bf16 (agg scratch)
    bhalf* W1cat  = aggb + NODE;                       // [512,128]  = W1^T | rW1^T
    bhalf* W2cat  = W1cat + 512 * 128;                 // [512,256]  = W2^T | rW2^T
    bhalf* rkW1t  = W2cat + 512 * 256;                 // [1024,2048]
    bhalf* rkW2t  = rkW1t + 2048 * 1024;               // [512,1024]
    bhalf* cW1t   = rkW2t + 1024 * 512;                // [1024,1024]
    bhalf* cW2t   = cW1t + 1024 * 1024;                // [512,1024]
    bhalf* rdkb   = cW2t + 1024 * 512;                 // [512,2048]
    float* stats1 = (float*)(rdkb + 512 * 2048);       // 512 raw sum|sumsq
    float* stats2 = stats1 + 512;                      // 512
    float* wbuf   = stats2 + 512;                      // 20000
    int*   counts  = (int*)(wbuf + N_NODES);           // N (adjacent w/ cursor)
    int*   cursor  = counts + N_NODES;                 // N
    int*   offsets = cursor + N_NODES;                 // N+1
    int*   eidx    = offsets + N_NODES + 1;            // N_EDGES
    int*   bsum    = eidx + N_EDGES;                   // 128
    // head buffers alias buf_mr (free after layer-2 combine)
    bhalf* rkhb  = (bhalf*)buf_mr;                     // [512,1024] bf16
    bhalf* zb    = rkhb + 512 * 1024;                  // [512,1024] bf16
    bhalf* ch1b  = zb + 512 * 1024;                    // [512,1024] bf16
    float* spart = (float*)(ch1b + 512 * 1024);        // split-K partials (<=2M fp32)

    dim3 blk(256);
    const int EPB = (N_EDGES + 255) / 256;
    const int NPB = (N_NODES + 255) / 256;             // 79
    const int NWAVE = (N_NODES * 64) / 256;            // wave per node
    dim3 gnode(8, (N_NODES + 63) / 64);                // dual GEMM: 2x4 col tiles

    // ---------------- weight/input conversion ----------------
    WTab tab;
    tab.e[0] = {W1,    W1cat,             128, 256,   32};
    tab.e[1] = {rW1,   W1cat + 256 * 128, 128, 256,   64};
    tab.e[2] = {W2,    W2cat,             256, 256,  128};
    tab.e[3] = {rW2,   W2cat + 256 * 256, 256, 256,  192};
    tab.e[4] = {rk_W1, rkW1t,            2048, 1024, 2240};
    tab.e[5] = {rk_W2, rkW2t,            1024, 512,  2752};
    tab.e[6] = {c_W1,  cW1t,             1024, 1024, 3776};
    tab.e[7] = {c_W2,  cW2t,             1024, 512,  4288};
    wconv_batch<<<4288, blk, 0, stream>>>(tab);
    {
        int n4a = N_NODES * IN_FEATS / 4, n4b = 512 * 2048 / 4;
        conv_batch<<<(n4a + n4b + 255) / 256, blk, 0, stream>>>(node_feats, nfb, n4a,
                                                                rdkit, rdkb, n4b);
    }

    // ---------------- zero scratch ----------------
    hipMemsetAsync(counts, 0, 2 * N_NODES * sizeof(int), stream);
    hipMemsetAsync(stats1, 0, 1024 * sizeof(float), stream);

    // ---------------- CSR build ----------------
    csr_count<<<EPB, blk, 0, stream>>>(dst, counts);
    csr_scan_a<<<NPB, blk, 0, stream>>>(counts, bsum);
    csr_scan_b<<<1, 128, 0, stream>>>(bsum, NPB);
    csr_scan_c<<<NPB, blk, 0, stream>>>(counts, bsum, offsets);
    csr_fill<<<EPB, blk, 0, stream>>>(src, dst, offsets, cursor, eidx);
    csr_sort_wave<<<NWAVE, blk, 0, stream>>>(offsets, eidx);

    // ---------------- Layer 1: agg(X) -> dual GEMM -> combine -> BN ----------
    edge_gather_b<IN_FEATS><<<NWAVE, blk, 0, stream>>>(nfb, offsets, eidx, aggb);
    gemm_dual<<<gnode, blk, 0, stream>>>(aggb, W1cat, nfb, W1cat + 256 * 128,
                                         buf_mr, N_NODES, IN_FEATS, 4, 512);
    combine_stats<<<256, blk, 0, stream>>>(buf_mr, 512, b1, rb1, vbuf, stats1);
    bn_row<0><<<NWAVE, blk, 0, stream>>>(vbuf, stats1, 1.0f / N_NODES, g1, be1,
                                         h1b, nullptr, nullptr, nullptr, nullptr);

    // ---------------- Layer 2 ----------------
    edge_gather_b<HID><<<NWAVE, blk, 0, stream>>>(h1b, offsets, eidx, aggb);
    gemm_dual<<<gnode, blk, 0, stream>>>(aggb, W2cat, h1b, W2cat + 256 * 256,
                                         buf_mr, N_NODES, HID, 4, 512);
    combine_stats<<<256, blk, 0, stream>>>(buf_mr, 512, b2, rb2, vbuf, stats2);
    bn_row<1><<<NWAVE, blk, 0, stream>>>(vbuf, stats2, 1.0f / N_NODES, g2, be2,
                                         nullptr, vbuf, aw_W, aw_b, wbuf);

    // ---------------- Readout ----------------
    readout<<<N_GRAPHS, HID, 0, stream>>>(vbuf, wbuf, gid, zb);

    // ---------------- RDKit branch (split-K) ----------------
    gemm_mfma<0,0><<<dim3(16, 8, 4), blk, 0, stream>>>(rdkb, rkW1t, spart, nullptr,
                                                       512, 2048, 1024);
    splitk_combine<1,1><<<512, blk, 0, stream>>>(spart, 4, 512, 1024, 1024, rk_b1, rkhb);
    gemm_mfma<0,0><<<dim3(8, 8, 8), blk, 0, stream>>>(rkhb, rkW2t, spart, nullptr,
                                                      512, 1024, 512);
    splitk_combine<1,1><<<256, blk, 0, stream>>>(spart, 8, 512, 512, 1024, rk_b2, zb + 512);

    // ---------------- Combined head (split-K) ----------------
    gemm_mfma<0,0><<<dim3(16, 8, 4), blk, 0, stream>>>(zb, cW1t, spart, nullptr,
                                                       512, 1024, 1024);
    splitk_combine<1,1><<<512, blk, 0, stream>>>(spart, 4, 512, 1024, 1024, c_b1, ch1b);
    gemm_mfma<0,0><<<dim3(8, 8, 8), blk, 0, stream>>>(ch1b, cW2t, spart, nullptr,
                                                      512, 1024, 512);
    splitk_combine_dot<<<512, 128, 0, stream>>>(spart, 8, 512, 512, c_b2, c_W3, c_b3, out);
}

// Round 9
// 280.893 us; speedup vs baseline: 9.5025x; 1.0334x over previous
//
#include <hip/hip_runtime.h>
#include <hip/hip_bf16.h>
#include <cstdint>
#include <cstddef>

#define N_NODES 20000
#define N_EDGES 320000
#define N_GRAPHS 512
#define IN_FEATS 128
#define HID 256

typedef __bf16 bhalf;
typedef __bf16 bhalf8 __attribute__((ext_vector_type(8)));
typedef __bf16 bhalf4 __attribute__((ext_vector_type(4)));
typedef __bf16 bhalf2 __attribute__((ext_vector_type(2)));
typedef float f32x4 __attribute__((ext_vector_type(4)));

// ---------------------------------------------------------------------------
// bf16 MFMA GEMM (head layers): C = A @ Bt^T. 64x64 tile, BK=64, 4 waves,
// register-prefetch. Split-K via gridDim.z (fp32 partials).
// ---------------------------------------------------------------------------
template<int RELU, int OUTBF16>
__global__ __launch_bounds__(256) void gemm_mfma(const bhalf* __restrict__ A,
                                                 const bhalf* __restrict__ Bt,
                                                 void* __restrict__ Cv,
                                                 const float* __restrict__ bias,
                                                 int M, int K, int ldc)
{
    __shared__ bhalf As[64 * 64];
    __shared__ bhalf Bs[64 * 64];

    const int t = threadIdx.x;
    const int lane = t & 63, wid = t >> 6;
    const int wm0 = (wid >> 1) * 32, wn0 = (wid & 1) * 32;
    const int m0 = blockIdx.y * 64, n0 = blockIdx.x * 64;
    const int S = gridDim.z, kz = blockIdx.z;
    const int Ks = K / S;

    const int srow = t >> 2;
    const int sc0 = (t & 3) << 3;

    f32x4 acc[2][2] = {};
    uint4 ra0, ra1, rb0, rb1;

    const bool mok = (m0 + srow) < M;
    const bhalf* Abase = A + (size_t)(m0 + srow) * K + (size_t)kz * Ks;
    const bhalf* Bbase = Bt + (size_t)(n0 + srow) * K + (size_t)kz * Ks;

    ra0 = mok ? *(const uint4*)(Abase + sc0)      : make_uint4(0u,0u,0u,0u);
    ra1 = mok ? *(const uint4*)(Abase + sc0 + 32) : make_uint4(0u,0u,0u,0u);
    rb0 = *(const uint4*)(Bbase + sc0);
    rb1 = *(const uint4*)(Bbase + sc0 + 32);

    const int swz = (srow & 7) << 3;
    for (int k0 = 0; k0 < Ks; k0 += 64) {
        __syncthreads();
        *(uint4*)&As[srow * 64 + (sc0 ^ swz)]        = ra0;
        *(uint4*)&As[srow * 64 + ((sc0 + 32) ^ swz)] = ra1;
        *(uint4*)&Bs[srow * 64 + (sc0 ^ swz)]        = rb0;
        *(uint4*)&Bs[srow * 64 + ((sc0 + 32) ^ swz)] = rb1;
        __syncthreads();
        if (k0 + 64 < Ks) {
            const bhalf* An = Abase + k0 + 64;
            const bhalf* Bn = Bbase + k0 + 64;
            ra0 = mok ? *(const uint4*)(An + sc0)      : make_uint4(0u,0u,0u,0u);
            ra1 = mok ? *(const uint4*)(An + sc0 + 32) : make_uint4(0u,0u,0u,0u);
            rb0 = *(const uint4*)(Bn + sc0);
            rb1 = *(const uint4*)(Bn + sc0 + 32);
        }
#pragma unroll
        for (int kb = 0; kb < 2; ++kb) {
            const int kc = kb * 32 + (lane >> 4) * 8;
            bhalf8 af[2], bfr[2];
#pragma unroll
            for (int i = 0; i < 2; ++i) {
                int rA = wm0 + i * 16 + (lane & 15);
                af[i] = *(const bhalf8*)&As[rA * 64 + (kc ^ ((rA & 7) << 3))];
                int rB = wn0 + i * 16 + (lane & 15);
                bfr[i] = *(const bhalf8*)&Bs[rB * 64 + (kc ^ ((rB & 7) << 3))];
            }
#pragma unroll
            for (int mi = 0; mi < 2; ++mi)
#pragma unroll
                for (int ni = 0; ni < 2; ++ni)
                    acc[mi][ni] = __builtin_amdgcn_mfma_f32_16x16x32_bf16(
                        af[mi], bfr[ni], acc[mi][ni], 0, 0, 0);
        }
    }

#pragma unroll
    for (int mi = 0; mi < 2; ++mi)
#pragma unroll
        for (int ni = 0; ni < 2; ++ni) {
            int col = n0 + wn0 + ni * 16 + (lane & 15);
            f32x4 v = acc[mi][ni];
            if (S > 1) {
#pragma unroll
                for (int r = 0; r < 4; ++r) {
                    int row = m0 + wm0 + mi * 16 + (lane >> 4) * 4 + r;
                    if (row < M)
                        ((float*)Cv)[((size_t)kz * M + row) * ldc + col] = v[r];
                }
            } else {
                float bb = bias ? bias[col] : 0.f;
#pragma unroll
                for (int r = 0; r < 4; ++r) {
                    int row = m0 + wm0 + mi * 16 + (lane >> 4) * 4 + r;
                    if (row < M) {
                        float x = v[r] + bb;
                        if (RELU) x = fmaxf(x, 0.f);
                        if (OUTBF16) ((bhalf*)Cv)[(size_t)row * ldc + col] = (bhalf)x;
                        else         ((float*)Cv)[(size_t)row * ldc + col] = x;
                    }
                }
            }
        }
}

// ---------------------------------------------------------------------------
// Fused GCN layer GEMM: per block computes BOTH m = Aagg @ BW^T and
// r = Ax @ BrW^T on the same 64x64 (row,col) tile, then epilogue
// v = relu(m+b) + relu(r+rb) -> bf16, plus per-column sum/sumsq atomics.
// K%64==0; grid (HID/64, ceil(M/64)). stats = raw [sum(256)|sumsq(256)].
// ---------------------------------------------------------------------------
__global__ __launch_bounds__(256) void gcn_gemm_fused(const bhalf* __restrict__ Aagg,
                                                      const bhalf* __restrict__ Ax,
                                                      const bhalf* __restrict__ BW,
                                                      const bhalf* __restrict__ BrW,
                                                      const float* __restrict__ b,
                                                      const float* __restrict__ rb,
                                                      bhalf* __restrict__ vout,
                                                      float* __restrict__ stats,
                                                      int M, int K)
{
    __shared__ bhalf As0[64 * 64];
    __shared__ bhalf As1[64 * 64];
    __shared__ bhalf Bs0[64 * 64];
    __shared__ bhalf Bs1[64 * 64];
    __shared__ float ssum[64], ssq[64];

    const int t = threadIdx.x;
    const int lane = t & 63, wid = t >> 6;
    const int wm0 = (wid >> 1) * 32, wn0 = (wid & 1) * 32;
    const int m0 = blockIdx.y * 64, n0 = blockIdx.x * 64;

    const int srow = t >> 2;
    const int sc0 = (t & 3) << 3;

    f32x4 acc0[2][2] = {};
    f32x4 acc1[2][2] = {};
    uint4 pa0[2], pa1[2], pb0[2], pb1[2];

    const bool mok = (m0 + srow) < M;
    const bhalf* A0base = Aagg + (size_t)(m0 + srow) * K;
    const bhalf* A1base = Ax + (size_t)(m0 + srow) * K;
    const bhalf* B0base = BW + (size_t)(n0 + srow) * K;
    const bhalf* B1base = BrW + (size_t)(n0 + srow) * K;

    pa0[0] = mok ? *(const uint4*)(A0base + sc0)      : make_uint4(0u,0u,0u,0u);
    pa0[1] = mok ? *(const uint4*)(A0base + sc0 + 32) : make_uint4(0u,0u,0u,0u);
    pa1[0] = mok ? *(const uint4*)(A1base + sc0)      : make_uint4(0u,0u,0u,0u);
    pa1[1] = mok ? *(const uint4*)(A1base + sc0 + 32) : make_uint4(0u,0u,0u,0u);
    pb0[0] = *(const uint4*)(B0base + sc0);
    pb0[1] = *(const uint4*)(B0base + sc0 + 32);
    pb1[0] = *(const uint4*)(B1base + sc0);
    pb1[1] = *(const uint4*)(B1base + sc0 + 32);

    const int swz = (srow & 7) << 3;
    for (int k0 = 0; k0 < K; k0 += 64) {
        __syncthreads();
        *(uint4*)&As0[srow * 64 + (sc0 ^ swz)]        = pa0[0];
        *(uint4*)&As0[srow * 64 + ((sc0 + 32) ^ swz)] = pa0[1];
        *(uint4*)&As1[srow * 64 + (sc0 ^ swz)]        = pa1[0];
        *(uint4*)&As1[srow * 64 + ((sc0 + 32) ^ swz)] = pa1[1];
        *(uint4*)&Bs0[srow * 64 + (sc0 ^ swz)]        = pb0[0];
        *(uint4*)&Bs0[srow * 64 + ((sc0 + 32) ^ swz)] = pb0[1];
        *(uint4*)&Bs1[srow * 64 + (sc0 ^ swz)]        = pb1[0];
        *(uint4*)&Bs1[srow * 64 + ((sc0 + 32) ^ swz)] = pb1[1];
        __syncthreads();
        if (k0 + 64 < K) {
            const bhalf* a0n = A0base + k0 + 64;
            const bhalf* a1n = A1base + k0 + 64;
            const bhalf* b0n = B0base + k0 + 64;
            const bhalf* b1n = B1base + k0 + 64;
            pa0[0] = mok ? *(const uint4*)(a0n + sc0)      : make_uint4(0u,0u,0u,0u);
            pa0[1] = mok ? *(const uint4*)(a0n + sc0 + 32) : make_uint4(0u,0u,0u,0u);
            pa1[0] = mok ? *(const uint4*)(a1n + sc0)      : make_uint4(0u,0u,0u,0u);
            pa1[1] = mok ? *(const uint4*)(a1n + sc0 + 32) : make_uint4(0u,0u,0u,0u);
            pb0[0] = *(const uint4*)(b0n + sc0);
            pb0[1] = *(const uint4*)(b0n + sc0 + 32);
            pb1[0] = *(const uint4*)(b1n + sc0);
            pb1[1] = *(const uint4*)(b1n + sc0 + 32);
        }
#pragma unroll
        for (int kb = 0; kb < 2; ++kb) {
            const int kc = kb * 32 + (lane >> 4) * 8;
            bhalf8 a0f[2], a1f[2], b0f[2], b1f[2];
#pragma unroll
            for (int i = 0; i < 2; ++i) {
                int rA = wm0 + i * 16 + (lane & 15);
                int oa = rA * 64 + (kc ^ ((rA & 7) << 3));
                a0f[i] = *(const bhalf8*)&As0[oa];
                a1f[i] = *(const bhalf8*)&As1[oa];
                int rB = wn0 + i * 16 + (lane & 15);
                int ob = rB * 64 + (kc ^ ((rB & 7) << 3));
                b0f[i] = *(const bhalf8*)&Bs0[ob];
                b1f[i] = *(const bhalf8*)&Bs1[ob];
            }
#pragma unroll
            for (int mi = 0; mi < 2; ++mi)
#pragma unroll
                for (int ni = 0; ni < 2; ++ni) {
                    acc0[mi][ni] = __builtin_amdgcn_mfma_f32_16x16x32_bf16(
                        a0f[mi], b0f[ni], acc0[mi][ni], 0, 0, 0);
                    acc1[mi][ni] = __builtin_amdgcn_mfma_f32_16x16x32_bf16(
                        a1f[mi], b1f[ni], acc1[mi][ni], 0, 0, 0);
                }
        }
    }

    // epilogue: v = relu(m+b)+relu(r+rb), bf16 store + column stats
    if (t < 64) { ssum[t] = 0.f; ssq[t] = 0.f; }
    __syncthreads();
    float sloc[2] = {0.f, 0.f}, s2loc[2] = {0.f, 0.f};
#pragma unroll
    for (int ni = 0; ni < 2; ++ni) {
        int cl = wn0 + ni * 16 + (lane & 15);
        int c = n0 + cl;
        float bb = b[c], rbb = rb[c];
#pragma unroll
        for (int mi = 0; mi < 2; ++mi) {
            f32x4 a0v = acc0[mi][ni], a1v = acc1[mi][ni];
#pragma unroll
            for (int r = 0; r < 4; ++r) {
                int row = m0 + wm0 + mi * 16 + (lane >> 4) * 4 + r;
                if (row < M) {
                    float x = fmaxf(a0v[r] + bb, 0.f) + fmaxf(a1v[r] + rbb, 0.f);
                    vout[(size_t)row * HID + c] = (bhalf)x;
                    sloc[ni] += x;
                    s2loc[ni] += x * x;
                }
            }
        }
        atomicAdd(&ssum[cl], sloc[ni]);
        atomicAdd(&ssq[cl], s2loc[ni]);
    }
    __syncthreads();
    if (t < 64) {
        atomicAdd(&stats[n0 + t], ssum[t]);
        atomicAdd(&stats[HID + n0 + t], ssq[t]);
    }
}

// sum S split-K partials + bias + act
template<int RELU, int OUTBF16>
__global__ __launch_bounds__(256) void splitk_combine(const float* __restrict__ part,
                                                      int S, int M, int N, int ldo,
                                                      const float* __restrict__ bias,
                                                      void* __restrict__ outv)
{
    int i = blockIdx.x * blockDim.x + threadIdx.x;
    int n4 = N >> 2;
    if (i >= M * n4) return;
    int row = i / n4, c4 = (i - row * n4) << 2;
    float4 s = make_float4(0.f, 0.f, 0.f, 0.f);
    for (int z = 0; z < S; ++z) {
        float4 p = *(const float4*)(part + ((size_t)z * M + row) * N + c4);
        s.x += p.x; s.y += p.y; s.z += p.z; s.w += p.w;
    }
    float4 bb = *(const float4*)(bias + c4);
    s.x += bb.x; s.y += bb.y; s.z += bb.z; s.w += bb.w;
    if (RELU) {
        s.x = fmaxf(s.x, 0.f); s.y = fmaxf(s.y, 0.f);
        s.z = fmaxf(s.z, 0.f); s.w = fmaxf(s.w, 0.f);
    }
    if (OUTBF16) {
        bhalf4 o = {(bhalf)s.x, (bhalf)s.y, (bhalf)s.z, (bhalf)s.w};
        *(bhalf4*)((bhalf*)outv + (size_t)row * ldo + c4) = o;
    } else {
        *(float4*)((float*)outv + (size_t)row * ldo + c4) = s;
    }
}

// last head layer: combine S partials + bias + relu, dot with W3
__global__ __launch_bounds__(128) void splitk_combine_dot(const float* __restrict__ part,
                                                          int S, int M, int N,
                                                          const float* __restrict__ bias,
                                                          const float* __restrict__ W3,
                                                          const float* __restrict__ b3,
                                                          float* __restrict__ out)
{
    int row = blockIdx.x, t = threadIdx.x;
    int c4 = t << 2;
    float4 s = make_float4(0.f, 0.f, 0.f, 0.f);
    for (int z = 0; z < S; ++z) {
        float4 p = *(const float4*)(part + ((size_t)z * M + row) * N + c4);
        s.x += p.x; s.y += p.y; s.z += p.z; s.w += p.w;
    }
    float4 bb = *(const float4*)(bias + c4);
    float4 w = *(const float4*)(W3 + c4);
    float d = fmaxf(s.x + bb.x, 0.f) * w.x + fmaxf(s.y + bb.y, 0.f) * w.y
            + fmaxf(s.z + bb.z, 0.f) * w.z + fmaxf(s.w + bb.w, 0.f) * w.w;
#pragma unroll
    for (int off = 32; off > 0; off >>= 1) d += __shfl_xor(d, off);
    __shared__ float ws2[2];
    if ((t & 63) == 0) ws2[t >> 6] = d;
    __syncthreads();
    if (t == 0) out[row] = ws2[0] + ws2[1] + b3[0];
}

// ---------------------------------------------------------------------------
// Batched weight transpose+convert
// ---------------------------------------------------------------------------
struct WEnt { const float* src; bhalf* dst; int K; int N; int tiles_end; };
struct WTab { WEnt e[8]; };

__global__ __launch_bounds__(256) void wconv_batch(WTab tab)
{
    __shared__ float tile[32][33];
    int tb = blockIdx.x;
    int idx = 0;
#pragma unroll
    for (int i = 0; i < 8; ++i)
        if (tb >= tab.e[i].tiles_end) idx = i + 1;
    const WEnt& E = tab.e[idx];
    int t0 = idx ? tab.e[idx - 1].tiles_end : 0;
    int lt = tb - t0;
    int tX = E.N >> 5;
    int bx = (lt % tX) << 5;
    int by = (lt / tX) << 5;
    int tx = threadIdx.x & 31, ty = threadIdx.x >> 5;
#pragma unroll
    for (int i = 0; i < 32; i += 8)
        tile[ty + i][tx] = E.src[(size_t)(by + ty + i) * E.N + bx + tx];
    __syncthreads();
#pragma unroll
    for (int i = 0; i < 32; i += 8)
        E.dst[(size_t)(bx + ty + i) * E.K + by + tx] = (bhalf)tile[tx][ty + i];
}

__global__ void conv_batch(const float* __restrict__ a, bhalf* __restrict__ oa, int n4a,
                           const float* __restrict__ b, bhalf* __restrict__ ob, int n4b)
{
    int i = blockIdx.x * blockDim.x + threadIdx.x;
    const float* s; bhalf* d; int j;
    if (i < n4a) { s = a; d = oa; j = i; }
    else { j = i - n4a; if (j >= n4b) return; s = b; d = ob; }
    float4 v = ((const float4*)s)[j];
    bhalf4 o = {(bhalf)v.x, (bhalf)v.y, (bhalf)v.z, (bhalf)v.w};
    ((bhalf4*)d)[j] = o;
}

// ---------------------------------------------------------------------------
// CSR build
// ---------------------------------------------------------------------------
__global__ void csr_count(const int* __restrict__ dst, int* __restrict__ counts)
{
    int e = blockIdx.x * blockDim.x + threadIdx.x;
    if (e >= N_EDGES) return;
    atomicAdd(&counts[dst[e]], 1);
}

__global__ __launch_bounds__(256) void csr_scan_a(const int* __restrict__ counts,
                                                  int* __restrict__ bsum)
{
    int i = blockIdx.x * 256 + threadIdx.x;
    int v = (i < N_NODES) ? counts[i] : 0;
#pragma unroll
    for (int off = 32; off > 0; off >>= 1) v += __shfl_down(v, off);
    __shared__ int ws[4];
    if ((threadIdx.x & 63) == 0) ws[threadIdx.x >> 6] = v;
    __syncthreads();
    if (threadIdx.x == 0) bsum[blockIdx.x] = ws[0] + ws[1] + ws[2] + ws[3];
}

__global__ __launch_bounds__(128) void csr_scan_b(int* __restrict__ bsum, int nb)
{
    __shared__ int tmp[128];
    int t = threadIdx.x;
    tmp[t] = (t < nb) ? bsum[t] : 0;
    __syncthreads();
    if (t == 0) {
        int run = 0;
        for (int i = 0; i < nb; ++i) { int c = tmp[i]; tmp[i] = run; run += c; }
    }
    __syncthreads();
    if (t < nb) bsum[t] = tmp[t];
}

__global__ __launch_bounds__(256) void csr_scan_c(const int* __restrict__ counts,
                                                  const int* __restrict__ bsum,
                                                  int* __restrict__ offsets)
{
    int t = threadIdx.x, b = blockIdx.x;
    int i = b * 256 + t;
    int v = (i < N_NODES) ? counts[i] : 0;
    int x = v;
#pragma unroll
    for (int off = 1; off < 64; off <<= 1) {
        int y = __shfl_up(x, off);
        if ((t & 63) >= off) x += y;
    }
    __shared__ int wsum[4];
    if ((t & 63) == 63) wsum[t >> 6] = x;
    __syncthreads();
    int add = bsum[b];
    for (int w = 0; w < (t >> 6); ++w) add += wsum[w];
    int excl = x - v + add;
    if (i < N_NODES) offsets[i] = excl;
    if (i == N_NODES - 1) offsets[N_NODES] = excl + v;
}

__global__ void csr_fill(const int* __restrict__ src, const int* __restrict__ dst,
                         const int* __restrict__ offsets, int* __restrict__ cursor,
                         int* __restrict__ eidx)
{
    int e = blockIdx.x * blockDim.x + threadIdx.x;
    if (e >= N_EDGES) return;
    int d = dst[e];
    int slot = offsets[d] + atomicAdd(&cursor[d], 1);
    eidx[slot] = src[e];
}

__global__ void csr_sort_wave(const int* __restrict__ offsets, int* __restrict__ eidx)
{
    int gidx = blockIdx.x * blockDim.x + threadIdx.x;
    int n = gidx >> 6, lane = gidx & 63;
    if (n >= N_NODES) return;
    int lo = offsets[n], hi = offsets[n + 1];
    int cnt = hi - lo;
    if (cnt <= 1) return;
    if (cnt <= 64) {
        int v = (lane < cnt) ? eidx[lo + lane] : 0x7fffffff;
        int rank = 0;
        for (int j = 0; j < cnt; ++j) {
            int vj = __shfl(v, j);
            if (vj < v || (vj == v && j < lane)) ++rank;
        }
        if (lane < cnt) eidx[lo + rank] = v;
    } else if (lane == 0) {
        for (int i = lo + 1; i < hi; ++i) {
            int v = eidx[i]; int j = i - 1;
            while (j >= lo && eidx[j] > v) { eidx[j + 1] = eidx[j]; --j; }
            eidx[j + 1] = v;
        }
    }
}

// ---------------------------------------------------------------------------
// Gather-aggregate on bf16 features (COLS = 128 or 256), fp32 accumulate,
// bf16 output. Wave per node.
// ---------------------------------------------------------------------------
template<int COLS>
__global__ __launch_bounds__(256) void edge_gather_b(const bhalf* __restrict__ m,
                                                     const int* __restrict__ offsets,
                                                     const int* __restrict__ eidx,
                                                     bhalf* __restrict__ agg)
{
    int gidx = blockIdx.x * blockDim.x + threadIdx.x;
    int n = gidx >> 6, lane = gidx & 63;
    if (n >= N_NODES) return;
    int lo = offsets[n], hi = offsets[n + 1];
    if (COLS == 256) {
        const bhalf* base = m + lane * 4;
        float4 acc = make_float4(0.f, 0.f, 0.f, 0.f);
        int i = lo;
        for (; i + 2 <= hi; i += 2) {
            bhalf4 v0 = *(const bhalf4*)(base + (size_t)eidx[i] * COLS);
            bhalf4 v1 = *(const bhalf4*)(base + (size_t)eidx[i + 1] * COLS);
            acc.x += (float)v0.x + (float)v1.x;
            acc.y += (float)v0.y + (float)v1.y;
            acc.z += (float)v0.z + (float)v1.z;
            acc.w += (float)v0.w + (float)v1.w;
        }
        if (i < hi) {
            bhalf4 v0 = *(const bhalf4*)(base + (size_t)eidx[i] * COLS);
            acc.x += (float)v0.x; acc.y += (float)v0.y;
            acc.z += (float)v0.z; acc.w += (float)v0.w;
        }
        bhalf4 o = {(bhalf)acc.x, (bhalf)acc.y, (bhalf)acc.z, (bhalf)acc.w};
        *(bhalf4*)(agg + (size_t)n * COLS + lane * 4) = o;
    } else {
        const bhalf* base = m + lane * 2;
        float ax = 0.f, ay = 0.f;
        int i = lo;
        for (; i + 2 <= hi; i += 2) {
            bhalf2 v0 = *(const bhalf2*)(base + (size_t)eidx[i] * COLS);
            bhalf2 v1 = *(const bhalf2*)(base + (size_t)eidx[i + 1] * COLS);
            ax += (float)v0.x + (float)v1.x;
            ay += (float)v0.y + (float)v1.y;
        }
        if (i < hi) {
            bhalf2 v0 = *(const bhalf2*)(base + (size_t)eidx[i] * COLS);
            ax += (float)v0.x; ay += (float)v0.y;
        }
        bhalf2 o = {(bhalf)ax, (bhalf)ay};
        *(bhalf2*)(agg + (size_t)n * COLS + lane * 2) = o;
    }
}

// ---------------------------------------------------------------------------
// Wave-per-node BN with inline finalize; v input is bf16.
// MODE 0: write bf16 h. MODE 1: write bf16 h + node attention weight.
// ---------------------------------------------------------------------------
template<int MODE>
__global__ __launch_bounds__(256) void bn_row(const bhalf* __restrict__ v,
                                              const float* __restrict__ stats,
                                              float inv_n,
                                              const float* __restrict__ g,
                                              const float* __restrict__ be,
                                              bhalf* __restrict__ outb,
                                              const float* __restrict__ awW,
                                              const float* __restrict__ awb,
                                              float* __restrict__ w)
{
    int gidx = blockIdx.x * blockDim.x + threadIdx.x;
    int n = gidx >> 6, lane = gidx & 63;
    if (n >= N_NODES) return;
    int col = lane * 4;
    bhalf4 vv = *(const bhalf4*)(v + (size_t)n * HID + col);
    float4 sm = *(const float4*)(stats + col);
    float4 sq = *(const float4*)(stats + HID + col);
    float4 gg = *(const float4*)(g + col);
    float4 bb = *(const float4*)(be + col);
    float mux = sm.x * inv_n, muy = sm.y * inv_n, muz = sm.z * inv_n, muw = sm.w * inv_n;
    float rsx = rsqrtf(sq.x * inv_n - mux * mux + 1e-5f);
    float rsy = rsqrtf(sq.y * inv_n - muy * muy + 1e-5f);
    float rsz = rsqrtf(sq.z * inv_n - muz * muz + 1e-5f);
    float rsw = rsqrtf(sq.w * inv_n - muw * muw + 1e-5f);
    float4 o;
    o.x = gg.x * ((float)vv.x - mux) * rsx + bb.x;
    o.y = gg.y * ((float)vv.y - muy) * rsy + bb.y;
    o.z = gg.z * ((float)vv.z - muz) * rsz + bb.z;
    o.w = gg.w * ((float)vv.w - muw) * rsw + bb.w;
    bhalf4 ob = {(bhalf)o.x, (bhalf)o.y, (bhalf)o.z, (bhalf)o.w};
    *(bhalf4*)(outb + (size_t)n * HID + col) = ob;
    if (MODE == 1) {
        float4 wv = *(const float4*)(awW + col);
        float d = o.x * wv.x + o.y * wv.y + o.z * wv.z + o.w * wv.w;
#pragma unroll
        for (int off = 32; off > 0; off >>= 1) d += __shfl_xor(d, off);
        if (lane == 0) w[n] = 1.f / (1.f + expf(-(d + awb[0])));
    }
}

// ---------------------------------------------------------------------------
__global__ __launch_bounds__(256) void readout(const bhalf* __restrict__ h,
                                               const float* __restrict__ w,
                                               const int* __restrict__ gid,
                                               bhalf* __restrict__ z)
{
    int g = blockIdx.x, col = threadIdx.x;
    int lo = 0, hi = N_NODES;
    while (lo < hi) { int mid = (lo + hi) >> 1; if (gid[mid] < g) lo = mid + 1; else hi = mid; }
    int start = lo;
    hi = N_NODES;
    while (lo < hi) { int mid = (lo + hi) >> 1; if (gid[mid] <= g) lo = mid + 1; else hi = mid; }
    int end = lo;
    float s = 0.f, mx = -INFINITY;
    for (int n = start; n < end; ++n) {
        float v = (float)h[(size_t)n * HID + col];
        s = fmaf(v, w[n], s);
        mx = fmaxf(mx, v);
    }
    z[(size_t)g * 1024 + col] = (bhalf)s;
    z[(size_t)g * 1024 + HID + col] = (bhalf)mx;
}

// ---------------------------------------------------------------------------
extern "C" void kernel_launch(void* const* d_in, const int* in_sizes, int n_in,
                              void* d_out, int out_size, void* d_ws, size_t ws_size,
                              hipStream_t stream)
{
    (void)in_sizes; (void)n_in; (void)out_size; (void)ws_size;

    const float* node_feats = (const float*)d_in[0];
    const float* rdkit      = (const float*)d_in[1];
    const int*   src        = (const int*)d_in[2];
    const int*   dst        = (const int*)d_in[3];
    const int*   gid        = (const int*)d_in[4];
    const float* W1  = (const float*)d_in[5];
    const float* b1  = (const float*)d_in[6];
    const float* rW1 = (const float*)d_in[7];
    const float* rb1 = (const float*)d_in[8];
    const float* g1  = (const float*)d_in[9];
    const float* be1 = (const float*)d_in[10];
    const float* W2  = (const float*)d_in[11];
    const float* b2  = (const float*)d_in[12];
    const float* rW2 = (const float*)d_in[13];
    const float* rb2 = (const float*)d_in[14];
    const float* g2  = (const float*)d_in[15];
    const float* be2 = (const float*)d_in[16];
    const float* aw_W  = (const float*)d_in[17];
    const float* aw_b  = (const float*)d_in[18];
    const float* rk_W1 = (const float*)d_in[19];
    const float* rk_b1 = (const float*)d_in[20];
    const float* rk_W2 = (const float*)d_in[21];
    const float* rk_b2 = (const float*)d_in[22];
    const float* c_W1  = (const float*)d_in[23];
    const float* c_b1  = (const float*)d_in[24];
    const float* c_W2  = (const float*)d_in[25];
    const float* c_b2  = (const float*)d_in[26];
    const float* c_W3  = (const float*)d_in[27];
    const float* c_b3  = (const float*)d_in[28];

    float* out = (float*)d_out;

    const size_t NODE = (size_t)N_NODES * HID;         // 5,120,000
    bhalf* nfb   = (bhalf*)d_ws;                       // [20000,128]
    bhalf* h1b   = nfb + (size_t)N_NODES * IN_FEATS;   // [20000,256]
    bhalf* h2b   = h1b + NODE;                         // [20000,256]
    bhalf* aggb  = h2b + NODE;                         // [20000,256]
    bhalf* vb    = aggb + NODE;                        // [20000,256]
    bhalf* W1cat = vb + NODE;                          // [512,128]
    bhalf* W2cat = W1cat + 512 * 128;                  // [512,256]
    bhalf* rkW1t = W2cat + 512 * 256;                  // [1024,2048]
    bhalf* rkW2t = rkW1t + 2048 * 1024;                // [512,1024]
    bhalf* cW1t  = rkW2t + 1024 * 512;                 // [1024,1024]
    bhalf* cW2t  = cW1t + 1024 * 1024;                 // [512,1024]
    bhalf* rdkb  = cW2t + 1024 * 512;                  // [512,2048]
    float* stats1 = (float*)(rdkb + 512 * 2048);       // 512 raw sum|sumsq
    float* stats2 = stats1 + 512;                      // 512
    float* wbuf   = stats2 + 512;                      // 20000
    int*   counts  = (int*)(wbuf + N_NODES);           // N (adjacent w/ cursor)
    int*   cursor  = counts + N_NODES;                 // N
    int*   offsets = cursor + N_NODES;                 // N+1
    int*   eidx    = offsets + N_NODES + 1;            // N_EDGES
    int*   bsum    = eidx + N_EDGES;                   // 128
    bhalf* rkhb  = (bhalf*)(bsum + 128);               // [512,1024]
    bhalf* zb    = rkhb + 512 * 1024;                  // [512,1024]
    bhalf* ch1b  = zb + 512 * 1024;                    // [512,1024]
    float* spart = (float*)(ch1b + 512 * 1024);        // split-K partials (<=16MB)

    dim3 blk(256);
    const int EPB = (N_EDGES + 255) / 256;
    const int NPB = (N_NODES + 255) / 256;             // 79
    const int NWAVE = (N_NODES * 64) / 256;            // wave per node
    dim3 gfused(HID / 64, (N_NODES + 63) / 64);        // (4, 313)

    // ---------------- weight/input conversion ----------------
    WTab tab;
    tab.e[0] = {W1,    W1cat,             128, 256,   32};
    tab.e[1] = {rW1,   W1cat + 256 * 128, 128, 256,   64};
    tab.e[2] = {W2,    W2cat,             256, 256,  128};
    tab.e[3] = {rW2,   W2cat + 256 * 256, 256, 256,  192};
    tab.e[4] = {rk_W1, rkW1t,            2048, 1024, 2240};
    tab.e[5] = {rk_W2, rkW2t,            1024, 512,  2752};
    tab.e[6] = {c_W1,  cW1t,             1024, 1024, 3776};
    tab.e[7] = {c_W2,  cW2t,             1024, 512,  4288};
    wconv_batch<<<4288, blk, 0, stream>>>(tab);
    {
        int n4a = N_NODES * IN_FEATS / 4, n4b = 512 * 2048 / 4;
        conv_batch<<<(n4a + n4b + 255) / 256, blk, 0, stream>>>(node_feats, nfb, n4a,
                                                                rdkit, rdkb, n4b);
    }

    // ---------------- zero scratch ----------------
    hipMemsetAsync(counts, 0, 2 * N_NODES * sizeof(int), stream);
    hipMemsetAsync(stats1, 0, 1024 * sizeof(float), stream);

    // ---------------- CSR build ----------------
    csr_count<<<EPB, blk, 0, stream>>>(dst, counts);
    csr_scan_a<<<NPB, blk, 0, stream>>>(counts, bsum);
    csr_scan_b<<<1, 128, 0, stream>>>(bsum, NPB);
    csr_scan_c<<<NPB, blk, 0, stream>>>(counts, bsum, offsets);
    csr_fill<<<EPB, blk, 0, stream>>>(src, dst, offsets, cursor, eidx);
    csr_sort_wave<<<NWAVE, blk, 0, stream>>>(offsets, eidx);

    // ---------------- Layer 1: gather -> fused GEMM(v,stats) -> BN ----------
    edge_gather_b<IN_FEATS><<<NWAVE, blk, 0, stream>>>(nfb, offsets, eidx, aggb);
    gcn_gemm_fused<<<gfused, blk, 0, stream>>>(aggb, nfb, W1cat, W1cat + 256 * 128,
                                               b1, rb1, vb, stats1, N_NODES, IN_FEATS);
    bn_row<0><<<NWAVE, blk, 0, stream>>>(vb, stats1, 1.0f / N_NODES, g1, be1,
                                         h1b, nullptr, nullptr, nullptr);

    // ---------------- Layer 2 ----------------
    edge_gather_b<HID><<<NWAVE, blk, 0, stream>>>(h1b, offsets, eidx, aggb);
    gcn_gemm_fused<<<gfused, blk, 0, stream>>>(aggb, h1b, W2cat, W2cat + 256 * 256,
                                               b2, rb2, vb, stats2, N_NODES, HID);
    bn_row<1><<<NWAVE, blk, 0, stream>>>(vb, stats2, 1.0f / N_NODES, g2, be2,
                                         h2b, aw_W, aw_b, wbuf);

    // ---------------- Readout ----------------
    readout<<<N_GRAPHS, HID, 0, stream>>>(h2b, wbuf, gid, zb);

    // ---------------- RDKit branch (split-K) ----------------
    gemm_mfma<0,0><<<dim3(16, 8, 8), blk, 0, stream>>>(rdkb, rkW1t, spart, nullptr,
                                                       512, 2048, 1024);
    splitk_combine<1,1><<<512, blk, 0, stream>>>(spart, 8, 512, 1024, 1024, rk_b1, rkhb);
    gemm_mfma<0,0><<<dim3(8, 8, 8), blk, 0, stream>>>(rkhb, rkW2t, spart, nullptr,
                                                      512, 1024, 512);
    splitk_combine<1,1><<<256, blk, 0, stream>>>(spart, 8, 512, 512, 1024, rk_b2, zb + 512);

    // ---------------- Combined head (split-K) ----------------
    gemm_mfma<0,0><<<dim3(16, 8, 4), blk, 0, stream>>>(zb, cW1t, spart, nullptr,
                                                       512, 1024, 1024);
    splitk_combine<1,1><<<512, blk, 0, stream>>>(spart, 4, 512, 1024, 1024, c_b1, ch1b);
    gemm_mfma<0,0><<<dim3(8, 8, 8), blk, 0, stream>>>(ch1b, cW2t, spart, nullptr,
                                                      512, 1024, 512);
    splitk_combine_dot<<<512, 128, 0, stream>>>(spart, 8, 512, 512, c_b2, c_W3, c_b3, out);
}

// Round 10
// 258.820 us; speedup vs baseline: 10.3129x; 1.0853x over previous
//
#include <hip/hip_runtime.h>
#include <hip/hip_bf16.h>
#include <cstdint>
#include <cstddef>

#define N_NODES 20000
#define N_EDGES 320000
#define N_GRAPHS 512
#define IN_FEATS 128
#define HID 256

typedef __bf16 bhalf;
typedef __bf16 bhalf8 __attribute__((ext_vector_type(8)));
typedef __bf16 bhalf4 __attribute__((ext_vector_type(4)));
typedef __bf16 bhalf2 __attribute__((ext_vector_type(2)));
typedef float f32x4 __attribute__((ext_vector_type(4)));

// ---------------------------------------------------------------------------
// bf16 MFMA GEMM (head layers): C = A @ Bt^T. 64x64 tile, BK=64, 4 waves,
// register-prefetch. Split-K via gridDim.z (fp32 partials).
// ---------------------------------------------------------------------------
template<int RELU, int OUTBF16>
__global__ __launch_bounds__(256) void gemm_mfma(const bhalf* __restrict__ A,
                                                 const bhalf* __restrict__ Bt,
                                                 void* __restrict__ Cv,
                                                 const float* __restrict__ bias,
                                                 int M, int K, int ldc)
{
    __shared__ bhalf As[64 * 64];
    __shared__ bhalf Bs[64 * 64];

    const int t = threadIdx.x;
    const int lane = t & 63, wid = t >> 6;
    const int wm0 = (wid >> 1) * 32, wn0 = (wid & 1) * 32;
    const int m0 = blockIdx.y * 64, n0 = blockIdx.x * 64;
    const int S = gridDim.z, kz = blockIdx.z;
    const int Ks = K / S;

    const int srow = t >> 2;
    const int sc0 = (t & 3) << 3;

    f32x4 acc[2][2] = {};
    uint4 ra0, ra1, rb0, rb1;

    const bool mok = (m0 + srow) < M;
    const bhalf* Abase = A + (size_t)(m0 + srow) * K + (size_t)kz * Ks;
    const bhalf* Bbase = Bt + (size_t)(n0 + srow) * K + (size_t)kz * Ks;

    ra0 = mok ? *(const uint4*)(Abase + sc0)      : make_uint4(0u,0u,0u,0u);
    ra1 = mok ? *(const uint4*)(Abase + sc0 + 32) : make_uint4(0u,0u,0u,0u);
    rb0 = *(const uint4*)(Bbase + sc0);
    rb1 = *(const uint4*)(Bbase + sc0 + 32);

    const int swz = (srow & 7) << 3;
    for (int k0 = 0; k0 < Ks; k0 += 64) {
        __syncthreads();
        *(uint4*)&As[srow * 64 + (sc0 ^ swz)]        = ra0;
        *(uint4*)&As[srow * 64 + ((sc0 + 32) ^ swz)] = ra1;
        *(uint4*)&Bs[srow * 64 + (sc0 ^ swz)]        = rb0;
        *(uint4*)&Bs[srow * 64 + ((sc0 + 32) ^ swz)] = rb1;
        __syncthreads();
        if (k0 + 64 < Ks) {
            const bhalf* An = Abase + k0 + 64;
            const bhalf* Bn = Bbase + k0 + 64;
            ra0 = mok ? *(const uint4*)(An + sc0)      : make_uint4(0u,0u,0u,0u);
            ra1 = mok ? *(const uint4*)(An + sc0 + 32) : make_uint4(0u,0u,0u,0u);
            rb0 = *(const uint4*)(Bn + sc0);
            rb1 = *(const uint4*)(Bn + sc0 + 32);
        }
#pragma unroll
        for (int kb = 0; kb < 2; ++kb) {
            const int kc = kb * 32 + (lane >> 4) * 8;
            bhalf8 af[2], bfr[2];
#pragma unroll
            for (int i = 0; i < 2; ++i) {
                int rA = wm0 + i * 16 + (lane & 15);
                af[i] = *(const bhalf8*)&As[rA * 64 + (kc ^ ((rA & 7) << 3))];
                int rB = wn0 + i * 16 + (lane & 15);
                bfr[i] = *(const bhalf8*)&Bs[rB * 64 + (kc ^ ((rB & 7) << 3))];
            }
#pragma unroll
            for (int mi = 0; mi < 2; ++mi)
#pragma unroll
                for (int ni = 0; ni < 2; ++ni)
                    acc[mi][ni] = __builtin_amdgcn_mfma_f32_16x16x32_bf16(
                        af[mi], bfr[ni], acc[mi][ni], 0, 0, 0);
        }
    }

#pragma unroll
    for (int mi = 0; mi < 2; ++mi)
#pragma unroll
        for (int ni = 0; ni < 2; ++ni) {
            int col = n0 + wn0 + ni * 16 + (lane & 15);
            f32x4 v = acc[mi][ni];
            if (S > 1) {
#pragma unroll
                for (int r = 0; r < 4; ++r) {
                    int row = m0 + wm0 + mi * 16 + (lane >> 4) * 4 + r;
                    if (row < M)
                        ((float*)Cv)[((size_t)kz * M + row) * ldc + col] = v[r];
                }
            } else {
                float bb = bias ? bias[col] : 0.f;
#pragma unroll
                for (int r = 0; r < 4; ++r) {
                    int row = m0 + wm0 + mi * 16 + (lane >> 4) * 4 + r;
                    if (row < M) {
                        float x = v[r] + bb;
                        if (RELU) x = fmaxf(x, 0.f);
                        if (OUTBF16) ((bhalf*)Cv)[(size_t)row * ldc + col] = (bhalf)x;
                        else         ((float*)Cv)[(size_t)row * ldc + col] = x;
                    }
                }
            }
        }
}

// ---------------------------------------------------------------------------
// Fused GCN layer GEMM, two-phase: phase 0 accumulates m = Aagg @ BW^T into
// accM; phase 1 accumulates r = Ax @ BrW^T into accR; one shared As/Bs LDS
// pair (16 KB), prefetch flows across the phase boundary. Epilogue:
// v = relu(m+b) + relu(r+rb) -> bf16 + per-column sum/sumsq atomics.
// K%64==0, K/64 a power of 2. grid (HID/64, ceil(M/64)).
// ---------------------------------------------------------------------------
__global__ __launch_bounds__(256) void gcn_gemm_fused(const bhalf* __restrict__ Aagg,
                                                      const bhalf* __restrict__ Ax,
                                                      const bhalf* __restrict__ BW,
                                                      const bhalf* __restrict__ BrW,
                                                      const float* __restrict__ b,
                                                      const float* __restrict__ rb,
                                                      bhalf* __restrict__ vout,
                                                      float* __restrict__ stats,
                                                      int M, int K)
{
    __shared__ bhalf As[64 * 64];
    __shared__ bhalf Bs[64 * 64];
    __shared__ float ssum[64], ssq[64];

    const int t = threadIdx.x;
    const int lane = t & 63, wid = t >> 6;
    const int wm0 = (wid >> 1) * 32, wn0 = (wid & 1) * 32;
    const int m0 = blockIdx.y * 64, n0 = blockIdx.x * 64;

    const int srow = t >> 2;
    const int sc0 = (t & 3) << 3;
    const int nk = K >> 6;

    f32x4 accM[2][2] = {};
    f32x4 accR[2][2] = {};
    uint4 ra0, ra1, rb0, rb1;

    const bool mok = (m0 + srow) < M;
    const bhalf* A0r = Aagg + (size_t)(m0 + srow) * K;
    const bhalf* A1r = Ax + (size_t)(m0 + srow) * K;
    const bhalf* B0r = BW + (size_t)(n0 + srow) * K;
    const bhalf* B1r = BrW + (size_t)(n0 + srow) * K;

    // prefetch ii=0 (phase 0, k=0)
    ra0 = mok ? *(const uint4*)(A0r + sc0)      : make_uint4(0u,0u,0u,0u);
    ra1 = mok ? *(const uint4*)(A0r + sc0 + 32) : make_uint4(0u,0u,0u,0u);
    rb0 = *(const uint4*)(B0r + sc0);
    rb1 = *(const uint4*)(B0r + sc0 + 32);

    const int swz = (srow & 7) << 3;
    const int total = 2 * nk;
    for (int ii = 0; ii < total; ++ii) {
        __syncthreads();
        *(uint4*)&As[srow * 64 + (sc0 ^ swz)]        = ra0;
        *(uint4*)&As[srow * 64 + ((sc0 + 32) ^ swz)] = ra1;
        *(uint4*)&Bs[srow * 64 + (sc0 ^ swz)]        = rb0;
        *(uint4*)&Bs[srow * 64 + ((sc0 + 32) ^ swz)] = rb1;
        __syncthreads();
        int jj = ii + 1;
        if (jj < total) {           // prefetch next tile (crosses phase boundary)
            bool seln = jj >= nk;
            int kk = (seln ? jj - nk : jj) << 6;
            const bhalf* Ab = (seln ? A1r : A0r) + kk;
            const bhalf* Bb = (seln ? B1r : B0r) + kk;
            ra0 = mok ? *(const uint4*)(Ab + sc0)      : make_uint4(0u,0u,0u,0u);
            ra1 = mok ? *(const uint4*)(Ab + sc0 + 32) : make_uint4(0u,0u,0u,0u);
            rb0 = *(const uint4*)(Bb + sc0);
            rb1 = *(const uint4*)(Bb + sc0 + 32);
        }
        const bool selc = ii >= nk;   // wave-uniform; accs statically named
#pragma unroll
        for (int kb = 0; kb < 2; ++kb) {
            const int kc = kb * 32 + (lane >> 4) * 8;
            bhalf8 af[2], bfr[2];
#pragma unroll
            for (int i = 0; i < 2; ++i) {
                int rA = wm0 + i * 16 + (lane & 15);
                af[i] = *(const bhalf8*)&As[rA * 64 + (kc ^ ((rA & 7) << 3))];
                int rB = wn0 + i * 16 + (lane & 15);
                bfr[i] = *(const bhalf8*)&Bs[rB * 64 + (kc ^ ((rB & 7) << 3))];
            }
            if (!selc) {
#pragma unroll
                for (int mi = 0; mi < 2; ++mi)
#pragma unroll
                    for (int ni = 0; ni < 2; ++ni)
                        accM[mi][ni] = __builtin_amdgcn_mfma_f32_16x16x32_bf16(
                            af[mi], bfr[ni], accM[mi][ni], 0, 0, 0);
            } else {
#pragma unroll
                for (int mi = 0; mi < 2; ++mi)
#pragma unroll
                    for (int ni = 0; ni < 2; ++ni)
                        accR[mi][ni] = __builtin_amdgcn_mfma_f32_16x16x32_bf16(
                            af[mi], bfr[ni], accR[mi][ni], 0, 0, 0);
            }
        }
    }

    // epilogue: v = relu(m+b)+relu(r+rb), bf16 store + column stats
    if (t < 64) { ssum[t] = 0.f; ssq[t] = 0.f; }
    __syncthreads();
    float sloc[2] = {0.f, 0.f}, s2loc[2] = {0.f, 0.f};
#pragma unroll
    for (int ni = 0; ni < 2; ++ni) {
        int cl = wn0 + ni * 16 + (lane & 15);
        int c = n0 + cl;
        float bb = b[c], rbb = rb[c];
#pragma unroll
        for (int mi = 0; mi < 2; ++mi) {
            f32x4 a0v = accM[mi][ni], a1v = accR[mi][ni];
#pragma unroll
            for (int r = 0; r < 4; ++r) {
                int row = m0 + wm0 + mi * 16 + (lane >> 4) * 4 + r;
                if (row < M) {
                    float x = fmaxf(a0v[r] + bb, 0.f) + fmaxf(a1v[r] + rbb, 0.f);
                    vout[(size_t)row * HID + c] = (bhalf)x;
                    sloc[ni] += x;
                    s2loc[ni] += x * x;
                }
            }
        }
        atomicAdd(&ssum[cl], sloc[ni]);
        atomicAdd(&ssq[cl], s2loc[ni]);
    }
    __syncthreads();
    if (t < 64) {
        atomicAdd(&stats[n0 + t], ssum[t]);
        atomicAdd(&stats[HID + n0 + t], ssq[t]);
    }
}

// sum S split-K partials + bias + act
template<int RELU, int OUTBF16>
__global__ __launch_bounds__(256) void splitk_combine(const float* __restrict__ part,
                                                      int S, int M, int N, int ldo,
                                                      const float* __restrict__ bias,
                                                      void* __restrict__ outv)
{
    int i = blockIdx.x * blockDim.x + threadIdx.x;
    int n4 = N >> 2;
    if (i >= M * n4) return;
    int row = i / n4, c4 = (i - row * n4) << 2;
    float4 s = make_float4(0.f, 0.f, 0.f, 0.f);
    for (int z = 0; z < S; ++z) {
        float4 p = *(const float4*)(part + ((size_t)z * M + row) * N + c4);
        s.x += p.x; s.y += p.y; s.z += p.z; s.w += p.w;
    }
    float4 bb = *(const float4*)(bias + c4);
    s.x += bb.x; s.y += bb.y; s.z += bb.z; s.w += bb.w;
    if (RELU) {
        s.x = fmaxf(s.x, 0.f); s.y = fmaxf(s.y, 0.f);
        s.z = fmaxf(s.z, 0.f); s.w = fmaxf(s.w, 0.f);
    }
    if (OUTBF16) {
        bhalf4 o = {(bhalf)s.x, (bhalf)s.y, (bhalf)s.z, (bhalf)s.w};
        *(bhalf4*)((bhalf*)outv + (size_t)row * ldo + c4) = o;
    } else {
        *(float4*)((float*)outv + (size_t)row * ldo + c4) = s;
    }
}

// last head layer: combine S partials + bias + relu, dot with W3
__global__ __launch_bounds__(128) void splitk_combine_dot(const float* __restrict__ part,
                                                          int S, int M, int N,
                                                          const float* __restrict__ bias,
                                                          const float* __restrict__ W3,
                                                          const float* __restrict__ b3,
                                                          float* __restrict__ out)
{
    int row = blockIdx.x, t = threadIdx.x;
    int c4 = t << 2;
    float4 s = make_float4(0.f, 0.f, 0.f, 0.f);
    for (int z = 0; z < S; ++z) {
        float4 p = *(const float4*)(part + ((size_t)z * M + row) * N + c4);
        s.x += p.x; s.y += p.y; s.z += p.z; s.w += p.w;
    }
    float4 bb = *(const float4*)(bias + c4);
    float4 w = *(const float4*)(W3 + c4);
    float d = fmaxf(s.x + bb.x, 0.f) * w.x + fmaxf(s.y + bb.y, 0.f) * w.y
            + fmaxf(s.z + bb.z, 0.f) * w.z + fmaxf(s.w + bb.w, 0.f) * w.w;
#pragma unroll
    for (int off = 32; off > 0; off >>= 1) d += __shfl_xor(d, off);
    __shared__ float ws2[2];
    if ((t & 63) == 0) ws2[t >> 6] = d;
    __syncthreads();
    if (t == 0) out[row] = ws2[0] + ws2[1] + b3[0];
}

// ---------------------------------------------------------------------------
// Batched weight transpose+convert
// ---------------------------------------------------------------------------
struct WEnt { const float* src; bhalf* dst; int K; int N; int tiles_end; };
struct WTab { WEnt e[8]; };

__global__ __launch_bounds__(256) void wconv_batch(WTab tab)
{
    __shared__ float tile[32][33];
    int tb = blockIdx.x;
    int idx = 0;
#pragma unroll
    for (int i = 0; i < 8; ++i)
        if (tb >= tab.e[i].tiles_end) idx = i + 1;
    const WEnt& E = tab.e[idx];
    int t0 = idx ? tab.e[idx - 1].tiles_end : 0;
    int lt = tb - t0;
    int tX = E.N >> 5;
    int bx = (lt % tX) << 5;
    int by = (lt / tX) << 5;
    int tx = threadIdx.x & 31, ty = threadIdx.x >> 5;
#pragma unroll
    for (int i = 0; i < 32; i += 8)
        tile[ty + i][tx] = E.src[(size_t)(by + ty + i) * E.N + bx + tx];
    __syncthreads();
#pragma unroll
    for (int i = 0; i < 32; i += 8)
        E.dst[(size_t)(bx + ty + i) * E.K + by + tx] = (bhalf)tile[tx][ty + i];
}

__global__ void conv_batch(const float* __restrict__ a, bhalf* __restrict__ oa, int n4a,
                           const float* __restrict__ b, bhalf* __restrict__ ob, int n4b)
{
    int i = blockIdx.x * blockDim.x + threadIdx.x;
    const float* s; bhalf* d; int j;
    if (i < n4a) { s = a; d = oa; j = i; }
    else { j = i - n4a; if (j >= n4b) return; s = b; d = ob; }
    float4 v = ((const float4*)s)[j];
    bhalf4 o = {(bhalf)v.x, (bhalf)v.y, (bhalf)v.z, (bhalf)v.w};
    ((bhalf4*)d)[j] = o;
}

// ---------------------------------------------------------------------------
// CSR build
// ---------------------------------------------------------------------------
__global__ void csr_count(const int* __restrict__ dst, int* __restrict__ counts)
{
    int e = blockIdx.x * blockDim.x + threadIdx.x;
    if (e >= N_EDGES) return;
    atomicAdd(&counts[dst[e]], 1);
}

__global__ __launch_bounds__(256) void csr_scan_a(const int* __restrict__ counts,
                                                  int* __restrict__ bsum)
{
    int i = blockIdx.x * 256 + threadIdx.x;
    int v = (i < N_NODES) ? counts[i] : 0;
#pragma unroll
    for (int off = 32; off > 0; off >>= 1) v += __shfl_down(v, off);
    __shared__ int ws[4];
    if ((threadIdx.x & 63) == 0) ws[threadIdx.x >> 6] = v;
    __syncthreads();
    if (threadIdx.x == 0) bsum[blockIdx.x] = ws[0] + ws[1] + ws[2] + ws[3];
}

__global__ __launch_bounds__(128) void csr_scan_b(int* __restrict__ bsum, int nb)
{
    __shared__ int tmp[128];
    int t = threadIdx.x;
    tmp[t] = (t < nb) ? bsum[t] : 0;
    __syncthreads();
    if (t == 0) {
        int run = 0;
        for (int i = 0; i < nb; ++i) { int c = tmp[i]; tmp[i] = run; run += c; }
    }
    __syncthreads();
    if (t < nb) bsum[t] = tmp[t];
}

__global__ __launch_bounds__(256) void csr_scan_c(const int* __restrict__ counts,
                                                  const int* __restrict__ bsum,
                                                  int* __restrict__ offsets)
{
    int t = threadIdx.x, b = blockIdx.x;
    int i = b * 256 + t;
    int v = (i < N_NODES) ? counts[i] : 0;
    int x = v;
#pragma unroll
    for (int off = 1; off < 64; off <<= 1) {
        int y = __shfl_up(x, off);
        if ((t & 63) >= off) x += y;
    }
    __shared__ int wsum[4];
    if ((t & 63) == 63) wsum[t >> 6] = x;
    __syncthreads();
    int add = bsum[b];
    for (int w = 0; w < (t >> 6); ++w) add += wsum[w];
    int excl = x - v + add;
    if (i < N_NODES) offsets[i] = excl;
    if (i == N_NODES - 1) offsets[N_NODES] = excl + v;
}

__global__ void csr_fill(const int* __restrict__ src, const int* __restrict__ dst,
                         const int* __restrict__ offsets, int* __restrict__ cursor,
                         int* __restrict__ eidx)
{
    int e = blockIdx.x * blockDim.x + threadIdx.x;
    if (e >= N_EDGES) return;
    int d = dst[e];
    int slot = offsets[d] + atomicAdd(&cursor[d], 1);
    eidx[slot] = src[e];
}

__global__ void csr_sort_wave(const int* __restrict__ offsets, int* __restrict__ eidx)
{
    int gidx = blockIdx.x * blockDim.x + threadIdx.x;
    int n = gidx >> 6, lane = gidx & 63;
    if (n >= N_NODES) return;
    int lo = offsets[n], hi = offsets[n + 1];
    int cnt = hi - lo;
    if (cnt <= 1) return;
    if (cnt <= 64) {
        int v = (lane < cnt) ? eidx[lo + lane] : 0x7fffffff;
        int rank = 0;
        for (int j = 0; j < cnt; ++j) {
            int vj = __shfl(v, j);
            if (vj < v || (vj == v && j < lane)) ++rank;
        }
        if (lane < cnt) eidx[lo + rank] = v;
    } else if (lane == 0) {
        for (int i = lo + 1; i < hi; ++i) {
            int v = eidx[i]; int j = i - 1;
            while (j >= lo && eidx[j] > v) { eidx[j + 1] = eidx[j]; --j; }
            eidx[j + 1] = v;
        }
    }
}

// ---------------------------------------------------------------------------
// Gather-aggregate on bf16 features (COLS = 128 or 256), fp32 accumulate,
// bf16 output. Wave per node.
// ---------------------------------------------------------------------------
template<int COLS>
__global__ __launch_bounds__(256) void edge_gather_b(const bhalf* __restrict__ m,
                                                     const int* __restrict__ offsets,
                                                     const int* __restrict__ eidx,
                                                     bhalf* __restrict__ agg)
{
    int gidx = blockIdx.x * blockDim.x + threadIdx.x;
    int n = gidx >> 6, lane = gidx & 63;
    if (n >= N_NODES) return;
    int lo = offsets[n], hi = offsets[n + 1];
    if (COLS == 256) {
        const bhalf* base = m + lane * 4;
        float4 acc = make_float4(0.f, 0.f, 0.f, 0.f);
        int i = lo;
        for (; i + 2 <= hi; i += 2) {
            bhalf4 v0 = *(const bhalf4*)(base + (size_t)eidx[i] * COLS);
            bhalf4 v1 = *(const bhalf4*)(base + (size_t)eidx[i + 1] * COLS);
            acc.x += (float)v0.x + (float)v1.x;
            acc.y += (float)v0.y + (float)v1.y;
            acc.z += (float)v0.z + (float)v1.z;
            acc.w += (float)v0.w + (float)v1.w;
        }
        if (i < hi) {
            bhalf4 v0 = *(const bhalf4*)(base + (size_t)eidx[i] * COLS);
            acc.x += (float)v0.x; acc.y += (float)v0.y;
            acc.z += (float)v0.z; acc.w += (float)v0.w;
        }
        bhalf4 o = {(bhalf)acc.x, (bhalf)acc.y, (bhalf)acc.z, (bhalf)acc.w};
        *(bhalf4*)(agg + (size_t)n * COLS + lane * 4) = o;
    } else {
        const bhalf* base = m + lane * 2;
        float ax = 0.f, ay = 0.f;
        int i = lo;
        for (; i + 2 <= hi; i += 2) {
            bhalf2 v0 = *(const bhalf2*)(base + (size_t)eidx[i] * COLS);
            bhalf2 v1 = *(const bhalf2*)(base + (size_t)eidx[i + 1] * COLS);
            ax += (float)v0.x + (float)v1.x;
            ay += (float)v0.y + (float)v1.y;
        }
        if (i < hi) {
            bhalf2 v0 = *(const bhalf2*)(base + (size_t)eidx[i] * COLS);
            ax += (float)v0.x; ay += (float)v0.y;
        }
        bhalf2 o = {(bhalf)ax, (bhalf)ay};
        *(bhalf2*)(agg + (size_t)n * COLS + lane * 2) = o;
    }
}

// ---------------------------------------------------------------------------
// Wave-per-node BN with inline finalize; v input is bf16.
// MODE 0: write bf16 h. MODE 1: write bf16 h + node attention weight.
// ---------------------------------------------------------------------------
template<int MODE>
__global__ __launch_bounds__(256) void bn_row(const bhalf* __restrict__ v,
                                              const float* __restrict__ stats,
                                              float inv_n,
                                              const float* __restrict__ g,
                                              const float* __restrict__ be,
                                              bhalf* __restrict__ outb,
                                              const float* __restrict__ awW,
                                              const float* __restrict__ awb,
                                              float* __restrict__ w)
{
    int gidx = blockIdx.x * blockDim.x + threadIdx.x;
    int n = gidx >> 6, lane = gidx & 63;
    if (n >= N_NODES) return;
    int col = lane * 4;
    bhalf4 vv = *(const bhalf4*)(v + (size_t)n * HID + col);
    float4 sm = *(const float4*)(stats + col);
    float4 sq = *(const float4*)(stats + HID + col);
    float4 gg = *(const float4*)(g + col);
    float4 bb = *(const float4*)(be + col);
    float mux = sm.x * inv_n, muy = sm.y * inv_n, muz = sm.z * inv_n, muw = sm.w * inv_n;
    float rsx = rsqrtf(sq.x * inv_n - mux * mux + 1e-5f);
    float rsy = rsqrtf(sq.y * inv_n - muy * muy + 1e-5f);
    float rsz = rsqrtf(sq.z * inv_n - muz * muz + 1e-5f);
    float rsw = rsqrtf(sq.w * inv_n - muw * muw + 1e-5f);
    float4 o;
    o.x = gg.x * ((float)vv.x - mux) * rsx + bb.x;
    o.y = gg.y * ((float)vv.y - muy) * rsy + bb.y;
    o.z = gg.z * ((float)vv.z - muz) * rsz + bb.z;
    o.w = gg.w * ((float)vv.w - muw) * rsw + bb.w;
    bhalf4 ob = {(bhalf)o.x, (bhalf)o.y, (bhalf)o.z, (bhalf)o.w};
    *(bhalf4*)(outb + (size_t)n * HID + col) = ob;
    if (MODE == 1) {
        float4 wv = *(const float4*)(awW + col);
        float d = o.x * wv.x + o.y * wv.y + o.z * wv.z + o.w * wv.w;
#pragma unroll
        for (int off = 32; off > 0; off >>= 1) d += __shfl_xor(d, off);
        if (lane == 0) w[n] = 1.f / (1.f + expf(-(d + awb[0])));
    }
}

// ---------------------------------------------------------------------------
__global__ __launch_bounds__(256) void readout(const bhalf* __restrict__ h,
                                               const float* __restrict__ w,
                                               const int* __restrict__ gid,
                                               bhalf* __restrict__ z)
{
    int g = blockIdx.x, col = threadIdx.x;
    int lo = 0, hi = N_NODES;
    while (lo < hi) { int mid = (lo + hi) >> 1; if (gid[mid] < g) lo = mid + 1; else hi = mid; }
    int start = lo;
    hi = N_NODES;
    while (lo < hi) { int mid = (lo + hi) >> 1; if (gid[mid] <= g) lo = mid + 1; else hi = mid; }
    int end = lo;
    float s = 0.f, mx = -INFINITY;
    for (int n = start; n < end; ++n) {
        float v = (float)h[(size_t)n * HID + col];
        s = fmaf(v, w[n], s);
        mx = fmaxf(mx, v);
    }
    z[(size_t)g * 1024 + col] = (bhalf)s;
    z[(size_t)g * 1024 + HID + col] = (bhalf)mx;
}

// ---------------------------------------------------------------------------
extern "C" void kernel_launch(void* const* d_in, const int* in_sizes, int n_in,
                              void* d_out, int out_size, void* d_ws, size_t ws_size,
                              hipStream_t stream)
{
    (void)in_sizes; (void)n_in; (void)out_size; (void)ws_size;

    const float* node_feats = (const float*)d_in[0];
    const float* rdkit      = (const float*)d_in[1];
    const int*   src        = (const int*)d_in[2];
    const int*   dst        = (const int*)d_in[3];
    const int*   gid        = (const int*)d_in[4];
    const float* W1  = (const float*)d_in[5];
    const float* b1  = (const float*)d_in[6];
    const float* rW1 = (const float*)d_in[7];
    const float* rb1 = (const float*)d_in[8];
    const float* g1  = (const float*)d_in[9];
    const float* be1 = (const float*)d_in[10];
    const float* W2  = (const float*)d_in[11];
    const float* b2  = (const float*)d_in[12];
    const float* rW2 = (const float*)d_in[13];
    const float* rb2 = (const float*)d_in[14];
    const float* g2  = (const float*)d_in[15];
    const float* be2 = (const float*)d_in[16];
    const float* aw_W  = (const float*)d_in[17];
    const float* aw_b  = (const float*)d_in[18];
    const float* rk_W1 = (const float*)d_in[19];
    const float* rk_b1 = (const float*)d_in[20];
    const float* rk_W2 = (const float*)d_in[21];
    const float* rk_b2 = (const float*)d_in[22];
    const float* c_W1  = (const float*)d_in[23];
    const float* c_b1  = (const float*)d_in[24];
    const float* c_W2  = (const float*)d_in[25];
    const float* c_b2  = (const float*)d_in[26];
    const float* c_W3  = (const float*)d_in[27];
    const float* c_b3  = (const float*)d_in[28];

    float* out = (float*)d_out;

    const size_t NODE = (size_t)N_NODES * HID;         // 5,120,000
    bhalf* nfb   = (bhalf*)d_ws;                       // [20000,128]
    bhalf* h1b   = nfb + (size_t)N_NODES * IN_FEATS;   // [20000,256]
    bhalf* h2b   = h1b + NODE;                         // [20000,256]
    bhalf* aggb  = h2b + NODE;                         // [20000,256]
    bhalf* vb    = aggb + NODE;                        // [20000,256]
    bhalf* W1cat = vb + NODE;                          // [512,128]
    bhalf* W2cat = W1cat + 512 * 128;                  // [512,256]
    bhalf* rkW1t = W2cat + 512 * 256;                  // [1024,2048]
    bhalf* rkW2t = rkW1t + 2048 * 1024;                // [512,1024]
    bhalf* cW1t  = rkW2t + 1024 * 512;                 // [1024,1024]
    bhalf* cW2t  = cW1t + 1024 * 1024;                 // [512,1024]
    bhalf* rdkb  = cW2t + 1024 * 512;                  // [512,2048]
    float* stats1 = (float*)(rdkb + 512 * 2048);       // 512 raw sum|sumsq
    float* stats2 = stats1 + 512;                      // 512
    float* wbuf   = stats2 + 512;                      // 20000
    int*   counts  = (int*)(wbuf + N_NODES);           // N (adjacent w/ cursor)
    int*   cursor  = counts + N_NODES;                 // N
    int*   offsets = cursor + N_NODES;                 // N+1
    int*   eidx    = offsets + N_NODES + 1;            // N_EDGES
    int*   bsum    = eidx + N_EDGES;                   // 128
    bhalf* rkhb  = (bhalf*)(bsum + 128);               // [512,1024]
    bhalf* zb    = rkhb + 512 * 1024;                  // [512,1024]
    bhalf* ch1b  = zb + 512 * 1024;                    // [512,1024]
    float* spart = (float*)(ch1b + 512 * 1024);        // split-K partials (<=16MB)

    dim3 blk(256);
    const int EPB = (N_EDGES + 255) / 256;
    const int NPB = (N_NODES + 255) / 256;             // 79
    const int NWAVE = (N_NODES * 64) / 256;            // wave per node
    dim3 gfused(HID / 64, (N_NODES + 63) / 64);        // (4, 313)

    // ---------------- weight/input conversion ----------------
    WTab tab;
    tab.e[0] = {W1,    W1cat,             128, 256,   32};
    tab.e[1] = {rW1,   W1cat + 256 * 128, 128, 256,   64};
    tab.e[2] = {W2,    W2cat,             256, 256,  128};
    tab.e[3] = {rW2,   W2cat + 256 * 256, 256, 256,  192};
    tab.e[4] = {rk_W1, rkW1t,            2048, 1024, 2240};
    tab.e[5] = {rk_W2, rkW2t,            1024, 512,  2752};
    tab.e[6] = {c_W1,  cW1t,             1024, 1024, 3776};
    tab.e[7] = {c_W2,  cW2t,             1024, 512,  4288};
    wconv_batch<<<4288, blk, 0, stream>>>(tab);
    {
        int n4a = N_NODES * IN_FEATS / 4, n4b = 512 * 2048 / 4;
        conv_batch<<<(n4a + n4b + 255) / 256, blk, 0, stream>>>(node_feats, nfb, n4a,
                                                                rdkit, rdkb, n4b);
    }

    // ---------------- zero scratch ----------------
    hipMemsetAsync(counts, 0, 2 * N_NODES * sizeof(int), stream);
    hipMemsetAsync(stats1, 0, 1024 * sizeof(float), stream);

    // ---------------- CSR build ----------------
    csr_count<<<EPB, blk, 0, stream>>>(dst, counts);
    csr_scan_a<<<NPB, blk, 0, stream>>>(counts, bsum);
    csr_scan_b<<<1, 128, 0, stream>>>(bsum, NPB);
    csr_scan_c<<<NPB, blk, 0, stream>>>(counts, bsum, offsets);
    csr_fill<<<EPB, blk, 0, stream>>>(src, dst, offsets, cursor, eidx);
    csr_sort_wave<<<NWAVE, blk, 0, stream>>>(offsets, eidx);

    // ---------------- Layer 1: gather -> fused GEMM(v,stats) -> BN ----------
    edge_gather_b<IN_FEATS><<<NWAVE, blk, 0, stream>>>(nfb, offsets, eidx, aggb);
    gcn_gemm_fused<<<gfused, blk, 0, stream>>>(aggb, nfb, W1cat, W1cat + 256 * 128,
                                               b1, rb1, vb, stats1, N_NODES, IN_FEATS);
    bn_row<0><<<NWAVE, blk, 0, stream>>>(vb, stats1, 1.0f / N_NODES, g1, be1,
                                         h1b, nullptr, nullptr, nullptr);

    // ---------------- Layer 2 ----------------
    edge_gather_b<HID><<<NWAVE, blk, 0, stream>>>(h1b, offsets, eidx, aggb);
    gcn_gemm_fused<<<gfused, blk, 0, stream>>>(aggb, h1b, W2cat, W2cat + 256 * 256,
                                               b2, rb2, vb, stats2, N_NODES, HID);
    bn_row<1><<<NWAVE, blk, 0, stream>>>(vb, stats2, 1.0f / N_NODES, g2, be2,
                                         h2b, aw_W, aw_b, wbuf);

    // ---------------- Readout ----------------
    readout<<<N_GRAPHS, HID, 0, stream>>>(h2b, wbuf, gid, zb);

    // ---------------- RDKit branch (split-K) ----------------
    gemm_mfma<0,0><<<dim3(16, 8, 8), blk, 0, stream>>>(rdkb, rkW1t, spart, nullptr,
                                                       512, 2048, 1024);
    splitk_combine<1,1><<<512, blk, 0, stream>>>(spart, 8, 512, 1024, 1024, rk_b1, rkhb);
    gemm_mfma<0,0><<<dim3(8, 8, 8), blk, 0, stream>>>(rkhb, rkW2t, spart, nullptr,
                                                      512, 1024, 512);
    splitk_combine<1,1><<<256, blk, 0, stream>>>(spart, 8, 512, 512, 1024, rk_b2, zb + 512);

    // ---------------- Combined head (split-K) ----------------
    gemm_mfma<0,0><<<dim3(16, 8, 4), blk, 0, stream>>>(zb, cW1t, spart, nullptr,
                                                       512, 1024, 1024);
    splitk_combine<1,1><<<512, blk, 0, stream>>>(spart, 4, 512, 1024, 1024, c_b1, ch1b);
    gemm_mfma<0,0><<<dim3(8, 8, 8), blk, 0, stream>>>(ch1b, cW2t, spart, nullptr,
                                                      512, 1024, 512);
    splitk_combine_dot<<<512, 128, 0, stream>>>(spart, 8, 512, 512, c_b2, c_W3, c_b3, out);
}

// Round 11
// 249.459 us; speedup vs baseline: 10.6999x; 1.0375x over previous
//
#include <hip/hip_runtime.h>
#include <hip/hip_bf16.h>
#include <cstdint>
#include <cstddef>

#define N_NODES 20000
#define N_EDGES 320000
#define N_GRAPHS 512
#define IN_FEATS 128
#define HID 256

typedef __bf16 bhalf;
typedef __bf16 bhalf8 __attribute__((ext_vector_type(8)));
typedef __bf16 bhalf4 __attribute__((ext_vector_type(4)));
typedef __bf16 bhalf2 __attribute__((ext_vector_type(2)));
typedef float f32x4 __attribute__((ext_vector_type(4)));

// ---------------------------------------------------------------------------
// bf16 MFMA GEMM (head layers): C = A @ Bt^T. 64x64 tile, BK=64, 4 waves,
// register-prefetch. Split-K via gridDim.z (fp32 partials).
// ---------------------------------------------------------------------------
template<int RELU, int OUTBF16>
__global__ __launch_bounds__(256) void gemm_mfma(const bhalf* __restrict__ A,
                                                 const bhalf* __restrict__ Bt,
                                                 void* __restrict__ Cv,
                                                 const float* __restrict__ bias,
                                                 int M, int K, int ldc)
{
    __shared__ bhalf As[64 * 64];
    __shared__ bhalf Bs[64 * 64];

    const int t = threadIdx.x;
    const int lane = t & 63, wid = t >> 6;
    const int wm0 = (wid >> 1) * 32, wn0 = (wid & 1) * 32;
    const int m0 = blockIdx.y * 64, n0 = blockIdx.x * 64;
    const int S = gridDim.z, kz = blockIdx.z;
    const int Ks = K / S;

    const int srow = t >> 2;
    const int sc0 = (t & 3) << 3;

    f32x4 acc[2][2] = {};
    uint4 ra0, ra1, rb0, rb1;

    const bool mok = (m0 + srow) < M;
    const bhalf* Abase = A + (size_t)(m0 + srow) * K + (size_t)kz * Ks;
    const bhalf* Bbase = Bt + (size_t)(n0 + srow) * K + (size_t)kz * Ks;

    ra0 = mok ? *(const uint4*)(Abase + sc0)      : make_uint4(0u,0u,0u,0u);
    ra1 = mok ? *(const uint4*)(Abase + sc0 + 32) : make_uint4(0u,0u,0u,0u);
    rb0 = *(const uint4*)(Bbase + sc0);
    rb1 = *(const uint4*)(Bbase + sc0 + 32);

    const int swz = (srow & 7) << 3;
    for (int k0 = 0; k0 < Ks; k0 += 64) {
        __syncthreads();
        *(uint4*)&As[srow * 64 + (sc0 ^ swz)]        = ra0;
        *(uint4*)&As[srow * 64 + ((sc0 + 32) ^ swz)] = ra1;
        *(uint4*)&Bs[srow * 64 + (sc0 ^ swz)]        = rb0;
        *(uint4*)&Bs[srow * 64 + ((sc0 + 32) ^ swz)] = rb1;
        __syncthreads();
        if (k0 + 64 < Ks) {
            const bhalf* An = Abase + k0 + 64;
            const bhalf* Bn = Bbase + k0 + 64;
            ra0 = mok ? *(const uint4*)(An + sc0)      : make_uint4(0u,0u,0u,0u);
            ra1 = mok ? *(const uint4*)(An + sc0 + 32) : make_uint4(0u,0u,0u,0u);
            rb0 = *(const uint4*)(Bn + sc0);
            rb1 = *(const uint4*)(Bn + sc0 + 32);
        }
#pragma unroll
        for (int kb = 0; kb < 2; ++kb) {
            const int kc = kb * 32 + (lane >> 4) * 8;
            bhalf8 af[2], bfr[2];
#pragma unroll
            for (int i = 0; i < 2; ++i) {
                int rA = wm0 + i * 16 + (lane & 15);
                af[i] = *(const bhalf8*)&As[rA * 64 + (kc ^ ((rA & 7) << 3))];
                int rB = wn0 + i * 16 + (lane & 15);
                bfr[i] = *(const bhalf8*)&Bs[rB * 64 + (kc ^ ((rB & 7) << 3))];
            }
#pragma unroll
            for (int mi = 0; mi < 2; ++mi)
#pragma unroll
                for (int ni = 0; ni < 2; ++ni)
                    acc[mi][ni] = __builtin_amdgcn_mfma_f32_16x16x32_bf16(
                        af[mi], bfr[ni], acc[mi][ni], 0, 0, 0);
        }
    }

#pragma unroll
    for (int mi = 0; mi < 2; ++mi)
#pragma unroll
        for (int ni = 0; ni < 2; ++ni) {
            int col = n0 + wn0 + ni * 16 + (lane & 15);
            f32x4 v = acc[mi][ni];
            if (S > 1) {
#pragma unroll
                for (int r = 0; r < 4; ++r) {
                    int row = m0 + wm0 + mi * 16 + (lane >> 4) * 4 + r;
                    if (row < M)
                        ((float*)Cv)[((size_t)kz * M + row) * ldc + col] = v[r];
                }
            } else {
                float bb = bias ? bias[col] : 0.f;
#pragma unroll
                for (int r = 0; r < 4; ++r) {
                    int row = m0 + wm0 + mi * 16 + (lane >> 4) * 4 + r;
                    if (row < M) {
                        float x = v[r] + bb;
                        if (RELU) x = fmaxf(x, 0.f);
                        if (OUTBF16) ((bhalf*)Cv)[(size_t)row * ldc + col] = (bhalf)x;
                        else         ((float*)Cv)[(size_t)row * ldc + col] = x;
                    }
                }
            }
        }
}

// ---------------------------------------------------------------------------
// Fused GCN layer GEMM, two-phase (m then r), shared 16KB LDS, prefetch
// across phase boundary. Epilogue: v = relu(m+b)+relu(r+rb) -> bf16 +
// per-column sum/sumsq atomics.
// ---------------------------------------------------------------------------
__global__ __launch_bounds__(256) void gcn_gemm_fused(const bhalf* __restrict__ Aagg,
                                                      const bhalf* __restrict__ Ax,
                                                      const bhalf* __restrict__ BW,
                                                      const bhalf* __restrict__ BrW,
                                                      const float* __restrict__ b,
                                                      const float* __restrict__ rb,
                                                      bhalf* __restrict__ vout,
                                                      float* __restrict__ stats,
                                                      int M, int K)
{
    __shared__ bhalf As[64 * 64];
    __shared__ bhalf Bs[64 * 64];
    __shared__ float ssum[64], ssq[64];

    const int t = threadIdx.x;
    const int lane = t & 63, wid = t >> 6;
    const int wm0 = (wid >> 1) * 32, wn0 = (wid & 1) * 32;
    const int m0 = blockIdx.y * 64, n0 = blockIdx.x * 64;

    const int srow = t >> 2;
    const int sc0 = (t & 3) << 3;
    const int nk = K >> 6;

    f32x4 accM[2][2] = {};
    f32x4 accR[2][2] = {};
    uint4 ra0, ra1, rb0, rb1;

    const bool mok = (m0 + srow) < M;
    const bhalf* A0r = Aagg + (size_t)(m0 + srow) * K;
    const bhalf* A1r = Ax + (size_t)(m0 + srow) * K;
    const bhalf* B0r = BW + (size_t)(n0 + srow) * K;
    const bhalf* B1r = BrW + (size_t)(n0 + srow) * K;

    ra0 = mok ? *(const uint4*)(A0r + sc0)      : make_uint4(0u,0u,0u,0u);
    ra1 = mok ? *(const uint4*)(A0r + sc0 + 32) : make_uint4(0u,0u,0u,0u);
    rb0 = *(const uint4*)(B0r + sc0);
    rb1 = *(const uint4*)(B0r + sc0 + 32);

    const int swz = (srow & 7) << 3;
    const int total = 2 * nk;
    for (int ii = 0; ii < total; ++ii) {
        __syncthreads();
        *(uint4*)&As[srow * 64 + (sc0 ^ swz)]        = ra0;
        *(uint4*)&As[srow * 64 + ((sc0 + 32) ^ swz)] = ra1;
        *(uint4*)&Bs[srow * 64 + (sc0 ^ swz)]        = rb0;
        *(uint4*)&Bs[srow * 64 + ((sc0 + 32) ^ swz)] = rb1;
        __syncthreads();
        int jj = ii + 1;
        if (jj < total) {
            bool seln = jj >= nk;
            int kk = (seln ? jj - nk : jj) << 6;
            const bhalf* Ab = (seln ? A1r : A0r) + kk;
            const bhalf* Bb = (seln ? B1r : B0r) + kk;
            ra0 = mok ? *(const uint4*)(Ab + sc0)      : make_uint4(0u,0u,0u,0u);
            ra1 = mok ? *(const uint4*)(Ab + sc0 + 32) : make_uint4(0u,0u,0u,0u);
            rb0 = *(const uint4*)(Bb + sc0);
            rb1 = *(const uint4*)(Bb + sc0 + 32);
        }
        const bool selc = ii >= nk;
#pragma unroll
        for (int kb = 0; kb < 2; ++kb) {
            const int kc = kb * 32 + (lane >> 4) * 8;
            bhalf8 af[2], bfr[2];
#pragma unroll
            for (int i = 0; i < 2; ++i) {
                int rA = wm0 + i * 16 + (lane & 15);
                af[i] = *(const bhalf8*)&As[rA * 64 + (kc ^ ((rA & 7) << 3))];
                int rB = wn0 + i * 16 + (lane & 15);
                bfr[i] = *(const bhalf8*)&Bs[rB * 64 + (kc ^ ((rB & 7) << 3))];
            }
            if (!selc) {
#pragma unroll
                for (int mi = 0; mi < 2; ++mi)
#pragma unroll
                    for (int ni = 0; ni < 2; ++ni)
                        accM[mi][ni] = __builtin_amdgcn_mfma_f32_16x16x32_bf16(
                            af[mi], bfr[ni], accM[mi][ni], 0, 0, 0);
            } else {
#pragma unroll
                for (int mi = 0; mi < 2; ++mi)
#pragma unroll
                    for (int ni = 0; ni < 2; ++ni)
                        accR[mi][ni] = __builtin_amdgcn_mfma_f32_16x16x32_bf16(
                            af[mi], bfr[ni], accR[mi][ni], 0, 0, 0);
            }
        }
    }

    if (t < 64) { ssum[t] = 0.f; ssq[t] = 0.f; }
    __syncthreads();
    float sloc[2] = {0.f, 0.f}, s2loc[2] = {0.f, 0.f};
#pragma unroll
    for (int ni = 0; ni < 2; ++ni) {
        int cl = wn0 + ni * 16 + (lane & 15);
        int c = n0 + cl;
        float bb = b[c], rbb = rb[c];
#pragma unroll
        for (int mi = 0; mi < 2; ++mi) {
            f32x4 a0v = accM[mi][ni], a1v = accR[mi][ni];
#pragma unroll
            for (int r = 0; r < 4; ++r) {
                int row = m0 + wm0 + mi * 16 + (lane >> 4) * 4 + r;
                if (row < M) {
                    float x = fmaxf(a0v[r] + bb, 0.f) + fmaxf(a1v[r] + rbb, 0.f);
                    vout[(size_t)row * HID + c] = (bhalf)x;
                    sloc[ni] += x;
                    s2loc[ni] += x * x;
                }
            }
        }
        atomicAdd(&ssum[cl], sloc[ni]);
        atomicAdd(&ssq[cl], s2loc[ni]);
    }
    __syncthreads();
    if (t < 64) {
        atomicAdd(&stats[n0 + t], ssum[t]);
        atomicAdd(&stats[HID + n0 + t], ssq[t]);
    }
}

// sum S split-K partials + bias + act
template<int RELU, int OUTBF16>
__global__ __launch_bounds__(256) void splitk_combine(const float* __restrict__ part,
                                                      int S, int M, int N, int ldo,
                                                      const float* __restrict__ bias,
                                                      void* __restrict__ outv)
{
    int i = blockIdx.x * blockDim.x + threadIdx.x;
    int n4 = N >> 2;
    if (i >= M * n4) return;
    int row = i / n4, c4 = (i - row * n4) << 2;
    float4 s = make_float4(0.f, 0.f, 0.f, 0.f);
    for (int z = 0; z < S; ++z) {
        float4 p = *(const float4*)(part + ((size_t)z * M + row) * N + c4);
        s.x += p.x; s.y += p.y; s.z += p.z; s.w += p.w;
    }
    float4 bb = *(const float4*)(bias + c4);
    s.x += bb.x; s.y += bb.y; s.z += bb.z; s.w += bb.w;
    if (RELU) {
        s.x = fmaxf(s.x, 0.f); s.y = fmaxf(s.y, 0.f);
        s.z = fmaxf(s.z, 0.f); s.w = fmaxf(s.w, 0.f);
    }
    if (OUTBF16) {
        bhalf4 o = {(bhalf)s.x, (bhalf)s.y, (bhalf)s.z, (bhalf)s.w};
        *(bhalf4*)((bhalf*)outv + (size_t)row * ldo + c4) = o;
    } else {
        *(float4*)((float*)outv + (size_t)row * ldo + c4) = s;
    }
}

// last head layer: combine S partials + bias + relu, dot with W3
__global__ __launch_bounds__(128) void splitk_combine_dot(const float* __restrict__ part,
                                                          int S, int M, int N,
                                                          const float* __restrict__ bias,
                                                          const float* __restrict__ W3,
                                                          const float* __restrict__ b3,
                                                          float* __restrict__ out)
{
    int row = blockIdx.x, t = threadIdx.x;
    int c4 = t << 2;
    float4 s = make_float4(0.f, 0.f, 0.f, 0.f);
    for (int z = 0; z < S; ++z) {
        float4 p = *(const float4*)(part + ((size_t)z * M + row) * N + c4);
        s.x += p.x; s.y += p.y; s.z += p.z; s.w += p.w;
    }
    float4 bb = *(const float4*)(bias + c4);
    float4 w = *(const float4*)(W3 + c4);
    float d = fmaxf(s.x + bb.x, 0.f) * w.x + fmaxf(s.y + bb.y, 0.f) * w.y
            + fmaxf(s.z + bb.z, 0.f) * w.z + fmaxf(s.w + bb.w, 0.f) * w.w;
#pragma unroll
    for (int off = 32; off > 0; off >>= 1) d += __shfl_xor(d, off);
    __shared__ float ws2[2];
    if ((t & 63) == 0) ws2[t >> 6] = d;
    __syncthreads();
    if (t == 0) out[row] = ws2[0] + ws2[1] + b3[0];
}

// ---------------------------------------------------------------------------
// Prep mega-kernel: blocks [0,4288) transpose+convert 8 weight tensors;
// [4288, 7812) convert node_feats + rdkit to bf16; [7812, ...) zero the
// stats+counts+cursor region.
// ---------------------------------------------------------------------------
struct WEnt { const float* src; bhalf* dst; int K; int N; int tiles_end; };
struct PrepTab {
    WEnt e[8];
    const float* ca; bhalf* coa; int n4a;
    const float* cb; bhalf* cob; int n4b;
    uint4* zbase; int zn;
};

#define WTILES 4288
#define CONVB  3524

__global__ __launch_bounds__(256) void prep_batch(PrepTab tab)
{
    __shared__ float tile[32][33];
    int tb = blockIdx.x;
    int t = threadIdx.x;
    if (tb < WTILES) {
        int idx = 0;
#pragma unroll
        for (int i = 0; i < 8; ++i)
            if (tb >= tab.e[i].tiles_end) idx = i + 1;
        const WEnt& E = tab.e[idx];
        int t0 = idx ? tab.e[idx - 1].tiles_end : 0;
        int lt = tb - t0;
        int tX = E.N >> 5;
        int bx = (lt % tX) << 5;
        int by = (lt / tX) << 5;
        int tx = t & 31, ty = t >> 5;
#pragma unroll
        for (int i = 0; i < 32; i += 8)
            tile[ty + i][tx] = E.src[(size_t)(by + ty + i) * E.N + bx + tx];
        __syncthreads();
#pragma unroll
        for (int i = 0; i < 32; i += 8)
            E.dst[(size_t)(bx + ty + i) * E.K + by + tx] = (bhalf)tile[tx][ty + i];
    } else if (tb < WTILES + CONVB) {
        int i = (tb - WTILES) * 256 + t;
        const float* s; bhalf* d; int j;
        if (i < tab.n4a) { s = tab.ca; d = tab.coa; j = i; }
        else { j = i - tab.n4a; if (j >= tab.n4b) return; s = tab.cb; d = tab.cob; }
        float4 v = ((const float4*)s)[j];
        bhalf4 o = {(bhalf)v.x, (bhalf)v.y, (bhalf)v.z, (bhalf)v.w};
        ((bhalf4*)d)[j] = o;
    } else {
        int j = (tb - WTILES - CONVB) * 256 + t;
        if (j < tab.zn) tab.zbase[j] = make_uint4(0u, 0u, 0u, 0u);
    }
}

// ---------------------------------------------------------------------------
// CSR build
// ---------------------------------------------------------------------------
__global__ void csr_count(const int* __restrict__ dst, int* __restrict__ counts)
{
    int e = blockIdx.x * blockDim.x + threadIdx.x;
    if (e >= N_EDGES) return;
    atomicAdd(&counts[dst[e]], 1);
}

__global__ __launch_bounds__(256) void csr_scan_a(const int* __restrict__ counts,
                                                  int* __restrict__ bsum)
{
    int i = blockIdx.x * 256 + threadIdx.x;
    int v = (i < N_NODES) ? counts[i] : 0;
#pragma unroll
    for (int off = 32; off > 0; off >>= 1) v += __shfl_down(v, off);
    __shared__ int ws[4];
    if ((threadIdx.x & 63) == 0) ws[threadIdx.x >> 6] = v;
    __syncthreads();
    if (threadIdx.x == 0) bsum[blockIdx.x] = ws[0] + ws[1] + ws[2] + ws[3];
}

// per-block prefix of bsum computed inline (scan_b folded in)
__global__ __launch_bounds__(256) void csr_scan_c(const int* __restrict__ counts,
                                                  const int* __restrict__ bsum, int nb,
                                                  int* __restrict__ offsets)
{
    int t = threadIdx.x, b = blockIdx.x;
    int i = b * 256 + t;
    int v = (i < N_NODES) ? counts[i] : 0;
    int x = v;
#pragma unroll
    for (int off = 1; off < 64; off <<= 1) {
        int y = __shfl_up(x, off);
        if ((t & 63) >= off) x += y;
    }
    __shared__ int wsum[4];
    __shared__ int tmp[128];
    __shared__ int addsh;
    if ((t & 63) == 63) wsum[t >> 6] = x;
    if (t < 128) tmp[t] = (t < nb) ? bsum[t] : 0;
    __syncthreads();
    if (t == 0) {
        int a = 0;
        for (int j = 0; j < b; ++j) a += tmp[j];
        addsh = a;
    }
    __syncthreads();
    int add = addsh;
    for (int w = 0; w < (t >> 6); ++w) add += wsum[w];
    int excl = x - v + add;
    if (i < N_NODES) offsets[i] = excl;
    if (i == N_NODES - 1) offsets[N_NODES] = excl + v;
}

__global__ void csr_fill(const int* __restrict__ src, const int* __restrict__ dst,
                         const int* __restrict__ offsets, int* __restrict__ cursor,
                         int* __restrict__ eidx)
{
    int e = blockIdx.x * blockDim.x + threadIdx.x;
    if (e >= N_EDGES) return;
    int d = dst[e];
    int slot = offsets[d] + atomicAdd(&cursor[d], 1);
    eidx[slot] = src[e];
}

__global__ void csr_sort_wave(const int* __restrict__ offsets, int* __restrict__ eidx)
{
    int gidx = blockIdx.x * blockDim.x + threadIdx.x;
    int n = gidx >> 6, lane = gidx & 63;
    if (n >= N_NODES) return;
    int lo = offsets[n], hi = offsets[n + 1];
    int cnt = hi - lo;
    if (cnt <= 1) return;
    if (cnt <= 64) {
        int v = (lane < cnt) ? eidx[lo + lane] : 0x7fffffff;
        int rank = 0;
        for (int j = 0; j < cnt; ++j) {
            int vj = __shfl(v, j);
            if (vj < v || (vj == v && j < lane)) ++rank;
        }
        if (lane < cnt) eidx[lo + rank] = v;
    } else if (lane == 0) {
        for (int i = lo + 1; i < hi; ++i) {
            int v = eidx[i]; int j = i - 1;
            while (j >= lo && eidx[j] > v) { eidx[j + 1] = eidx[j]; --j; }
            eidx[j + 1] = v;
        }
    }
}

// ---------------------------------------------------------------------------
// Gather-aggregate, layer 1 (128 cols): wave per node, bhalf2/lane, unroll 4.
// ---------------------------------------------------------------------------
__global__ __launch_bounds__(256) void edge_gather1(const bhalf* __restrict__ m,
                                                    const int* __restrict__ offsets,
                                                    const int* __restrict__ eidx,
                                                    bhalf* __restrict__ agg)
{
    int gidx = blockIdx.x * blockDim.x + threadIdx.x;
    int n = gidx >> 6, lane = gidx & 63;
    if (n >= N_NODES) return;
    int lo = offsets[n], hi = offsets[n + 1];
    const bhalf* base = m + lane * 2;
    float ax = 0.f, ay = 0.f;
    int i = lo;
    for (; i + 4 <= hi; i += 4) {
        bhalf2 v0 = *(const bhalf2*)(base + (size_t)eidx[i] * IN_FEATS);
        bhalf2 v1 = *(const bhalf2*)(base + (size_t)eidx[i + 1] * IN_FEATS);
        bhalf2 v2 = *(const bhalf2*)(base + (size_t)eidx[i + 2] * IN_FEATS);
        bhalf2 v3 = *(const bhalf2*)(base + (size_t)eidx[i + 3] * IN_FEATS);
        ax += ((float)v0.x + (float)v1.x) + ((float)v2.x + (float)v3.x);
        ay += ((float)v0.y + (float)v1.y) + ((float)v2.y + (float)v3.y);
    }
    for (; i < hi; ++i) {
        bhalf2 v0 = *(const bhalf2*)(base + (size_t)eidx[i] * IN_FEATS);
        ax += (float)v0.x; ay += (float)v0.y;
    }
    bhalf2 o = {(bhalf)ax, (bhalf)ay};
    *(bhalf2*)(agg + (size_t)n * IN_FEATS + lane * 2) = o;
}

// ---------------------------------------------------------------------------
// Gather-aggregate, layer 2 (256 cols): TWO waves per node (half-row each),
// bhalf2/lane, unroll 4 -> 2x wave parallelism on the random-access path.
// ---------------------------------------------------------------------------
__global__ __launch_bounds__(256) void edge_gather2(const bhalf* __restrict__ m,
                                                    const int* __restrict__ offsets,
                                                    const int* __restrict__ eidx,
                                                    bhalf* __restrict__ agg)
{
    int gidx = blockIdx.x * blockDim.x + threadIdx.x;
    int w = gidx >> 6, lane = gidx & 63;
    int n = w >> 1, half = w & 1;
    if (n >= N_NODES) return;
    int lo = offsets[n], hi = offsets[n + 1];
    int coff = half * 128 + lane * 2;
    const bhalf* base = m + coff;
    float ax = 0.f, ay = 0.f;
    int i = lo;
    for (; i + 4 <= hi; i += 4) {
        bhalf2 v0 = *(const bhalf2*)(base + (size_t)eidx[i] * HID);
        bhalf2 v1 = *(const bhalf2*)(base + (size_t)eidx[i + 1] * HID);
        bhalf2 v2 = *(const bhalf2*)(base + (size_t)eidx[i + 2] * HID);
        bhalf2 v3 = *(const bhalf2*)(base + (size_t)eidx[i + 3] * HID);
        ax += ((float)v0.x + (float)v1.x) + ((float)v2.x + (float)v3.x);
        ay += ((float)v0.y + (float)v1.y) + ((float)v2.y + (float)v3.y);
    }
    for (; i < hi; ++i) {
        bhalf2 v0 = *(const bhalf2*)(base + (size_t)eidx[i] * HID);
        ax += (float)v0.x; ay += (float)v0.y;
    }
    bhalf2 o = {(bhalf)ax, (bhalf)ay};
    *(bhalf2*)(agg + (size_t)n * HID + coff) = o;
}

// ---------------------------------------------------------------------------
// Wave-per-node BN with inline finalize; v input is bf16.
// MODE 0: write bf16 h. MODE 1: write bf16 h + node attention weight.
// ---------------------------------------------------------------------------
template<int MODE>
__global__ __launch_bounds__(256) void bn_row(const bhalf* __restrict__ v,
                                              const float* __restrict__ stats,
                                              float inv_n,
                                              const float* __restrict__ g,
                                              const float* __restrict__ be,
                                              bhalf* __restrict__ outb,
                                              const float* __restrict__ awW,
                                              const float* __restrict__ awb,
                                              float* __restrict__ w)
{
    int gidx = blockIdx.x * blockDim.x + threadIdx.x;
    int n = gidx >> 6, lane = gidx & 63;
    if (n >= N_NODES) return;
    int col = lane * 4;
    bhalf4 vv = *(const bhalf4*)(v + (size_t)n * HID + col);
    float4 sm = *(const float4*)(stats + col);
    float4 sq = *(const float4*)(stats + HID + col);
    float4 gg = *(const float4*)(g + col);
    float4 bb = *(const float4*)(be + col);
    float mux = sm.x * inv_n, muy = sm.y * inv_n, muz = sm.z * inv_n, muw = sm.w * inv_n;
    float rsx = rsqrtf(sq.x * inv_n - mux * mux + 1e-5f);
    float rsy = rsqrtf(sq.y * inv_n - muy * muy + 1e-5f);
    float rsz = rsqrtf(sq.z * inv_n - muz * muz + 1e-5f);
    float rsw = rsqrtf(sq.w * inv_n - muw * muw + 1e-5f);
    float4 o;
    o.x = gg.x * ((float)vv.x - mux) * rsx + bb.x;
    o.y = gg.y * ((float)vv.y - muy) * rsy + bb.y;
    o.z = gg.z * ((float)vv.z - muz) * rsz + bb.z;
    o.w = gg.w * ((float)vv.w - muw) * rsw + bb.w;
    bhalf4 ob = {(bhalf)o.x, (bhalf)o.y, (bhalf)o.z, (bhalf)o.w};
    *(bhalf4*)(outb + (size_t)n * HID + col) = ob;
    if (MODE == 1) {
        float4 wv = *(const float4*)(awW + col);
        float d = o.x * wv.x + o.y * wv.y + o.z * wv.z + o.w * wv.w;
#pragma unroll
        for (int off = 32; off > 0; off >>= 1) d += __shfl_xor(d, off);
        if (lane == 0) w[n] = 1.f / (1.f + expf(-(d + awb[0])));
    }
}

// ---------------------------------------------------------------------------
__global__ __launch_bounds__(256) void readout(const bhalf* __restrict__ h,
                                               const float* __restrict__ w,
                                               const int* __restrict__ gid,
                                               bhalf* __restrict__ z)
{
    int g = blockIdx.x, col = threadIdx.x;
    int lo = 0, hi = N_NODES;
    while (lo < hi) { int mid = (lo + hi) >> 1; if (gid[mid] < g) lo = mid + 1; else hi = mid; }
    int start = lo;
    hi = N_NODES;
    while (lo < hi) { int mid = (lo + hi) >> 1; if (gid[mid] <= g) lo = mid + 1; else hi = mid; }
    int end = lo;
    float s = 0.f, mx = -INFINITY;
    for (int n = start; n < end; ++n) {
        float v = (float)h[(size_t)n * HID + col];
        s = fmaf(v, w[n], s);
        mx = fmaxf(mx, v);
    }
    z[(size_t)g * 1024 + col] = (bhalf)s;
    z[(size_t)g * 1024 + HID + col] = (bhalf)mx;
}

// ---------------------------------------------------------------------------
extern "C" void kernel_launch(void* const* d_in, const int* in_sizes, int n_in,
                              void* d_out, int out_size, void* d_ws, size_t ws_size,
                              hipStream_t stream)
{
    (void)in_sizes; (void)n_in; (void)out_size; (void)ws_size;

    const float* node_feats = (const float*)d_in[0];
    const float* rdkit      = (const float*)d_in[1];
    const int*   src        = (const int*)d_in[2];
    const int*   dst        = (const int*)d_in[3];
    const int*   gid        = (const int*)d_in[4];
    const float* W1  = (const float*)d_in[5];
    const float* b1  = (const float*)d_in[6];
    const float* rW1 = (const float*)d_in[7];
    const float* rb1 = (const float*)d_in[8];
    const float* g1  = (const float*)d_in[9];
    const float* be1 = (const float*)d_in[10];
    const float* W2  = (const float*)d_in[11];
    const float* b2  = (const float*)d_in[12];
    const float* rW2 = (const float*)d_in[13];
    const float* rb2 = (const float*)d_in[14];
    const float* g2  = (const float*)d_in[15];
    const float* be2 = (const float*)d_in[16];
    const float* aw_W  = (const float*)d_in[17];
    const float* aw_b  = (const float*)d_in[18];
    const float* rk_W1 = (const float*)d_in[19];
    const float* rk_b1 = (const float*)d_in[20];
    const float* rk_W2 = (const float*)d_in[21];
    const float* rk_b2 = (const float*)d_in[22];
    const float* c_W1  = (const float*)d_in[23];
    const float* c_b1  = (const float*)d_in[24];
    const float* c_W2  = (const float*)d_in[25];
    const float* c_b2  = (const float*)d_in[26];
    const float* c_W3  = (const float*)d_in[27];
    const float* c_b3  = (const float*)d_in[28];

    float* out = (float*)d_out;

    const size_t NODE = (size_t)N_NODES * HID;         // 5,120,000
    bhalf* nfb   = (bhalf*)d_ws;                       // [20000,128]
    bhalf* h1b   = nfb + (size_t)N_NODES * IN_FEATS;   // [20000,256]
    bhalf* h2b   = h1b + NODE;                         // [20000,256]
    bhalf* aggb  = h2b + NODE;                         // [20000,256]
    bhalf* vb    = aggb + NODE;                        // [20000,256]
    bhalf* W1cat = vb + NODE;                          // [512,128]
    bhalf* W2cat = W1cat + 512 * 128;                  // [512,256]
    bhalf* rkW1t = W2cat + 512 * 256;                  // [1024,2048]
    bhalf* rkW2t = rkW1t + 2048 * 1024;                // [512,1024]
    bhalf* cW1t  = rkW2t + 1024 * 512;                 // [1024,1024]
    bhalf* cW2t  = cW1t + 1024 * 1024;                 // [512,1024]
    bhalf* rdkb  = cW2t + 1024 * 512;                  // [512,2048]
    // zero region: stats1|stats2|counts|cursor contiguous (41024 x 4B)
    float* stats1 = (float*)(rdkb + 512 * 2048);       // 512 raw sum|sumsq
    float* stats2 = stats1 + 512;                      // 512
    int*   counts = (int*)(stats2 + 512);              // N
    int*   cursor = counts + N_NODES;                  // N
    float* wbuf   = (float*)(cursor + N_NODES);        // 20000
    int*   offsets = (int*)(wbuf + N_NODES);           // N+1
    int*   eidx    = offsets + N_NODES + 1;            // N_EDGES
    int*   bsum    = eidx + N_EDGES;                   // 128
    bhalf* rkhb  = (bhalf*)(bsum + 128);               // [512,1024]
    bhalf* zb    = rkhb + 512 * 1024;                  // [512,1024]
    bhalf* ch1b  = zb + 512 * 1024;                    // [512,1024]
    float* spart = (float*)(ch1b + 512 * 1024);        // split-K partials (<=16MB)

    dim3 blk(256);
    const int EPB = (N_EDGES + 255) / 256;
    const int NPB = (N_NODES + 255) / 256;             // 79
    const int NWAVE = (N_NODES * 64) / 256;            // 5000: wave per node
    const int NWAVE2 = (N_NODES * 128) / 256;          // 10000: 2 waves per node
    dim3 gfused(HID / 64, (N_NODES + 63) / 64);        // (4, 313)

    // ---------------- prep: weights + inputs + zeroing (1 launch) ----------
    PrepTab tab;
    tab.e[0] = {W1,    W1cat,             128, 256,   32};
    tab.e[1] = {rW1,   W1cat + 256 * 128, 128, 256,   64};
    tab.e[2] = {W2,    W2cat,             256, 256,  128};
    tab.e[3] = {rW2,   W2cat + 256 * 256, 256, 256,  192};
    tab.e[4] = {rk_W1, rkW1t,            2048, 1024, 2240};
    tab.e[5] = {rk_W2, rkW2t,            1024, 512,  2752};
    tab.e[6] = {c_W1,  cW1t,             1024, 1024, 3776};
    tab.e[7] = {c_W2,  cW2t,             1024, 512,  4288};
    tab.ca = node_feats; tab.coa = nfb;  tab.n4a = N_NODES * IN_FEATS / 4;
    tab.cb = rdkit;      tab.cob = rdkb; tab.n4b = 512 * 2048 / 4;
    tab.zbase = (uint4*)stats1;
    tab.zn = (1024 + 2 * N_NODES) / 4;                 // 41024 ints -> 10256 uint4
    const int ZB = (tab.zn + 255) / 256;               // 41
    prep_batch<<<WTILES + CONVB + ZB, blk, 0, stream>>>(tab);

    // ---------------- CSR build ----------------
    csr_count<<<EPB, blk, 0, stream>>>(dst, counts);
    csr_scan_a<<<NPB, blk, 0, stream>>>(counts, bsum);
    csr_scan_c<<<NPB, blk, 0, stream>>>(counts, bsum, NPB, offsets);
    csr_fill<<<EPB, blk, 0, stream>>>(src, dst, offsets, cursor, eidx);
    csr_sort_wave<<<NWAVE, blk, 0, stream>>>(offsets, eidx);

    // ---------------- Layer 1: gather -> fused GEMM(v,stats) -> BN ----------
    edge_gather1<<<NWAVE, blk, 0, stream>>>(nfb, offsets, eidx, aggb);
    gcn_gemm_fused<<<gfused, blk, 0, stream>>>(aggb, nfb, W1cat, W1cat + 256 * 128,
                                               b1, rb1, vb, stats1, N_NODES, IN_FEATS);
    bn_row<0><<<NWAVE, blk, 0, stream>>>(vb, stats1, 1.0f / N_NODES, g1, be1,
                                         h1b, nullptr, nullptr, nullptr);

    // ---------------- Layer 2 ----------------
    edge_gather2<<<NWAVE2, blk, 0, stream>>>(h1b, offsets, eidx, aggb);
    gcn_gemm_fused<<<gfused, blk, 0, stream>>>(aggb, h1b, W2cat, W2cat + 256 * 256,
                                               b2, rb2, vb, stats2, N_NODES, HID);
    bn_row<1><<<NWAVE, blk, 0, stream>>>(vb, stats2, 1.0f / N_NODES, g2, be2,
                                         h2b, aw_W, aw_b, wbuf);

    // ---------------- Readout ----------------
    readout<<<N_GRAPHS, HID, 0, stream>>>(h2b, wbuf, gid, zb);

    // ---------------- RDKit branch (split-K) ----------------
    gemm_mfma<0,0><<<dim3(16, 8, 8), blk, 0, stream>>>(rdkb, rkW1t, spart, nullptr,
                                                       512, 2048, 1024);
    splitk_combine<1,1><<<512, blk, 0, stream>>>(spart, 8, 512, 1024, 1024, rk_b1, rkhb);
    gemm_mfma<0,0><<<dim3(8, 8, 8), blk, 0, stream>>>(rkhb, rkW2t, spart, nullptr,
                                                      512, 1024, 512);
    splitk_combine<1,1><<<256, blk, 0, stream>>>(spart, 8, 512, 512, 1024, rk_b2, zb + 512);

    // ---------------- Combined head (split-K) ----------------
    gemm_mfma<0,0><<<dim3(16, 8, 4), blk, 0, stream>>>(zb, cW1t, spart, nullptr,
                                                       512, 1024, 1024);
    splitk_combine<1,1><<<512, blk, 0, stream>>>(spart, 4, 512, 1024, 1024, c_b1, ch1b);
    gemm_mfma<0,0><<<dim3(8, 8, 8), blk, 0, stream>>>(ch1b, cW2t, spart, nullptr,
                                                      512, 1024, 512);
    splitk_combine_dot<<<512, 128, 0, stream>>>(spart, 8, 512, 512, c_b2, c_W3, c_b3, out);
}

// Round 12
// 233.024 us; speedup vs baseline: 11.4545x; 1.0705x over previous
//
#include <hip/hip_runtime.h>
#include <hip/hip_bf16.h>
#include <cstdint>
#include <cstddef>

#define N_NODES 20000
#define N_EDGES 320000
#define N_GRAPHS 512
#define IN_FEATS 128
#define HID 256

typedef __bf16 bhalf;
typedef __bf16 bhalf8 __attribute__((ext_vector_type(8)));
typedef __bf16 bhalf4 __attribute__((ext_vector_type(4)));
typedef __bf16 bhalf2 __attribute__((ext_vector_type(2)));
typedef float f32x4 __attribute__((ext_vector_type(4)));

// Bijective XCD-aware block swizzle (m204): consecutive hardware dispatch ids
// (round-robin across 8 XCDs) map to contiguous logical tile ranges per XCD,
// so column-blocks sharing an A row-panel land on the same XCD's L2.
__device__ __forceinline__ int2 xcd_swz(int bx, int by, int nbx, int nby)
{
    int lid = by * nbx + bx;
    int nwg = nbx * nby;
    int q = nwg >> 3, r = nwg & 7;
    int xcd = lid & 7, loc = lid >> 3;
    int s = (xcd < r ? xcd * (q + 1) : r * (q + 1) + (xcd - r) * q) + loc;
    return make_int2(s % nbx, s / nbx);
}

// ---------------------------------------------------------------------------
// bf16 MFMA GEMM (head layers): C = A @ Bt^T. 64x64 tile, BK=64, 4 waves,
// register-prefetch. Split-K via gridDim.z (fp32 partials). XCD-swizzled.
// ---------------------------------------------------------------------------
template<int RELU, int OUTBF16>
__global__ __launch_bounds__(256) void gemm_mfma(const bhalf* __restrict__ A,
                                                 const bhalf* __restrict__ Bt,
                                                 void* __restrict__ Cv,
                                                 const float* __restrict__ bias,
                                                 int M, int K, int ldc)
{
    __shared__ bhalf As[64 * 64];
    __shared__ bhalf Bs[64 * 64];

    const int t = threadIdx.x;
    const int lane = t & 63, wid = t >> 6;
    const int wm0 = (wid >> 1) * 32, wn0 = (wid & 1) * 32;
    int2 bsw = xcd_swz(blockIdx.x, blockIdx.y, gridDim.x, gridDim.y);
    const int m0 = bsw.y * 64, n0 = bsw.x * 64;
    const int S = gridDim.z, kz = blockIdx.z;
    const int Ks = K / S;

    const int srow = t >> 2;
    const int sc0 = (t & 3) << 3;

    f32x4 acc[2][2] = {};
    uint4 ra0, ra1, rb0, rb1;

    const bool mok = (m0 + srow) < M;
    const bhalf* Abase = A + (size_t)(m0 + srow) * K + (size_t)kz * Ks;
    const bhalf* Bbase = Bt + (size_t)(n0 + srow) * K + (size_t)kz * Ks;

    ra0 = mok ? *(const uint4*)(Abase + sc0)      : make_uint4(0u,0u,0u,0u);
    ra1 = mok ? *(const uint4*)(Abase + sc0 + 32) : make_uint4(0u,0u,0u,0u);
    rb0 = *(const uint4*)(Bbase + sc0);
    rb1 = *(const uint4*)(Bbase + sc0 + 32);

    const int swz = (srow & 7) << 3;
    for (int k0 = 0; k0 < Ks; k0 += 64) {
        __syncthreads();
        *(uint4*)&As[srow * 64 + (sc0 ^ swz)]        = ra0;
        *(uint4*)&As[srow * 64 + ((sc0 + 32) ^ swz)] = ra1;
        *(uint4*)&Bs[srow * 64 + (sc0 ^ swz)]        = rb0;
        *(uint4*)&Bs[srow * 64 + ((sc0 + 32) ^ swz)] = rb1;
        __syncthreads();
        if (k0 + 64 < Ks) {
            const bhalf* An = Abase + k0 + 64;
            const bhalf* Bn = Bbase + k0 + 64;
            ra0 = mok ? *(const uint4*)(An + sc0)      : make_uint4(0u,0u,0u,0u);
            ra1 = mok ? *(const uint4*)(An + sc0 + 32) : make_uint4(0u,0u,0u,0u);
            rb0 = *(const uint4*)(Bn + sc0);
            rb1 = *(const uint4*)(Bn + sc0 + 32);
        }
#pragma unroll
        for (int kb = 0; kb < 2; ++kb) {
            const int kc = kb * 32 + (lane >> 4) * 8;
            bhalf8 af[2], bfr[2];
#pragma unroll
            for (int i = 0; i < 2; ++i) {
                int rA = wm0 + i * 16 + (lane & 15);
                af[i] = *(const bhalf8*)&As[rA * 64 + (kc ^ ((rA & 7) << 3))];
                int rB = wn0 + i * 16 + (lane & 15);
                bfr[i] = *(const bhalf8*)&Bs[rB * 64 + (kc ^ ((rB & 7) << 3))];
            }
#pragma unroll
            for (int mi = 0; mi < 2; ++mi)
#pragma unroll
                for (int ni = 0; ni < 2; ++ni)
                    acc[mi][ni] = __builtin_amdgcn_mfma_f32_16x16x32_bf16(
                        af[mi], bfr[ni], acc[mi][ni], 0, 0, 0);
        }
    }

#pragma unroll
    for (int mi = 0; mi < 2; ++mi)
#pragma unroll
        for (int ni = 0; ni < 2; ++ni) {
            int col = n0 + wn0 + ni * 16 + (lane & 15);
            f32x4 v = acc[mi][ni];
            if (S > 1) {
#pragma unroll
                for (int r = 0; r < 4; ++r) {
                    int row = m0 + wm0 + mi * 16 + (lane >> 4) * 4 + r;
                    if (row < M)
                        ((float*)Cv)[((size_t)kz * M + row) * ldc + col] = v[r];
                }
            } else {
                float bb = bias ? bias[col] : 0.f;
#pragma unroll
                for (int r = 0; r < 4; ++r) {
                    int row = m0 + wm0 + mi * 16 + (lane >> 4) * 4 + r;
                    if (row < M) {
                        float x = v[r] + bb;
                        if (RELU) x = fmaxf(x, 0.f);
                        if (OUTBF16) ((bhalf*)Cv)[(size_t)row * ldc + col] = (bhalf)x;
                        else         ((float*)Cv)[(size_t)row * ldc + col] = x;
                    }
                }
            }
        }
}

// ---------------------------------------------------------------------------
// Fused GCN layer GEMM, two-phase (m then r), shared 16KB LDS, prefetch
// across phase boundary, XCD-swizzled. Epilogue: v = relu(m+b)+relu(r+rb)
// -> bf16 + per-column sum/sumsq atomics.
// ---------------------------------------------------------------------------
__global__ __launch_bounds__(256) void gcn_gemm_fused(const bhalf* __restrict__ Aagg,
                                                      const bhalf* __restrict__ Ax,
                                                      const bhalf* __restrict__ BW,
                                                      const bhalf* __restrict__ BrW,
                                                      const float* __restrict__ b,
                                                      const float* __restrict__ rb,
                                                      bhalf* __restrict__ vout,
                                                      float* __restrict__ stats,
                                                      int M, int K)
{
    __shared__ bhalf As[64 * 64];
    __shared__ bhalf Bs[64 * 64];
    __shared__ float ssum[64], ssq[64];

    const int t = threadIdx.x;
    const int lane = t & 63, wid = t >> 6;
    const int wm0 = (wid >> 1) * 32, wn0 = (wid & 1) * 32;
    int2 bsw = xcd_swz(blockIdx.x, blockIdx.y, gridDim.x, gridDim.y);
    const int m0 = bsw.y * 64, n0 = bsw.x * 64;

    const int srow = t >> 2;
    const int sc0 = (t & 3) << 3;
    const int nk = K >> 6;

    f32x4 accM[2][2] = {};
    f32x4 accR[2][2] = {};
    uint4 ra0, ra1, rb0, rb1;

    const bool mok = (m0 + srow) < M;
    const bhalf* A0r = Aagg + (size_t)(m0 + srow) * K;
    const bhalf* A1r = Ax + (size_t)(m0 + srow) * K;
    const bhalf* B0r = BW + (size_t)(n0 + srow) * K;
    const bhalf* B1r = BrW + (size_t)(n0 + srow) * K;

    ra0 = mok ? *(const uint4*)(A0r + sc0)      : make_uint4(0u,0u,0u,0u);
    ra1 = mok ? *(const uint4*)(A0r + sc0 + 32) : make_uint4(0u,0u,0u,0u);
    rb0 = *(const uint4*)(B0r + sc0);
    rb1 = *(const uint4*)(B0r + sc0 + 32);

    const int swz = (srow & 7) << 3;
    const int total = 2 * nk;
    for (int ii = 0; ii < total; ++ii) {
        __syncthreads();
        *(uint4*)&As[srow * 64 + (sc0 ^ swz)]        = ra0;
        *(uint4*)&As[srow * 64 + ((sc0 + 32) ^ swz)] = ra1;
        *(uint4*)&Bs[srow * 64 + (sc0 ^ swz)]        = rb0;
        *(uint4*)&Bs[srow * 64 + ((sc0 + 32) ^ swz)] = rb1;
        __syncthreads();
        int jj = ii + 1;
        if (jj < total) {
            bool seln = jj >= nk;
            int kk = (seln ? jj - nk : jj) << 6;
            const bhalf* Ab = (seln ? A1r : A0r) + kk;
            const bhalf* Bb = (seln ? B1r : B0r) + kk;
            ra0 = mok ? *(const uint4*)(Ab + sc0)      : make_uint4(0u,0u,0u,0u);
            ra1 = mok ? *(const uint4*)(Ab + sc0 + 32) : make_uint4(0u,0u,0u,0u);
            rb0 = *(const uint4*)(Bb + sc0);
            rb1 = *(const uint4*)(Bb + sc0 + 32);
        }
        const bool selc = ii >= nk;
#pragma unroll
        for (int kb = 0; kb < 2; ++kb) {
            const int kc = kb * 32 + (lane >> 4) * 8;
            bhalf8 af[2], bfr[2];
#pragma unroll
            for (int i = 0; i < 2; ++i) {
                int rA = wm0 + i * 16 + (lane & 15);
                af[i] = *(const bhalf8*)&As[rA * 64 + (kc ^ ((rA & 7) << 3))];
                int rB = wn0 + i * 16 + (lane & 15);
                bfr[i] = *(const bhalf8*)&Bs[rB * 64 + (kc ^ ((rB & 7) << 3))];
            }
            if (!selc) {
#pragma unroll
                for (int mi = 0; mi < 2; ++mi)
#pragma unroll
                    for (int ni = 0; ni < 2; ++ni)
                        accM[mi][ni] = __builtin_amdgcn_mfma_f32_16x16x32_bf16(
                            af[mi], bfr[ni], accM[mi][ni], 0, 0, 0);
            } else {
#pragma unroll
                for (int mi = 0; mi < 2; ++mi)
#pragma unroll
                    for (int ni = 0; ni < 2; ++ni)
                        accR[mi][ni] = __builtin_amdgcn_mfma_f32_16x16x32_bf16(
                            af[mi], bfr[ni], accR[mi][ni], 0, 0, 0);
            }
        }
    }

    if (t < 64) { ssum[t] = 0.f; ssq[t] = 0.f; }
    __syncthreads();
    float sloc[2] = {0.f, 0.f}, s2loc[2] = {0.f, 0.f};
#pragma unroll
    for (int ni = 0; ni < 2; ++ni) {
        int cl = wn0 + ni * 16 + (lane & 15);
        int c = n0 + cl;
        float bb = b[c], rbb = rb[c];
#pragma unroll
        for (int mi = 0; mi < 2; ++mi) {
            f32x4 a0v = accM[mi][ni], a1v = accR[mi][ni];
#pragma unroll
            for (int r = 0; r < 4; ++r) {
                int row = m0 + wm0 + mi * 16 + (lane >> 4) * 4 + r;
                if (row < M) {
                    float x = fmaxf(a0v[r] + bb, 0.f) + fmaxf(a1v[r] + rbb, 0.f);
                    vout[(size_t)row * HID + c] = (bhalf)x;
                    sloc[ni] += x;
                    s2loc[ni] += x * x;
                }
            }
        }
        atomicAdd(&ssum[cl], sloc[ni]);
        atomicAdd(&ssq[cl], s2loc[ni]);
    }
    __syncthreads();
    if (t < 64) {
        atomicAdd(&stats[n0 + t], ssum[t]);
        atomicAdd(&stats[HID + n0 + t], ssq[t]);
    }
}

// sum S split-K partials + bias + act
template<int RELU, int OUTBF16>
__global__ __launch_bounds__(256) void splitk_combine(const float* __restrict__ part,
                                                      int S, int M, int N, int ldo,
                                                      const float* __restrict__ bias,
                                                      void* __restrict__ outv)
{
    int i = blockIdx.x * blockDim.x + threadIdx.x;
    int n4 = N >> 2;
    if (i >= M * n4) return;
    int row = i / n4, c4 = (i - row * n4) << 2;
    float4 s = make_float4(0.f, 0.f, 0.f, 0.f);
    for (int z = 0; z < S; ++z) {
        float4 p = *(const float4*)(part + ((size_t)z * M + row) * N + c4);
        s.x += p.x; s.y += p.y; s.z += p.z; s.w += p.w;
    }
    float4 bb = *(const float4*)(bias + c4);
    s.x += bb.x; s.y += bb.y; s.z += bb.z; s.w += bb.w;
    if (RELU) {
        s.x = fmaxf(s.x, 0.f); s.y = fmaxf(s.y, 0.f);
        s.z = fmaxf(s.z, 0.f); s.w = fmaxf(s.w, 0.f);
    }
    if (OUTBF16) {
        bhalf4 o = {(bhalf)s.x, (bhalf)s.y, (bhalf)s.z, (bhalf)s.w};
        *(bhalf4*)((bhalf*)outv + (size_t)row * ldo + c4) = o;
    } else {
        *(float4*)((float*)outv + (size_t)row * ldo + c4) = s;
    }
}

// last head layer: combine S partials + bias + relu, dot with W3
__global__ __launch_bounds__(128) void splitk_combine_dot(const float* __restrict__ part,
                                                          int S, int M, int N,
                                                          const float* __restrict__ bias,
                                                          const float* __restrict__ W3,
                                                          const float* __restrict__ b3,
                                                          float* __restrict__ out)
{
    int row = blockIdx.x, t = threadIdx.x;
    int c4 = t << 2;
    float4 s = make_float4(0.f, 0.f, 0.f, 0.f);
    for (int z = 0; z < S; ++z) {
        float4 p = *(const float4*)(part + ((size_t)z * M + row) * N + c4);
        s.x += p.x; s.y += p.y; s.z += p.z; s.w += p.w;
    }
    float4 bb = *(const float4*)(bias + c4);
    float4 w = *(const float4*)(W3 + c4);
    float d = fmaxf(s.x + bb.x, 0.f) * w.x + fmaxf(s.y + bb.y, 0.f) * w.y
            + fmaxf(s.z + bb.z, 0.f) * w.z + fmaxf(s.w + bb.w, 0.f) * w.w;
#pragma unroll
    for (int off = 32; off > 0; off >>= 1) d += __shfl_xor(d, off);
    __shared__ float ws2[2];
    if ((t & 63) == 0) ws2[t >> 6] = d;
    __syncthreads();
    if (t == 0) out[row] = ws2[0] + ws2[1] + b3[0];
}

// ---------------------------------------------------------------------------
// Prep mega-kernel: weight transpose+convert | input conversion | zeroing.
// ---------------------------------------------------------------------------
struct WEnt { const float* src; bhalf* dst; int K; int N; int tiles_end; };
struct PrepTab {
    WEnt e[8];
    const float* ca; bhalf* coa; int n4a;
    const float* cb; bhalf* cob; int n4b;
    uint4* zbase; int zn;
};

#define WTILES 4288
#define CONVB  3524

__global__ __launch_bounds__(256) void prep_batch(PrepTab tab)
{
    __shared__ float tile[32][33];
    int tb = blockIdx.x;
    int t = threadIdx.x;
    if (tb < WTILES) {
        int idx = 0;
#pragma unroll
        for (int i = 0; i < 8; ++i)
            if (tb >= tab.e[i].tiles_end) idx = i + 1;
        const WEnt& E = tab.e[idx];
        int t0 = idx ? tab.e[idx - 1].tiles_end : 0;
        int lt = tb - t0;
        int tX = E.N >> 5;
        int bx = (lt % tX) << 5;
        int by = (lt / tX) << 5;
        int tx = t & 31, ty = t >> 5;
#pragma unroll
        for (int i = 0; i < 32; i += 8)
            tile[ty + i][tx] = E.src[(size_t)(by + ty + i) * E.N + bx + tx];
        __syncthreads();
#pragma unroll
        for (int i = 0; i < 32; i += 8)
            E.dst[(size_t)(bx + ty + i) * E.K + by + tx] = (bhalf)tile[tx][ty + i];
    } else if (tb < WTILES + CONVB) {
        int i = (tb - WTILES) * 256 + t;
        const float* s; bhalf* d; int j;
        if (i < tab.n4a) { s = tab.ca; d = tab.coa; j = i; }
        else { j = i - tab.n4a; if (j >= tab.n4b) return; s = tab.cb; d = tab.cob; }
        float4 v = ((const float4*)s)[j];
        bhalf4 o = {(bhalf)v.x, (bhalf)v.y, (bhalf)v.z, (bhalf)v.w};
        ((bhalf4*)d)[j] = o;
    } else {
        int j = (tb - WTILES - CONVB) * 256 + t;
        if (j < tab.zn) tab.zbase[j] = make_uint4(0u, 0u, 0u, 0u);
    }
}

// ---------------------------------------------------------------------------
// CSR build
// ---------------------------------------------------------------------------
__global__ void csr_count(const int* __restrict__ dst, int* __restrict__ counts)
{
    int e = blockIdx.x * blockDim.x + threadIdx.x;
    if (e >= N_EDGES) return;
    atomicAdd(&counts[dst[e]], 1);
}

__global__ __launch_bounds__(256) void csr_scan_a(const int* __restrict__ counts,
                                                  int* __restrict__ bsum)
{
    int i = blockIdx.x * 256 + threadIdx.x;
    int v = (i < N_NODES) ? counts[i] : 0;
#pragma unroll
    for (int off = 32; off > 0; off >>= 1) v += __shfl_down(v, off);
    __shared__ int ws[4];
    if ((threadIdx.x & 63) == 0) ws[threadIdx.x >> 6] = v;
    __syncthreads();
    if (threadIdx.x == 0) bsum[blockIdx.x] = ws[0] + ws[1] + ws[2] + ws[3];
}

// per-block prefix of bsum computed inline
__global__ __launch_bounds__(256) void csr_scan_c(const int* __restrict__ counts,
                                                  const int* __restrict__ bsum, int nb,
                                                  int* __restrict__ offsets)
{
    int t = threadIdx.x, b = blockIdx.x;
    int i = b * 256 + t;
    int v = (i < N_NODES) ? counts[i] : 0;
    int x = v;
#pragma unroll
    for (int off = 1; off < 64; off <<= 1) {
        int y = __shfl_up(x, off);
        if ((t & 63) >= off) x += y;
    }
    __shared__ int wsum[4];
    __shared__ int tmp[128];
    __shared__ int addsh;
    if ((t & 63) == 63) wsum[t >> 6] = x;
    if (t < 128) tmp[t] = (t < nb) ? bsum[t] : 0;
    __syncthreads();
    if (t == 0) {
        int a = 0;
        for (int j = 0; j < b; ++j) a += tmp[j];
        addsh = a;
    }
    __syncthreads();
    int add = addsh;
    for (int w = 0; w < (t >> 6); ++w) add += wsum[w];
    int excl = x - v + add;
    if (i < N_NODES) offsets[i] = excl;
    if (i == N_NODES - 1) offsets[N_NODES] = excl + v;
}

__global__ void csr_fill(const int* __restrict__ src, const int* __restrict__ dst,
                         const int* __restrict__ offsets, int* __restrict__ cursor,
                         int* __restrict__ eidx)
{
    int e = blockIdx.x * blockDim.x + threadIdx.x;
    if (e >= N_EDGES) return;
    int d = dst[e];
    int slot = offsets[d] + atomicAdd(&cursor[d], 1);
    eidx[slot] = src[e];
}

__global__ void csr_sort_wave(const int* __restrict__ offsets, int* __restrict__ eidx)
{
    int gidx = blockIdx.x * blockDim.x + threadIdx.x;
    int n = gidx >> 6, lane = gidx & 63;
    if (n >= N_NODES) return;
    int lo = offsets[n], hi = offsets[n + 1];
    int cnt = hi - lo;
    if (cnt <= 1) return;
    if (cnt <= 64) {
        int v = (lane < cnt) ? eidx[lo + lane] : 0x7fffffff;
        int rank = 0;
        for (int j = 0; j < cnt; ++j) {
            int vj = __shfl(v, j);
            if (vj < v || (vj == v && j < lane)) ++rank;
        }
        if (lane < cnt) eidx[lo + rank] = v;
    } else if (lane == 0) {
        for (int i = lo + 1; i < hi; ++i) {
            int v = eidx[i]; int j = i - 1;
            while (j >= lo && eidx[j] > v) { eidx[j + 1] = eidx[j]; --j; }
            eidx[j + 1] = v;
        }
    }
}

// ---------------------------------------------------------------------------
// Gather-aggregate, layer 1 (128 cols = 256B row): one wave = 4 edges/step,
// 16 lanes x 16B per row. Final shfl-xor combine across the 4 lane-groups.
// ---------------------------------------------------------------------------
__global__ __launch_bounds__(256) void edge_gather1(const bhalf* __restrict__ m,
                                                    const int* __restrict__ offsets,
                                                    const int* __restrict__ eidx,
                                                    bhalf* __restrict__ agg)
{
    int gidx = blockIdx.x * blockDim.x + threadIdx.x;
    int n = gidx >> 6, lane = gidx & 63;
    if (n >= N_NODES) return;
    int lo = offsets[n], hi = offsets[n + 1];
    int sub = lane >> 4;              // edge slot 0..3
    int colb = (lane & 15) * 8;       // 8 bf16 columns
    float acc[8] = {};
    int i = lo;
    for (; i + 8 <= hi; i += 8) {
        bhalf8 v0 = *(const bhalf8*)(m + (size_t)eidx[i + sub] * IN_FEATS + colb);
        bhalf8 v1 = *(const bhalf8*)(m + (size_t)eidx[i + 4 + sub] * IN_FEATS + colb);
#pragma unroll
        for (int j = 0; j < 8; ++j) acc[j] += (float)v0[j] + (float)v1[j];
    }
    if (i + 4 <= hi) {
        bhalf8 v0 = *(const bhalf8*)(m + (size_t)eidx[i + sub] * IN_FEATS + colb);
#pragma unroll
        for (int j = 0; j < 8; ++j) acc[j] += (float)v0[j];
        i += 4;
    }
    if (i < hi && sub < hi - i) {
        bhalf8 v0 = *(const bhalf8*)(m + (size_t)eidx[i + sub] * IN_FEATS + colb);
#pragma unroll
        for (int j = 0; j < 8; ++j) acc[j] += (float)v0[j];
    }
#pragma unroll
    for (int j = 0; j < 8; ++j) {
        acc[j] += __shfl_xor(acc[j], 16);
        acc[j] += __shfl_xor(acc[j], 32);
    }
    if (sub == 0) {
        bhalf8 o;
#pragma unroll
        for (int j = 0; j < 8; ++j) o[j] = (bhalf)acc[j];
        *(bhalf8*)(agg + (size_t)n * IN_FEATS + colb) = o;
    }
}

// ---------------------------------------------------------------------------
// Gather-aggregate, layer 2 (256 cols = 512B row): one wave = 2 edges/step,
// 32 lanes x 16B per row, unroll 4 -> 4 outstanding 16B loads per lane.
// ---------------------------------------------------------------------------
__global__ __launch_bounds__(256) void edge_gather2(const bhalf* __restrict__ m,
                                                    const int* __restrict__ offsets,
                                                    const int* __restrict__ eidx,
                                                    bhalf* __restrict__ agg)
{
    int gidx = blockIdx.x * blockDim.x + threadIdx.x;
    int n = gidx >> 6, lane = gidx & 63;
    if (n >= N_NODES) return;
    int lo = offsets[n], hi = offsets[n + 1];
    int sub = lane >> 5;              // edge slot 0..1
    int colb = (lane & 31) * 8;       // 8 bf16 columns
    float acc[8] = {};
    int i = lo;
    for (; i + 8 <= hi; i += 8) {
        bhalf8 v0 = *(const bhalf8*)(m + (size_t)eidx[i + sub] * HID + colb);
        bhalf8 v1 = *(const bhalf8*)(m + (size_t)eidx[i + 2 + sub] * HID + colb);
        bhalf8 v2 = *(const bhalf8*)(m + (size_t)eidx[i + 4 + sub] * HID + colb);
        bhalf8 v3 = *(const bhalf8*)(m + (size_t)eidx[i + 6 + sub] * HID + colb);
#pragma unroll
        for (int j = 0; j < 8; ++j)
            acc[j] += ((float)v0[j] + (float)v1[j]) + ((float)v2[j] + (float)v3[j]);
    }
    for (; i + 2 <= hi; i += 2) {
        bhalf8 v0 = *(const bhalf8*)(m + (size_t)eidx[i + sub] * HID + colb);
#pragma unroll
        for (int j = 0; j < 8; ++j) acc[j] += (float)v0[j];
    }
    if (i < hi && sub == 0) {
        bhalf8 v0 = *(const bhalf8*)(m + (size_t)eidx[i] * HID + colb);
#pragma unroll
        for (int j = 0; j < 8; ++j) acc[j] += (float)v0[j];
    }
#pragma unroll
    for (int j = 0; j < 8; ++j)
        acc[j] += __shfl_xor(acc[j], 32);
    if (sub == 0) {
        bhalf8 o;
#pragma unroll
        for (int j = 0; j < 8; ++j) o[j] = (bhalf)acc[j];
        *(bhalf8*)(agg + (size_t)n * HID + colb) = o;
    }
}

// ---------------------------------------------------------------------------
// Wave-per-node BN with inline finalize; v input is bf16.
// MODE 0: write bf16 h. MODE 1: write bf16 h + node attention weight.
// ---------------------------------------------------------------------------
template<int MODE>
__global__ __launch_bounds__(256) void bn_row(const bhalf* __restrict__ v,
                                              const float* __restrict__ stats,
                                              float inv_n,
                                              const float* __restrict__ g,
                                              const float* __restrict__ be,
                                              bhalf* __restrict__ outb,
                                              const float* __restrict__ awW,
                                              const float* __restrict__ awb,
                                              float* __restrict__ w)
{
    int gidx = blockIdx.x * blockDim.x + threadIdx.x;
    int n = gidx >> 6, lane = gidx & 63;
    if (n >= N_NODES) return;
    int col = lane * 4;
    bhalf4 vv = *(const bhalf4*)(v + (size_t)n * HID + col);
    float4 sm = *(const float4*)(stats + col);
    float4 sq = *(const float4*)(stats + HID + col);
    float4 gg = *(const float4*)(g + col);
    float4 bb = *(const float4*)(be + col);
    float mux = sm.x * inv_n, muy = sm.y * inv_n, muz = sm.z * inv_n, muw = sm.w * inv_n;
    float rsx = rsqrtf(sq.x * inv_n - mux * mux + 1e-5f);
    float rsy = rsqrtf(sq.y * inv_n - muy * muy + 1e-5f);
    float rsz = rsqrtf(sq.z * inv_n - muz * muz + 1e-5f);
    float rsw = rsqrtf(sq.w * inv_n - muw * muw + 1e-5f);
    float4 o;
    o.x = gg.x * ((float)vv.x - mux) * rsx + bb.x;
    o.y = gg.y * ((float)vv.y - muy) * rsy + bb.y;
    o.z = gg.z * ((float)vv.z - muz) * rsz + bb.z;
    o.w = gg.w * ((float)vv.w - muw) * rsw + bb.w;
    bhalf4 ob = {(bhalf)o.x, (bhalf)o.y, (bhalf)o.z, (bhalf)o.w};
    *(bhalf4*)(outb + (size_t)n * HID + col) = ob;
    if (MODE == 1) {
        float4 wv = *(const float4*)(awW + col);
        float d = o.x * wv.x + o.y * wv.y + o.z * wv.z + o.w * wv.w;
#pragma unroll
        for (int off = 32; off > 0; off >>= 1) d += __shfl_xor(d, off);
        if (lane == 0) w[n] = 1.f / (1.f + expf(-(d + awb[0])));
    }
}

// ---------------------------------------------------------------------------
__global__ __launch_bounds__(256) void readout(const bhalf* __restrict__ h,
                                               const float* __restrict__ w,
                                               const int* __restrict__ gid,
                                               bhalf* __restrict__ z)
{
    int g = blockIdx.x, col = threadIdx.x;
    int lo = 0, hi = N_NODES;
    while (lo < hi) { int mid = (lo + hi) >> 1; if (gid[mid] < g) lo = mid + 1; else hi = mid; }
    int start = lo;
    hi = N_NODES;
    while (lo < hi) { int mid = (lo + hi) >> 1; if (gid[mid] <= g) lo = mid + 1; else hi = mid; }
    int end = lo;
    float s = 0.f, mx = -INFINITY;
    for (int n = start; n < end; ++n) {
        float v = (float)h[(size_t)n * HID + col];
        s = fmaf(v, w[n], s);
        mx = fmaxf(mx, v);
    }
    z[(size_t)g * 1024 + col] = (bhalf)s;
    z[(size_t)g * 1024 + HID + col] = (bhalf)mx;
}

// ---------------------------------------------------------------------------
extern "C" void kernel_launch(void* const* d_in, const int* in_sizes, int n_in,
                              void* d_out, int out_size, void* d_ws, size_t ws_size,
                              hipStream_t stream)
{
    (void)in_sizes; (void)n_in; (void)out_size; (void)ws_size;

    const float* node_feats = (const float*)d_in[0];
    const float* rdkit      = (const float*)d_in[1];
    const int*   src        = (const int*)d_in[2];
    const int*   dst        = (const int*)d_in[3];
    const int*   gid        = (const int*)d_in[4];
    const float* W1  = (const float*)d_in[5];
    const float* b1  = (const float*)d_in[6];
    const float* rW1 = (const float*)d_in[7];
    const float* rb1 = (const float*)d_in[8];
    const float* g1  = (const float*)d_in[9];
    const float* be1 = (const float*)d_in[10];
    const float* W2  = (const float*)d_in[11];
    const float* b2  = (const float*)d_in[12];
    const float* rW2 = (const float*)d_in[13];
    const float* rb2 = (const float*)d_in[14];
    const float* g2  = (const float*)d_in[15];
    const float* be2 = (const float*)d_in[16];
    const float* aw_W  = (const float*)d_in[17];
    const float* aw_b  = (const float*)d_in[18];
    const float* rk_W1 = (const float*)d_in[19];
    const float* rk_b1 = (const float*)d_in[20];
    const float* rk_W2 = (const float*)d_in[21];
    const float* rk_b2 = (const float*)d_in[22];
    const float* c_W1  = (const float*)d_in[23];
    const float* c_b1  = (const float*)d_in[24];
    const float* c_W2  = (const float*)d_in[25];
    const float* c_b2  = (const float*)d_in[26];
    const float* c_W3  = (const float*)d_in[27];
    const float* c_b3  = (const float*)d_in[28];

    float* out = (float*)d_out;

    const size_t NODE = (size_t)N_NODES * HID;         // 5,120,000
    bhalf* nfb   = (bhalf*)d_ws;                       // [20000,128]
    bhalf* h1b   = nfb + (size_t)N_NODES * IN_FEATS;   // [20000,256]
    bhalf* h2b   = h1b + NODE;                         // [20000,256]
    bhalf* aggb  = h2b + NODE;                         // [20000,256]
    bhalf* vb    = aggb + NODE;                        // [20000,256]
    bhalf* W1cat = vb + NODE;                          // [512,128]
    bhalf* W2cat = W1cat + 512 * 128;                  // [512,256]
    bhalf* rkW1t = W2cat + 512 * 256;                  // [1024,2048]
    bhalf* rkW2t = rkW1t + 2048 * 1024;                // [512,1024]
    bhalf* cW1t  = rkW2t + 1024 * 512;                 // [1024,1024]
    bhalf* cW2t  = cW1t + 1024 * 1024;                 // [512,1024]
    bhalf* rdkb  = cW2t + 1024 * 512;                  // [512,2048]
    // zero region: stats1|stats2|counts|cursor contiguous (41024 x 4B)
    float* stats1 = (float*)(rdkb + 512 * 2048);       // 512 raw sum|sumsq
    float* stats2 = stats1 + 512;                      // 512
    int*   counts = (int*)(stats2 + 512);              // N
    int*   cursor = counts + N_NODES;                  // N
    float* wbuf   = (float*)(cursor + N_NODES);        // 20000
    int*   offsets = (int*)(wbuf + N_NODES);           // N+1
    int*   eidx    = offsets + N_NODES + 1;            // N_EDGES
    int*   bsum    = eidx + N_EDGES;                   // 128
    bhalf* rkhb  = (bhalf*)(bsum + 128);               // [512,1024]
    bhalf* zb    = rkhb + 512 * 1024;                  // [512,1024]
    bhalf* ch1b  = zb + 512 * 1024;                    // [512,1024]
    float* spart = (float*)(ch1b + 512 * 1024);        // split-K partials (<=16MB)

    dim3 blk(256);
    const int EPB = (N_EDGES + 255) / 256;
    const int NPB = (N_NODES + 255) / 256;             // 79
    const int NWAVE = (N_NODES * 64) / 256;            // 5000: wave per node
    dim3 gfused(HID / 64, (N_NODES + 63) / 64);        // (4, 313)

    // ---------------- prep: weights + inputs + zeroing (1 launch) ----------
    PrepTab tab;
    tab.e[0] = {W1,    W1cat,             128, 256,   32};
    tab.e[1] = {rW1,   W1cat + 256 * 128, 128, 256,   64};
    tab.e[2] = {W2,    W2cat,             256, 256,  128};
    tab.e[3] = {rW2,   W2cat + 256 * 256, 256, 256,  192};
    tab.e[4] = {rk_W1, rkW1t,            2048, 1024, 2240};
    tab.e[5] = {rk_W2, rkW2t,            1024, 512,  2752};
    tab.e[6] = {c_W1,  cW1t,             1024, 1024, 3776};
    tab.e[7] = {c_W2,  cW2t,             1024, 512,  4288};
    tab.ca = node_feats; tab.coa = nfb;  tab.n4a = N_NODES * IN_FEATS / 4;
    tab.cb = rdkit;      tab.cob = rdkb; tab.n4b = 512 * 2048 / 4;
    tab.zbase = (uint4*)stats1;
    tab.zn = (1024 + 2 * N_NODES) / 4;                 // 41024 ints -> 10256 uint4
    const int ZB = (tab.zn + 255) / 256;               // 41
    prep_batch<<<WTILES + CONVB + ZB, blk, 0, stream>>>(tab);

    // ---------------- CSR build ----------------
    csr_count<<<EPB, blk, 0, stream>>>(dst, counts);
    csr_scan_a<<<NPB, blk, 0, stream>>>(counts, bsum);
    csr_scan_c<<<NPB, blk, 0, stream>>>(counts, bsum, NPB, offsets);
    csr_fill<<<EPB, blk, 0, stream>>>(src, dst, offsets, cursor, eidx);
    csr_sort_wave<<<NWAVE, blk, 0, stream>>>(offsets, eidx);

    // ---------------- Layer 1: gather -> fused GEMM(v,stats) -> BN ----------
    edge_gather1<<<NWAVE, blk, 0, stream>>>(nfb, offsets, eidx, aggb);
    gcn_gemm_fused<<<gfused, blk, 0, stream>>>(aggb, nfb, W1cat, W1cat + 256 * 128,
                                               b1, rb1, vb, stats1, N_NODES, IN_FEATS);
    bn_row<0><<<NWAVE, blk, 0, stream>>>(vb, stats1, 1.0f / N_NODES, g1, be1,
                                         h1b, nullptr, nullptr, nullptr);

    // ---------------- Layer 2 ----------------
    edge_gather2<<<NWAVE, blk, 0, stream>>>(h1b, offsets, eidx, aggb);
    gcn_gemm_fused<<<gfused, blk, 0, stream>>>(aggb, h1b, W2cat, W2cat + 256 * 256,
                                               b2, rb2, vb, stats2, N_NODES, HID);
    bn_row<1><<<NWAVE, blk, 0, stream>>>(vb, stats2, 1.0f / N_NODES, g2, be2,
                                         h2b, aw_W, aw_b, wbuf);

    // ---------------- Readout ----------------
    readout<<<N_GRAPHS, HID, 0, stream>>>(h2b, wbuf, gid, zb);

    // ---------------- RDKit branch (split-K) ----------------
    gemm_mfma<0,0><<<dim3(16, 8, 8), blk, 0, stream>>>(rdkb, rkW1t, spart, nullptr,
                                                       512, 2048, 1024);
    splitk_combine<1,1><<<512, blk, 0, stream>>>(spart, 8, 512, 1024, 1024, rk_b1, rkhb);
    gemm_mfma<0,0><<<dim3(8, 8, 8), blk, 0, stream>>>(rkhb, rkW2t, spart, nullptr,
                                                      512, 1024, 512);
    splitk_combine<1,1><<<256, blk, 0, stream>>>(spart, 8, 512, 512, 1024, rk_b2, zb + 512);

    // ---------------- Combined head (split-K) ----------------
    gemm_mfma<0,0><<<dim3(16, 8, 4), blk, 0, stream>>>(zb, cW1t, spart, nullptr,
                                                       512, 1024, 1024);
    splitk_combine<1,1><<<512, blk, 0, stream>>>(spart, 4, 512, 1024, 1024, c_b1, ch1b);
    gemm_mfma<0,0><<<dim3(8, 8, 8), blk, 0, stream>>>(ch1b, cW2t, spart, nullptr,
                                                      512, 1024, 512);
    splitk_combine_dot<<<512, 128, 0, stream>>>(spart, 8, 512, 512, c_b2, c_W3, c_b3, out);
}

// Round 14
// 230.203 us; speedup vs baseline: 11.5949x; 1.0123x over previous
//
#include <hip/hip_runtime.h>
#include <hip/hip_bf16.h>
#include <cstdint>
#include <cstddef>

#define N_NODES 20000
#define N_EDGES 320000
#define N_GRAPHS 512
#define IN_FEATS 128
#define HID 256

typedef __bf16 bhalf;
typedef __bf16 bhalf8 __attribute__((ext_vector_type(8)));
typedef __bf16 bhalf4 __attribute__((ext_vector_type(4)));
typedef __bf16 bhalf2 __attribute__((ext_vector_type(2)));
typedef float f32x4 __attribute__((ext_vector_type(4)));

// Bijective XCD-aware block swizzle (m204).
__device__ __forceinline__ int2 xcd_swz(int bx, int by, int nbx, int nby)
{
    int lid = by * nbx + bx;
    int nwg = nbx * nby;
    int q = nwg >> 3, r = nwg & 7;
    int xcd = lid & 7, loc = lid >> 3;
    int s = (xcd < r ? xcd * (q + 1) : r * (q + 1) + (xcd - r) * q) + loc;
    return make_int2(s % nbx, s / nbx);
}

// ---------------------------------------------------------------------------
// bf16 MFMA GEMM (head layers): C = A @ Bt^T. 64x64 tile, BK=64, 4 waves,
// register-prefetch. Split-K via gridDim.z (fp32 partials). XCD-swizzled.
// ---------------------------------------------------------------------------
template<int RELU, int OUTBF16>
__global__ __launch_bounds__(256) void gemm_mfma(const bhalf* __restrict__ A,
                                                 const bhalf* __restrict__ Bt,
                                                 void* __restrict__ Cv,
                                                 const float* __restrict__ bias,
                                                 int M, int K, int ldc)
{
    __shared__ bhalf As[64 * 64];
    __shared__ bhalf Bs[64 * 64];

    const int t = threadIdx.x;
    const int lane = t & 63, wid = t >> 6;
    const int wm0 = (wid >> 1) * 32, wn0 = (wid & 1) * 32;
    int2 bsw = xcd_swz(blockIdx.x, blockIdx.y, gridDim.x, gridDim.y);
    const int m0 = bsw.y * 64, n0 = bsw.x * 64;
    const int S = gridDim.z, kz = blockIdx.z;
    const int Ks = K / S;

    const int srow = t >> 2;
    const int sc0 = (t & 3) << 3;

    f32x4 acc[2][2] = {};
    uint4 ra0, ra1, rb0, rb1;

    const bool mok = (m0 + srow) < M;
    const bhalf* Abase = A + (size_t)(m0 + srow) * K + (size_t)kz * Ks;
    const bhalf* Bbase = Bt + (size_t)(n0 + srow) * K + (size_t)kz * Ks;

    ra0 = mok ? *(const uint4*)(Abase + sc0)      : make_uint4(0u,0u,0u,0u);
    ra1 = mok ? *(const uint4*)(Abase + sc0 + 32) : make_uint4(0u,0u,0u,0u);
    rb0 = *(const uint4*)(Bbase + sc0);
    rb1 = *(const uint4*)(Bbase + sc0 + 32);

    const int swz = (srow & 7) << 3;
    for (int k0 = 0; k0 < Ks; k0 += 64) {
        __syncthreads();
        *(uint4*)&As[srow * 64 + (sc0 ^ swz)]        = ra0;
        *(uint4*)&As[srow * 64 + ((sc0 + 32) ^ swz)] = ra1;
        *(uint4*)&Bs[srow * 64 + (sc0 ^ swz)]        = rb0;
        *(uint4*)&Bs[srow * 64 + ((sc0 + 32) ^ swz)] = rb1;
        __syncthreads();
        if (k0 + 64 < Ks) {
            const bhalf* An = Abase + k0 + 64;
            const bhalf* Bn = Bbase + k0 + 64;
            ra0 = mok ? *(const uint4*)(An + sc0)      : make_uint4(0u,0u,0u,0u);
            ra1 = mok ? *(const uint4*)(An + sc0 + 32) : make_uint4(0u,0u,0u,0u);
            rb0 = *(const uint4*)(Bn + sc0);
            rb1 = *(const uint4*)(Bn + sc0 + 32);
        }
#pragma unroll
        for (int kb = 0; kb < 2; ++kb) {
            const int kc = kb * 32 + (lane >> 4) * 8;
            bhalf8 af[2], bfr[2];
#pragma unroll
            for (int i = 0; i < 2; ++i) {
                int rA = wm0 + i * 16 + (lane & 15);
                af[i] = *(const bhalf8*)&As[rA * 64 + (kc ^ ((rA & 7) << 3))];
                int rB = wn0 + i * 16 + (lane & 15);
                bfr[i] = *(const bhalf8*)&Bs[rB * 64 + (kc ^ ((rB & 7) << 3))];
            }
#pragma unroll
            for (int mi = 0; mi < 2; ++mi)
#pragma unroll
                for (int ni = 0; ni < 2; ++ni)
                    acc[mi][ni] = __builtin_amdgcn_mfma_f32_16x16x32_bf16(
                        af[mi], bfr[ni], acc[mi][ni], 0, 0, 0);
        }
    }

#pragma unroll
    for (int mi = 0; mi < 2; ++mi)
#pragma unroll
        for (int ni = 0; ni < 2; ++ni) {
            int col = n0 + wn0 + ni * 16 + (lane & 15);
            f32x4 v = acc[mi][ni];
            if (S > 1) {
#pragma unroll
                for (int r = 0; r < 4; ++r) {
                    int row = m0 + wm0 + mi * 16 + (lane >> 4) * 4 + r;
                    if (row < M)
                        ((float*)Cv)[((size_t)kz * M + row) * ldc + col] = v[r];
                }
            } else {
                float bb = bias ? bias[col] : 0.f;
#pragma unroll
                for (int r = 0; r < 4; ++r) {
                    int row = m0 + wm0 + mi * 16 + (lane >> 4) * 4 + r;
                    if (row < M) {
                        float x = v[r] + bb;
                        if (RELU) x = fmaxf(x, 0.f);
                        if (OUTBF16) ((bhalf*)Cv)[(size_t)row * ldc + col] = (bhalf)x;
                        else         ((float*)Cv)[(size_t)row * ldc + col] = x;
                    }
                }
            }
        }
}

// ---------------------------------------------------------------------------
// Fused GCN layer GEMM, two-phase (m then r). BN=1: the Ax input is raw v of
// the previous layer; BN1 affine (from stats/g/be) is applied during LDS
// staging of phase-1 tiles. NOTE: vout must NOT alias Aagg/Ax (inter-block
// read/write race otherwise — round-13 lesson).
// ---------------------------------------------------------------------------
template<int BN>
__global__ __launch_bounds__(256) void gcn_gemm_fused(const bhalf* __restrict__ Aagg,
                                                      const bhalf* __restrict__ Ax,
                                                      const bhalf* __restrict__ BW,
                                                      const bhalf* __restrict__ BrW,
                                                      const float* __restrict__ b,
                                                      const float* __restrict__ rb,
                                                      bhalf* __restrict__ vout,
                                                      float* __restrict__ stats,
                                                      int M, int K,
                                                      const float* __restrict__ bnstats,
                                                      const float* __restrict__ bng,
                                                      const float* __restrict__ bnbe,
                                                      float inv_n)
{
    __shared__ bhalf As[64 * 64];
    __shared__ bhalf Bs[64 * 64];
    __shared__ float ssum[64], ssq[64];
    __shared__ float bnS[256], bnB[256];

    const int t = threadIdx.x;
    const int lane = t & 63, wid = t >> 6;
    const int wm0 = (wid >> 1) * 32, wn0 = (wid & 1) * 32;
    int2 bsw = xcd_swz(blockIdx.x, blockIdx.y, gridDim.x, gridDim.y);
    const int m0 = bsw.y * 64, n0 = bsw.x * 64;

    const int srow = t >> 2;
    const int sc0 = (t & 3) << 3;
    const int nk = K >> 6;

    if (BN && t < K) {
        float mu = bnstats[t] * inv_n;
        float rs = rsqrtf(bnstats[K + t] * inv_n - mu * mu + 1e-5f);
        float s = bng[t] * rs;
        bnS[t] = s;
        bnB[t] = bnbe[t] - mu * s;
    }

    f32x4 accM[2][2] = {};
    f32x4 accR[2][2] = {};
    uint4 ra0, ra1, rb0, rb1;

    const bool mok = (m0 + srow) < M;
    const bhalf* A0r = Aagg + (size_t)(m0 + srow) * K;
    const bhalf* A1r = Ax + (size_t)(m0 + srow) * K;
    const bhalf* B0r = BW + (size_t)(n0 + srow) * K;
    const bhalf* B1r = BrW + (size_t)(n0 + srow) * K;

    ra0 = mok ? *(const uint4*)(A0r + sc0)      : make_uint4(0u,0u,0u,0u);
    ra1 = mok ? *(const uint4*)(A0r + sc0 + 32) : make_uint4(0u,0u,0u,0u);
    rb0 = *(const uint4*)(B0r + sc0);
    rb1 = *(const uint4*)(B0r + sc0 + 32);

    const int swz = (srow & 7) << 3;
    const int total = 2 * nk;
    if (BN) __syncthreads();   // bnS/bnB visible before first phase-1 write
    for (int ii = 0; ii < total; ++ii) {
        __syncthreads();
        if (BN && ii >= nk) {   // apply BN1 affine to the Ax tile being staged
            int kb0 = ((ii - nk) << 6) + sc0;
            bhalf8 a0 = *(bhalf8*)&ra0, a1 = *(bhalf8*)&ra1;
#pragma unroll
            for (int j = 0; j < 8; ++j) {
                a0[j] = (bhalf)((float)a0[j] * bnS[kb0 + j] + bnB[kb0 + j]);
                a1[j] = (bhalf)((float)a1[j] * bnS[kb0 + 32 + j] + bnB[kb0 + 32 + j]);
            }
            ra0 = *(uint4*)&a0; ra1 = *(uint4*)&a1;
        }
        *(uint4*)&As[srow * 64 + (sc0 ^ swz)]        = ra0;
        *(uint4*)&As[srow * 64 + ((sc0 + 32) ^ swz)] = ra1;
        *(uint4*)&Bs[srow * 64 + (sc0 ^ swz)]        = rb0;
        *(uint4*)&Bs[srow * 64 + ((sc0 + 32) ^ swz)] = rb1;
        __syncthreads();
        int jj = ii + 1;
        if (jj < total) {
            bool seln = jj >= nk;
            int kk = (seln ? jj - nk : jj) << 6;
            const bhalf* Ab = (seln ? A1r : A0r) + kk;
            const bhalf* Bb = (seln ? B1r : B0r) + kk;
            ra0 = mok ? *(const uint4*)(Ab + sc0)      : make_uint4(0u,0u,0u,0u);
            ra1 = mok ? *(const uint4*)(Ab + sc0 + 32) : make_uint4(0u,0u,0u,0u);
            rb0 = *(const uint4*)(Bb + sc0);
            rb1 = *(const uint4*)(Bb + sc0 + 32);
        }
        const bool selc = ii >= nk;
#pragma unroll
        for (int kb = 0; kb < 2; ++kb) {
            const int kc = kb * 32 + (lane >> 4) * 8;
            bhalf8 af[2], bfr[2];
#pragma unroll
            for (int i = 0; i < 2; ++i) {
                int rA = wm0 + i * 16 + (lane & 15);
                af[i] = *(const bhalf8*)&As[rA * 64 + (kc ^ ((rA & 7) << 3))];
                int rB = wn0 + i * 16 + (lane & 15);
                bfr[i] = *(const bhalf8*)&Bs[rB * 64 + (kc ^ ((rB & 7) << 3))];
            }
            if (!selc) {
#pragma unroll
                for (int mi = 0; mi < 2; ++mi)
#pragma unroll
                    for (int ni = 0; ni < 2; ++ni)
                        accM[mi][ni] = __builtin_amdgcn_mfma_f32_16x16x32_bf16(
                            af[mi], bfr[ni], accM[mi][ni], 0, 0, 0);
            } else {
#pragma unroll
                for (int mi = 0; mi < 2; ++mi)
#pragma unroll
                    for (int ni = 0; ni < 2; ++ni)
                        accR[mi][ni] = __builtin_amdgcn_mfma_f32_16x16x32_bf16(
                            af[mi], bfr[ni], accR[mi][ni], 0, 0, 0);
            }
        }
    }

    if (t < 64) { ssum[t] = 0.f; ssq[t] = 0.f; }
    __syncthreads();
    float sloc[2] = {0.f, 0.f}, s2loc[2] = {0.f, 0.f};
#pragma unroll
    for (int ni = 0; ni < 2; ++ni) {
        int cl = wn0 + ni * 16 + (lane & 15);
        int c = n0 + cl;
        float bb = b[c], rbb = rb[c];
#pragma unroll
        for (int mi = 0; mi < 2; ++mi) {
            f32x4 a0v = accM[mi][ni], a1v = accR[mi][ni];
#pragma unroll
            for (int r = 0; r < 4; ++r) {
                int row = m0 + wm0 + mi * 16 + (lane >> 4) * 4 + r;
                if (row < M) {
                    float x = fmaxf(a0v[r] + bb, 0.f) + fmaxf(a1v[r] + rbb, 0.f);
                    vout[(size_t)row * HID + c] = (bhalf)x;
                    sloc[ni] += x;
                    s2loc[ni] += x * x;
                }
            }
        }
        atomicAdd(&ssum[cl], sloc[ni]);
        atomicAdd(&ssq[cl], s2loc[ni]);
    }
    __syncthreads();
    if (t < 64) {
        atomicAdd(&stats[n0 + t], ssum[t]);
        atomicAdd(&stats[HID + n0 + t], ssq[t]);
    }
}

// sum S split-K partials + bias + act
template<int RELU, int OUTBF16>
__global__ __launch_bounds__(256) void splitk_combine(const float* __restrict__ part,
                                                      int S, int M, int N, int ldo,
                                                      const float* __restrict__ bias,
                                                      void* __restrict__ outv)
{
    int i = blockIdx.x * blockDim.x + threadIdx.x;
    int n4 = N >> 2;
    if (i >= M * n4) return;
    int row = i / n4, c4 = (i - row * n4) << 2;
    float4 s = make_float4(0.f, 0.f, 0.f, 0.f);
    for (int z = 0; z < S; ++z) {
        float4 p = *(const float4*)(part + ((size_t)z * M + row) * N + c4);
        s.x += p.x; s.y += p.y; s.z += p.z; s.w += p.w;
    }
    float4 bb = *(const float4*)(bias + c4);
    s.x += bb.x; s.y += bb.y; s.z += bb.z; s.w += bb.w;
    if (RELU) {
        s.x = fmaxf(s.x, 0.f); s.y = fmaxf(s.y, 0.f);
        s.z = fmaxf(s.z, 0.f); s.w = fmaxf(s.w, 0.f);
    }
    if (OUTBF16) {
        bhalf4 o = {(bhalf)s.x, (bhalf)s.y, (bhalf)s.z, (bhalf)s.w};
        *(bhalf4*)((bhalf*)outv + (size_t)row * ldo + c4) = o;
    } else {
        *(float4*)((float*)outv + (size_t)row * ldo + c4) = s;
    }
}

// last head layer: combine S partials + bias + relu, dot with W3
__global__ __launch_bounds__(128) void splitk_combine_dot(const float* __restrict__ part,
                                                          int S, int M, int N,
                                                          const float* __restrict__ bias,
                                                          const float* __restrict__ W3,
                                                          const float* __restrict__ b3,
                                                          float* __restrict__ out)
{
    int row = blockIdx.x, t = threadIdx.x;
    int c4 = t << 2;
    float4 s = make_float4(0.f, 0.f, 0.f, 0.f);
    for (int z = 0; z < S; ++z) {
        float4 p = *(const float4*)(part + ((size_t)z * M + row) * N + c4);
        s.x += p.x; s.y += p.y; s.z += p.z; s.w += p.w;
    }
    float4 bb = *(const float4*)(bias + c4);
    float4 w = *(const float4*)(W3 + c4);
    float d = fmaxf(s.x + bb.x, 0.f) * w.x + fmaxf(s.y + bb.y, 0.f) * w.y
            + fmaxf(s.z + bb.z, 0.f) * w.z + fmaxf(s.w + bb.w, 0.f) * w.w;
#pragma unroll
    for (int off = 32; off > 0; off >>= 1) d += __shfl_xor(d, off);
    __shared__ float ws2[2];
    if ((t & 63) == 0) ws2[t >> 6] = d;
    __syncthreads();
    if (t == 0) out[row] = ws2[0] + ws2[1] + b3[0];
}

// ---------------------------------------------------------------------------
// Prep mega-kernel: weight transpose+convert | input conversion | zeroing.
// ---------------------------------------------------------------------------
struct WEnt { const float* src; bhalf* dst; int K; int N; int tiles_end; };
struct PrepTab {
    WEnt e[8];
    const float* ca; bhalf* coa; int n4a;
    const float* cb; bhalf* cob; int n4b;
    uint4* zbase; int zn;
};

#define WTILES 4288
#define CONVB  3524

__global__ __launch_bounds__(256) void prep_batch(PrepTab tab)
{
    __shared__ float tile[32][33];
    int tb = blockIdx.x;
    int t = threadIdx.x;
    if (tb < WTILES) {
        int idx = 0;
#pragma unroll
        for (int i = 0; i < 8; ++i)
            if (tb >= tab.e[i].tiles_end) idx = i + 1;
        const WEnt& E = tab.e[idx];
        int t0 = idx ? tab.e[idx - 1].tiles_end : 0;
        int lt = tb - t0;
        int tX = E.N >> 5;
        int bx = (lt % tX) << 5;
        int by = (lt / tX) << 5;
        int tx = t & 31, ty = t >> 5;
#pragma unroll
        for (int i = 0; i < 32; i += 8)
            tile[ty + i][tx] = E.src[(size_t)(by + ty + i) * E.N + bx + tx];
        __syncthreads();
#pragma unroll
        for (int i = 0; i < 32; i += 8)
            E.dst[(size_t)(bx + ty + i) * E.K + by + tx] = (bhalf)tile[tx][ty + i];
    } else if (tb < WTILES + CONVB) {
        int i = (tb - WTILES) * 256 + t;
        const float* s; bhalf* d; int j;
        if (i < tab.n4a) { s = tab.ca; d = tab.coa; j = i; }
        else { j = i - tab.n4a; if (j >= tab.n4b) return; s = tab.cb; d = tab.cob; }
        float4 v = ((const float4*)s)[j];
        bhalf4 o = {(bhalf)v.x, (bhalf)v.y, (bhalf)v.z, (bhalf)v.w};
        ((bhalf4*)d)[j] = o;
    } else {
        int j = (tb - WTILES - CONVB) * 256 + t;
        if (j < tab.zn) tab.zbase[j] = make_uint4(0u, 0u, 0u, 0u);
    }
}

// ---------------------------------------------------------------------------
// CSR build
// ---------------------------------------------------------------------------
__global__ void csr_count(const int* __restrict__ dst, int* __restrict__ counts)
{
    int e = blockIdx.x * blockDim.x + threadIdx.x;
    if (e >= N_EDGES) return;
    atomicAdd(&counts[dst[e]], 1);
}

__global__ __launch_bounds__(256) void csr_scan_a(const int* __restrict__ counts,
                                                  int* __restrict__ bsum)
{
    int i = blockIdx.x * 256 + threadIdx.x;
    int v = (i < N_NODES) ? counts[i] : 0;
#pragma unroll
    for (int off = 32; off > 0; off >>= 1) v += __shfl_down(v, off);
    __shared__ int ws[4];
    if ((threadIdx.x & 63) == 0) ws[threadIdx.x >> 6] = v;
    __syncthreads();
    if (threadIdx.x == 0) bsum[blockIdx.x] = ws[0] + ws[1] + ws[2] + ws[3];
}

// per-block prefix of bsum computed inline
__global__ __launch_bounds__(256) void csr_scan_c(const int* __restrict__ counts,
                                                  const int* __restrict__ bsum, int nb,
                                                  int* __restrict__ offsets)
{
    int t = threadIdx.x, b = blockIdx.x;
    int i = b * 256 + t;
    int v = (i < N_NODES) ? counts[i] : 0;
    int x = v;
#pragma unroll
    for (int off = 1; off < 64; off <<= 1) {
        int y = __shfl_up(x, off);
        if ((t & 63) >= off) x += y;
    }
    __shared__ int wsum[4];
    __shared__ int tmp[128];
    __shared__ int addsh;
    if ((t & 63) == 63) wsum[t >> 6] = x;
    if (t < 128) tmp[t] = (t < nb) ? bsum[t] : 0;
    __syncthreads();
    if (t == 0) {
        int a = 0;
        for (int j = 0; j < b; ++j) a += tmp[j];
        addsh = a;
    }
    __syncthreads();
    int add = addsh;
    for (int w = 0; w < (t >> 6); ++w) add += wsum[w];
    int excl = x - v + add;
    if (i < N_NODES) offsets[i] = excl;
    if (i == N_NODES - 1) offsets[N_NODES] = excl + v;
}

__global__ void csr_fill(const int* __restrict__ src, const int* __restrict__ dst,
                         const int* __restrict__ offsets, int* __restrict__ cursor,
                         int* __restrict__ eidx)
{
    int e = blockIdx.x * blockDim.x + threadIdx.x;
    if (e >= N_EDGES) return;
    int d = dst[e];
    int slot = offsets[d] + atomicAdd(&cursor[d], 1);
    eidx[slot] = src[e];
}

__global__ void csr_sort_wave(const int* __restrict__ offsets, int* __restrict__ eidx)
{
    int gidx = blockIdx.x * blockDim.x + threadIdx.x;
    int n = gidx >> 6, lane = gidx & 63;
    if (n >= N_NODES) return;
    int lo = offsets[n], hi = offsets[n + 1];
    int cnt = hi - lo;
    if (cnt <= 1) return;
    if (cnt <= 64) {
        int v = (lane < cnt) ? eidx[lo + lane] : 0x7fffffff;
        int rank = 0;
        for (int j = 0; j < cnt; ++j) {
            int vj = __shfl(v, j);
            if (vj < v || (vj == v && j < lane)) ++rank;
        }
        if (lane < cnt) eidx[lo + rank] = v;
    } else if (lane == 0) {
        for (int i = lo + 1; i < hi; ++i) {
            int v = eidx[i]; int j = i - 1;
            while (j >= lo && eidx[j] > v) { eidx[j + 1] = eidx[j]; --j; }
            eidx[j + 1] = v;
        }
    }
}

// ---------------------------------------------------------------------------
// Gather-aggregate, layer 1 (128 cols): one wave = 4 edges/step, 16 lanes x
// 16B per row, shfl-xor combine across lane-groups.
// ---------------------------------------------------------------------------
__global__ __launch_bounds__(256) void edge_gather1(const bhalf* __restrict__ m,
                                                    const int* __restrict__ offsets,
                                                    const int* __restrict__ eidx,
                                                    bhalf* __restrict__ agg)
{
    int gidx = blockIdx.x * blockDim.x + threadIdx.x;
    int n = gidx >> 6, lane = gidx & 63;
    if (n >= N_NODES) return;
    int lo = offsets[n], hi = offsets[n + 1];
    int sub = lane >> 4;
    int colb = (lane & 15) * 8;
    float acc[8] = {};
    int i = lo;
    for (; i + 8 <= hi; i += 8) {
        bhalf8 v0 = *(const bhalf8*)(m + (size_t)eidx[i + sub] * IN_FEATS + colb);
        bhalf8 v1 = *(const bhalf8*)(m + (size_t)eidx[i + 4 + sub] * IN_FEATS + colb);
#pragma unroll
        for (int j = 0; j < 8; ++j) acc[j] += (float)v0[j] + (float)v1[j];
    }
    if (i + 4 <= hi) {
        bhalf8 v0 = *(const bhalf8*)(m + (size_t)eidx[i + sub] * IN_FEATS + colb);
#pragma unroll
        for (int j = 0; j < 8; ++j) acc[j] += (float)v0[j];
        i += 4;
    }
    if (i < hi && sub < hi - i) {
        bhalf8 v0 = *(const bhalf8*)(m + (size_t)eidx[i + sub] * IN_FEATS + colb);
#pragma unroll
        for (int j = 0; j < 8; ++j) acc[j] += (float)v0[j];
    }
#pragma unroll
    for (int j = 0; j < 8; ++j) {
        acc[j] += __shfl_xor(acc[j], 16);
        acc[j] += __shfl_xor(acc[j], 32);
    }
    if (sub == 0) {
        bhalf8 o;
#pragma unroll
        for (int j = 0; j < 8; ++j) o[j] = (bhalf)acc[j];
        *(bhalf8*)(agg + (size_t)n * IN_FEATS + colb) = o;
    }
}

// ---------------------------------------------------------------------------
// Gather-aggregate, layer 2 with fused BN1: aggregates BN(v) via
// sum BN(v) = s*sum(v) + deg*t. One wave = 2 edges/step, 32 lanes x 16B.
// ---------------------------------------------------------------------------
__global__ __launch_bounds__(256) void edge_gather2_bn(const bhalf* __restrict__ m,
                                                       const int* __restrict__ offsets,
                                                       const int* __restrict__ eidx,
                                                       const float* __restrict__ bnstats,
                                                       const float* __restrict__ bng,
                                                       const float* __restrict__ bnbe,
                                                       float inv_n,
                                                       bhalf* __restrict__ agg)
{
    int gidx = blockIdx.x * blockDim.x + threadIdx.x;
    int n = gidx >> 6, lane = gidx & 63;
    if (n >= N_NODES) return;
    int lo = offsets[n], hi = offsets[n + 1];
    int sub = lane >> 5;
    int colb = (lane & 31) * 8;
    float acc[8] = {};
    int i = lo;
    for (; i + 8 <= hi; i += 8) {
        bhalf8 v0 = *(const bhalf8*)(m + (size_t)eidx[i + sub] * HID + colb);
        bhalf8 v1 = *(const bhalf8*)(m + (size_t)eidx[i + 2 + sub] * HID + colb);
        bhalf8 v2 = *(const bhalf8*)(m + (size_t)eidx[i + 4 + sub] * HID + colb);
        bhalf8 v3 = *(const bhalf8*)(m + (size_t)eidx[i + 6 + sub] * HID + colb);
#pragma unroll
        for (int j = 0; j < 8; ++j)
            acc[j] += ((float)v0[j] + (float)v1[j]) + ((float)v2[j] + (float)v3[j]);
    }
    for (; i + 2 <= hi; i += 2) {
        bhalf8 v0 = *(const bhalf8*)(m + (size_t)eidx[i + sub] * HID + colb);
#pragma unroll
        for (int j = 0; j < 8; ++j) acc[j] += (float)v0[j];
    }
    if (i < hi && sub == 0) {
        bhalf8 v0 = *(const bhalf8*)(m + (size_t)eidx[i] * HID + colb);
#pragma unroll
        for (int j = 0; j < 8; ++j) acc[j] += (float)v0[j];
    }
#pragma unroll
    for (int j = 0; j < 8; ++j)
        acc[j] += __shfl_xor(acc[j], 32);
    if (sub == 0) {
        float d = (float)(hi - lo);
        bhalf8 o;
#pragma unroll
        for (int j = 0; j < 8; ++j) {
            int c = colb + j;
            float mu = bnstats[c] * inv_n;
            float rs = rsqrtf(bnstats[HID + c] * inv_n - mu * mu + 1e-5f);
            float s = bng[c] * rs;
            float tt = bnbe[c] - mu * s;
            o[j] = (bhalf)(acc[j] * s + d * tt);
        }
        *(bhalf8*)(agg + (size_t)n * HID + colb) = o;
    }
}

// ---------------------------------------------------------------------------
// Wave-per-node BN with inline finalize; v input is bf16. Writes bf16 h +
// node attention weight.
// ---------------------------------------------------------------------------
__global__ __launch_bounds__(256) void bn_row_aw(const bhalf* __restrict__ v,
                                                 const float* __restrict__ stats,
                                                 float inv_n,
                                                 const float* __restrict__ g,
                                                 const float* __restrict__ be,
                                                 bhalf* __restrict__ outb,
                                                 const float* __restrict__ awW,
                                                 const float* __restrict__ awb,
                                                 float* __restrict__ w)
{
    int gidx = blockIdx.x * blockDim.x + threadIdx.x;
    int n = gidx >> 6, lane = gidx & 63;
    if (n >= N_NODES) return;
    int col = lane * 4;
    bhalf4 vv = *(const bhalf4*)(v + (size_t)n * HID + col);
    float4 sm = *(const float4*)(stats + col);
    float4 sq = *(const float4*)(stats + HID + col);
    float4 gg = *(const float4*)(g + col);
    float4 bb = *(const float4*)(be + col);
    float mux = sm.x * inv_n, muy = sm.y * inv_n, muz = sm.z * inv_n, muw = sm.w * inv_n;
    float rsx = rsqrtf(sq.x * inv_n - mux * mux + 1e-5f);
    float rsy = rsqrtf(sq.y * inv_n - muy * muy + 1e-5f);
    float rsz = rsqrtf(sq.z * inv_n - muz * muz + 1e-5f);
    float rsw = rsqrtf(sq.w * inv_n - muw * muw + 1e-5f);
    float4 o;
    o.x = gg.x * ((float)vv.x - mux) * rsx + bb.x;
    o.y = gg.y * ((float)vv.y - muy) * rsy + bb.y;
    o.z = gg.z * ((float)vv.z - muz) * rsz + bb.z;
    o.w = gg.w * ((float)vv.w - muw) * rsw + bb.w;
    bhalf4 ob = {(bhalf)o.x, (bhalf)o.y, (bhalf)o.z, (bhalf)o.w};
    *(bhalf4*)(outb + (size_t)n * HID + col) = ob;
    float4 wv = *(const float4*)(awW + col);
    float d = o.x * wv.x + o.y * wv.y + o.z * wv.z + o.w * wv.w;
#pragma unroll
    for (int off = 32; off > 0; off >>= 1) d += __shfl_xor(d, off);
    if (lane == 0) w[n] = 1.f / (1.f + expf(-(d + awb[0])));
}

// ---------------------------------------------------------------------------
__global__ __launch_bounds__(256) void readout(const bhalf* __restrict__ h,
                                               const float* __restrict__ w,
                                               const int* __restrict__ gid,
                                               bhalf* __restrict__ z)
{
    int g = blockIdx.x, col = threadIdx.x;
    int lo = 0, hi = N_NODES;
    while (lo < hi) { int mid = (lo + hi) >> 1; if (gid[mid] < g) lo = mid + 1; else hi = mid; }
    int start = lo;
    hi = N_NODES;
    while (lo < hi) { int mid = (lo + hi) >> 1; if (gid[mid] <= g) lo = mid + 1; else hi = mid; }
    int end = lo;
    float s = 0.f, mx = -INFINITY;
    for (int n = start; n < end; ++n) {
        float v = (float)h[(size_t)n * HID + col];
        s = fmaf(v, w[n], s);
        mx = fmaxf(mx, v);
    }
    z[(size_t)g * 1024 + col] = (bhalf)s;
    z[(size_t)g * 1024 + HID + col] = (bhalf)mx;
}

// ---------------------------------------------------------------------------
extern "C" void kernel_launch(void* const* d_in, const int* in_sizes, int n_in,
                              void* d_out, int out_size, void* d_ws, size_t ws_size,
                              hipStream_t stream)
{
    (void)in_sizes; (void)n_in; (void)out_size; (void)ws_size;

    const float* node_feats = (const float*)d_in[0];
    const float* rdkit      = (const float*)d_in[1];
    const int*   src        = (const int*)d_in[2];
    const int*   dst        = (const int*)d_in[3];
    const int*   gid        = (const int*)d_in[4];
    const float* W1  = (const float*)d_in[5];
    const float* b1  = (const float*)d_in[6];
    const float* rW1 = (const float*)d_in[7];
    const float* rb1 = (const float*)d_in[8];
    const float* g1  = (const float*)d_in[9];
    const float* be1 = (const float*)d_in[10];
    const float* W2  = (const float*)d_in[11];
    const float* b2  = (const float*)d_in[12];
    const float* rW2 = (const float*)d_in[13];
    const float* rb2 = (const float*)d_in[14];
    const float* g2  = (const float*)d_in[15];
    const float* be2 = (const float*)d_in[16];
    const float* aw_W  = (const float*)d_in[17];
    const float* aw_b  = (const float*)d_in[18];
    const float* rk_W1 = (const float*)d_in[19];
    const float* rk_b1 = (const float*)d_in[20];
    const float* rk_W2 = (const float*)d_in[21];
    const float* rk_b2 = (const float*)d_in[22];
    const float* c_W1  = (const float*)d_in[23];
    const float* c_b1  = (const float*)d_in[24];
    const float* c_W2  = (const float*)d_in[25];
    const float* c_b2  = (const float*)d_in[26];
    const float* c_W3  = (const float*)d_in[27];
    const float* c_b3  = (const float*)d_in[28];

    float* out = (float*)d_out;

    const size_t NODE = (size_t)N_NODES * HID;         // 5,120,000
    bhalf* nfb   = (bhalf*)d_ws;                       // [20000,128]
    bhalf* h2b   = nfb + (size_t)N_NODES * IN_FEATS;   // [20000,256]
    bhalf* aggb  = h2b + NODE;                         // [20000,256]
    bhalf* vb    = aggb + NODE;                        // [20000,256] layer-1 v
    bhalf* vb2   = vb + NODE;                          // [20000,256] layer-2 v (no alias!)
    bhalf* W1cat = vb2 + NODE;                         // [512,128]
    bhalf* W2cat = W1cat + 512 * 128;                  // [512,256]
    bhalf* rkW1t = W2cat + 512 * 256;                  // [1024,2048]
    bhalf* rkW2t = rkW1t + 2048 * 1024;                // [512,1024]
    bhalf* cW1t  = rkW2t + 1024 * 512;                 // [1024,1024]
    bhalf* cW2t  = cW1t + 1024 * 1024;                 // [512,1024]
    bhalf* rdkb  = cW2t + 1024 * 512;                  // [512,2048]
    // zero region: stats1|stats2|counts|cursor contiguous (41024 x 4B)
    float* stats1 = (float*)(rdkb + 512 * 2048);       // 512 raw sum|sumsq
    float* stats2 = stats1 + 512;                      // 512
    int*   counts = (int*)(stats2 + 512);              // N
    int*   cursor = counts + N_NODES;                  // N
    float* wbuf   = (float*)(cursor + N_NODES);        // 20000
    int*   offsets = (int*)(wbuf + N_NODES);           // N+1
    int*   eidx    = offsets + N_NODES + 1;            // N_EDGES
    int*   bsum    = eidx + N_EDGES;                   // 128
    bhalf* rkhb  = (bhalf*)(bsum + 128);               // [512,1024]
    bhalf* zb    = rkhb + 512 * 1024;                  // [512,1024]
    bhalf* ch1b  = zb + 512 * 1024;                    // [512,1024]
    float* spart = (float*)(ch1b + 512 * 1024);        // split-K partials (<=16MB)

    dim3 blk(256);
    const int EPB = (N_EDGES + 255) / 256;
    const int NPB = (N_NODES + 255) / 256;             // 79
    const int NWAVE = (N_NODES * 64) / 256;            // 5000: wave per node
    dim3 gfused(HID / 64, (N_NODES + 63) / 64);        // (4, 313)

    // ---------------- prep: weights + inputs + zeroing (1 launch) ----------
    PrepTab tab;
    tab.e[0] = {W1,    W1cat,             128, 256,   32};
    tab.e[1] = {rW1,   W1cat + 256 * 128, 128, 256,   64};
    tab.e[2] = {W2,    W2cat,             256, 256,  128};
    tab.e[3] = {rW2,   W2cat + 256 * 256, 256, 256,  192};
    tab.e[4] = {rk_W1, rkW1t,            2048, 1024, 2240};
    tab.e[5] = {rk_W2, rkW2t,            1024, 512,  2752};
    tab.e[6] = {c_W1,  cW1t,             1024, 1024, 3776};
    tab.e[7] = {c_W2,  cW2t,             1024, 512,  4288};
    tab.ca = node_feats; tab.coa = nfb;  tab.n4a = N_NODES * IN_FEATS / 4;
    tab.cb = rdkit;      tab.cob = rdkb; tab.n4b = 512 * 2048 / 4;
    tab.zbase = (uint4*)stats1;
    tab.zn = (1024 + 2 * N_NODES) / 4;                 // 41024 ints -> 10256 uint4
    const int ZB = (tab.zn + 255) / 256;               // 41
    prep_batch<<<WTILES + CONVB + ZB, blk, 0, stream>>>(tab);

    // ---------------- CSR build ----------------
    csr_count<<<EPB, blk, 0, stream>>>(dst, counts);
    csr_scan_a<<<NPB, blk, 0, stream>>>(counts, bsum);
    csr_scan_c<<<NPB, blk, 0, stream>>>(counts, bsum, NPB, offsets);
    csr_fill<<<EPB, blk, 0, stream>>>(src, dst, offsets, cursor, eidx);
    csr_sort_wave<<<NWAVE, blk, 0, stream>>>(offsets, eidx);

    // ---------------- Layer 1: gather -> fused GEMM(v,stats) ----------------
    edge_gather1<<<NWAVE, blk, 0, stream>>>(nfb, offsets, eidx, aggb);
    gcn_gemm_fused<0><<<gfused, blk, 0, stream>>>(aggb, nfb, W1cat, W1cat + 256 * 128,
                                                  b1, rb1, vb, stats1, N_NODES, IN_FEATS,
                                                  nullptr, nullptr, nullptr, 0.f);

    // ---------------- Layer 2: BN1 fused into gather + GEMM Ax path ---------
    edge_gather2_bn<<<NWAVE, blk, 0, stream>>>(vb, offsets, eidx,
                                               stats1, g1, be1, 1.0f / N_NODES, aggb);
    gcn_gemm_fused<1><<<gfused, blk, 0, stream>>>(aggb, vb, W2cat, W2cat + 256 * 256,
                                                  b2, rb2, vb2, stats2, N_NODES, HID,
                                                  stats1, g1, be1, 1.0f / N_NODES);
    bn_row_aw<<<NWAVE, blk, 0, stream>>>(vb2, stats2, 1.0f / N_NODES, g2, be2,
                                         h2b, aw_W, aw_b, wbuf);

    // ---------------- Readout ----------------
    readout<<<N_GRAPHS, HID, 0, stream>>>(h2b, wbuf, gid, zb);

    // ---------------- RDKit branch (split-K) ----------------
    gemm_mfma<0,0><<<dim3(16, 8, 4), blk, 0, stream>>>(rdkb, rkW1t, spart, nullptr,
                                                       512, 2048, 1024);
    splitk_combine<1,1><<<512, blk, 0, stream>>>(spart, 4, 512, 1024, 1024, rk_b1, rkhb);
    gemm_mfma<0,0><<<dim3(8, 8, 8), blk, 0, stream>>>(rkhb, rkW2t, spart, nullptr,
                                                      512, 1024, 512);
    splitk_combine<1,1><<<256, blk, 0, stream>>>(spart, 8, 512, 512, 1024, rk_b2, zb + 512);

    // ---------------- Combined head (split-K) ----------------
    gemm_mfma<0,0><<<dim3(16, 8, 4), blk, 0, stream>>>(zb, cW1t, spart, nullptr,
                                                       512, 1024, 1024);
    splitk_combine<1,1><<<512, blk, 0, stream>>>(spart, 4, 512, 1024, 1024, c_b1, ch1b);
    gemm_mfma<0,0><<<dim3(8, 8, 8), blk, 0, stream>>>(ch1b, cW2t, spart, nullptr,
                                                      512, 1024, 512);
    splitk_combine_dot<<<512, 128, 0, stream>>>(spart, 8, 512, 512, c_b2, c_W3, c_b3, out);
}